// Round 5
// baseline (1386.755 us; speedup 1.0000x reference)
//
#include <hip/hip_runtime.h>
#include <math.h>

constexpr int NNODES  = 102400;
constexpr int NEDGES  = 409600;
constexpr int NGRAPHS = 2048;
constexpr int HIDDEN  = 128;

__device__ __forceinline__ float relu_f(float v) { return fmaxf(v, 0.0f); }

// ---------------- histogram ----------------
__global__ void hist_kernel(const int* __restrict__ idx, int n, int* __restrict__ counts) {
  int i = blockIdx.x * blockDim.x + threadIdx.x;
  if (i < n) atomicAdd(&counts[idx[i]], 1);
}

// ---------------- scans (exclusive prefix over counts) ----------------
__global__ void scan_block_kernel(const int* __restrict__ in, int n,
                                  int* __restrict__ out_excl, int* __restrict__ bsums) {
  __shared__ int s[256];
  int t = threadIdx.x;
  int i = blockIdx.x * 256 + t;
  int v = (i < n) ? in[i] : 0;
  s[t] = v;
  __syncthreads();
  for (int off = 1; off < 256; off <<= 1) {
    int x = (t >= off) ? s[t - off] : 0;
    __syncthreads();
    s[t] += x;
    __syncthreads();
  }
  if (i < n) out_excl[i] = s[t] - v;
  if (t == 255) bsums[blockIdx.x] = s[255];
}

__global__ void scan_top_kernel(int* __restrict__ bsums, int nb) {
  __shared__ int s[1024];
  int t = threadIdx.x;
  int v = (t < nb) ? bsums[t] : 0;
  s[t] = v;
  __syncthreads();
  for (int off = 1; off < 1024; off <<= 1) {
    int x = (t >= off) ? s[t - off] : 0;
    __syncthreads();
    s[t] += x;
    __syncthreads();
  }
  if (t < nb) bsums[t] = s[t] - v;
  if (t == 1023) bsums[nb] = s[1023];  // total
}

__global__ void scan_add_kernel(int* __restrict__ arr, const int* __restrict__ bsums,
                                int n, int* __restrict__ nextcopy) {
  int i = blockIdx.x * 256 + threadIdx.x;
  if (i < n) {
    int v = arr[i] + bsums[blockIdx.x];
    arr[i] = v;
    if (nextcopy) nextcopy[i] = v;
  }
  if (i == 0) arr[n] = bsums[gridDim.x];
}

// scatter: also emit local row index (dst & 31) since gin blocks tile 32 rows
__global__ void scatter_kernel(const int* __restrict__ ei, int* __restrict__ nxt,
                               int* __restrict__ csr_src, unsigned char* __restrict__ csr_dstl) {
  int e = blockIdx.x * blockDim.x + threadIdx.x;
  if (e < NEDGES) {
    int s = ei[e];            // src row
    int d = ei[NEDGES + e];   // dst row
    int pos = atomicAdd(&nxt[d], 1);
    csr_src[pos] = s;
    csr_dstl[pos] = (unsigned char)(d & 31);
  }
}

// ---------------- fused GIN layer ----------------
// Phase 1a: self-term init. Phase 1b: edge-parallel gather (contiguous edge
// range per block, chunk per wave, independent loads -> pipelined; ds_add_f32
// accumulate). Then mm1/mm2 on 4x4 register tiles with single time-multiplexed
// LDS buffer (18.4 KB -> 8 blocks/CU).
template<int DIN, bool XF>
__global__ __launch_bounds__(256, 8) void gin_kernel(
    const float* __restrict__ X,
    const int* __restrict__ row_ptr, const int* __restrict__ csr_src,
    const unsigned char* __restrict__ csr_dstl,
    const float* __restrict__ W1, const float* __restrict__ b1,
    const float* __restrict__ W2, const float* __restrict__ b2,
    const float* __restrict__ scale, const float* __restrict__ shift,
    float* __restrict__ O, float* __restrict__ bn_sum, float* __restrict__ bn_sq) {
  constexpr int R = 32, STR = R + 4;   // pad 36: 16B-aligned b128 reads
  constexpr int KMAX = (DIN > HIDDEN) ? DIN : HIDDEN;
  __shared__ __align__(16) float buf[KMAX * STR];   // xT, then mT, then reduction
  const int t = threadIdx.x;
  const int wv = t >> 6, lane = t & 63;
  const int base = blockIdx.x * R;

  const int fp = 2 * lane;     // feature pair for aggregation
  float sc0 = 1.f, sh0 = 0.f, sc1 = 1.f, sh1 = 0.f;
  if (XF && fp < DIN) { sc0 = scale[fp]; sh0 = shift[fp]; sc1 = scale[fp + 1]; sh1 = shift[fp + 1]; }

  // ---- phase 1a: self term -> buf (transposed)
  if (fp < DIN) {
    for (int rr = 0; rr < 8; ++rr) {
      const int r = wv * 8 + rr;
      const float2 s = *(const float2*)&X[(long)(base + r) * DIN + fp];
      float a0 = XF ? relu_f(fmaf(s.x, sc0, sh0)) : s.x;
      float a1 = XF ? relu_f(fmaf(s.y, sc1, sh1)) : s.y;
      buf[fp * STR + r] = a0;
      buf[(fp + 1) * STR + r] = a1;
    }
  }
  __syncthreads();

  // ---- phase 1b: edge-parallel gather, ds_add_f32 accumulate
  if (fp < DIN) {
    const int E0 = row_ptr[base], E1 = row_ptr[base + R];
    const int cnt = E1 - E0;
    const int chunk = (cnt + 3) >> 2;
    int e = E0 + wv * chunk;
    const int ee = min(E1, e + chunk);
    for (; e + 2 <= ee; e += 2) {
      const int sa = csr_src[e];
      const int sb = csr_src[e + 1];
      const int da = csr_dstl[e];
      const int db = csr_dstl[e + 1];
      const float2 u = *(const float2*)&X[(long)sa * DIN + fp];
      const float2 v = *(const float2*)&X[(long)sb * DIN + fp];
      float u0 = XF ? relu_f(fmaf(u.x, sc0, sh0)) : u.x;
      float u1 = XF ? relu_f(fmaf(u.y, sc1, sh1)) : u.y;
      float v0 = XF ? relu_f(fmaf(v.x, sc0, sh0)) : v.x;
      float v1 = XF ? relu_f(fmaf(v.y, sc1, sh1)) : v.y;
      atomicAdd(&buf[fp * STR + da], u0);
      atomicAdd(&buf[(fp + 1) * STR + da], u1);
      atomicAdd(&buf[fp * STR + db], v0);
      atomicAdd(&buf[(fp + 1) * STR + db], v1);
    }
    if (e < ee) {
      const int sa = csr_src[e];
      const int da = csr_dstl[e];
      const float2 u = *(const float2*)&X[(long)sa * DIN + fp];
      float u0 = XF ? relu_f(fmaf(u.x, sc0, sh0)) : u.x;
      float u1 = XF ? relu_f(fmaf(u.y, sc1, sh1)) : u.y;
      atomicAdd(&buf[fp * STR + da], u0);
      atomicAdd(&buf[(fp + 1) * STR + da], u1);
    }
  }
  __syncthreads();

  const int rg = t >> 5, cg = t & 31;     // 8 row-groups x 32 col-groups
  const int r0 = rg * 4, j0 = cg * 4;     // 4x4 tile per thread

  // ---- mm1: acc = h @ W1 + b1 (keep in regs; buf still holds xT)
  float acc[4][4];
  {
    const float4 bb = *(const float4*)&b1[j0];
    for (int r = 0; r < 4; ++r) { acc[r][0]=bb.x; acc[r][1]=bb.y; acc[r][2]=bb.z; acc[r][3]=bb.w; }
    for (int k = 0; k < DIN; ++k) {
      const float4 w = *(const float4*)&W1[k * HIDDEN + j0];
      const float4 x = *(const float4*)&buf[k * STR + r0];
      const float xa[4] = {x.x, x.y, x.z, x.w};
      const float wa[4] = {w.x, w.y, w.z, w.w};
      for (int r = 0; r < 4; ++r)
        for (int c = 0; c < 4; ++c)
          acc[r][c] = fmaf(xa[r], wa[c], acc[r][c]);
    }
  }
  __syncthreads();   // all xT reads done -> buf reusable as mT

  // ---- write mid = relu(acc) transposed into buf
  for (int c = 0; c < 4; ++c) {
    float4 m = { relu_f(acc[0][c]), relu_f(acc[1][c]), relu_f(acc[2][c]), relu_f(acc[3][c]) };
    *(float4*)&buf[(j0 + c) * STR + r0] = m;
  }
  __syncthreads();

  // ---- mm2: o = mid @ W2 + b2; store pre-BN + BN partials
  float csum[4] = {0,0,0,0}, csq[4] = {0,0,0,0};
  {
    const float4 bb = *(const float4*)&b2[j0];
    for (int r = 0; r < 4; ++r) { acc[r][0]=bb.x; acc[r][1]=bb.y; acc[r][2]=bb.z; acc[r][3]=bb.w; }
    for (int k = 0; k < HIDDEN; ++k) {
      const float4 w = *(const float4*)&W2[k * HIDDEN + j0];
      const float4 x = *(const float4*)&buf[k * STR + r0];
      const float xa[4] = {x.x, x.y, x.z, x.w};
      const float wa[4] = {w.x, w.y, w.z, w.w};
      for (int r = 0; r < 4; ++r)
        for (int c = 0; c < 4; ++c)
          acc[r][c] = fmaf(xa[r], wa[c], acc[r][c]);
    }
    for (int r = 0; r < 4; ++r) {
      float4 o = { acc[r][0], acc[r][1], acc[r][2], acc[r][3] };
      *(float4*)&O[(long)(base + r0 + r) * HIDDEN + j0] = o;
      for (int c = 0; c < 4; ++c) {
        csum[c] += acc[r][c];
        csq[c] = fmaf(acc[r][c], acc[r][c], csq[c]);
      }
    }
  }
  __syncthreads();  // all mm2 reads done -> buf reusable as reduction scratch
  for (int c = 0; c < 4; ++c) {
    buf[(j0 + c) * 8 + rg] = csum[c];
    buf[1024 + (j0 + c) * 8 + rg] = csq[c];
  }
  __syncthreads();
  if (t < HIDDEN) {
    float s = 0.f, q = 0.f;
    for (int g = 0; g < 8; ++g) { s += buf[t * 8 + g]; q += buf[1024 + t * 8 + g]; }
    atomicAdd(&bn_sum[t], s);
    atomicAdd(&bn_sq[t], q);
  }
}

__global__ void bn_finalize_kernel(const float* __restrict__ bn_sum, const float* __restrict__ bn_sq,
                                   const float* __restrict__ g, const float* __restrict__ b,
                                   float* __restrict__ scale, float* __restrict__ shift) {
  int j = threadIdx.x;
  float mu  = bn_sum[j] * (1.0f / NNODES);
  float var = fmaxf(bn_sq[j] * (1.0f / NNODES) - mu * mu, 0.0f);
  float sc  = g[j] / sqrtf(var + 1e-5f);
  scale[j] = sc;
  shift[j] = b[j] - mu * sc;
}

// ---------------- global add pool (with final BN+relu fold) ----------------
__global__ __launch_bounds__(256) void pool_kernel(const float* __restrict__ O,
    const int* __restrict__ gp, const float* __restrict__ scale, const float* __restrict__ shift,
    float* __restrict__ P) {
  int t = threadIdx.x;
  int g = blockIdx.x * 4 + (t >> 6);
  int lane = t & 63;
  int f0 = lane, f1 = lane + 64;
  float sc0 = scale[f0], sh0 = shift[f0], sc1 = scale[f1], sh1 = shift[f1];
  int n0 = gp[g], n1 = gp[g + 1];
  float a0 = 0.f, a1 = 0.f;
  for (int n = n0; n < n1; ++n) {
    a0 += relu_f(fmaf(O[(long)n * HIDDEN + f0], sc0, sh0));
    a1 += relu_f(fmaf(O[(long)n * HIDDEN + f1], sc1, sh1));
  }
  P[g * HIDDEN + f0] = a0;
  P[g * HIDDEN + f1] = a1;
}

// ---------------- protein conv1d(1->32,k=8) + relu + global max ----------------
__global__ __launch_bounds__(256) void conv_kernel(const float* __restrict__ PS,
    const float* __restrict__ CK, const float* __restrict__ CB, float* __restrict__ XP) {
  __shared__ float seq[1000];
  const int t = threadIdx.x, g = blockIdx.x;
  for (int i = t; i < 1000; i += 256) seq[i] = PS[g * 1000 + i];
  __syncthreads();
  const int pl = t & 31, cgp = t >> 5;   // 32 position lanes x 8 channel-groups(4 ch)
  float kr[4][8];
  for (int cc = 0; cc < 4; ++cc)
    for (int k = 0; k < 8; ++k) kr[cc][k] = CK[(cgp * 4 + cc) * 8 + k];
  float m[4] = {-1e30f, -1e30f, -1e30f, -1e30f};
  for (int i = 0; i < 32; ++i) {
    int p = pl + 32 * i;
    if (p < 993) {
      float sv[8];
      for (int k = 0; k < 8; ++k) sv[k] = seq[p + k];
      for (int cc = 0; cc < 4; ++cc) {
        float s = 0.f;
        for (int k = 0; k < 8; ++k) s = fmaf(sv[k], kr[cc][k], s);
        m[cc] = fmaxf(m[cc], s);
      }
    }
  }
  for (int off = 16; off >= 1; off >>= 1)
    for (int cc = 0; cc < 4; ++cc) m[cc] = fmaxf(m[cc], __shfl_xor(m[cc], off));
  if (pl == 0)
    for (int cc = 0; cc < 4; ++cc)
      XP[g * 32 + cgp * 4 + cc] = relu_f(m[cc] + CB[cgp * 4 + cc]);
}

// ---------------- tail gemm: C = relu(A@W + b), 16 rows x 64 cols per block ----------------
template<bool RELU_A>
__global__ __launch_bounds__(256) void gemm2_kernel(const float* __restrict__ A, int lda, int K,
    const float* __restrict__ W, int ldw, const float* __restrict__ bias,
    float* __restrict__ C, int ldc, int coff) {
  constexpr int RT = 16, CH = 64, STR = RT + 4;
  __shared__ __align__(16) float AT[CH * STR];
  const int t = threadIdx.x;
  const int rg = t >> 6, cg = t & 63;
  const int r0 = rg * 4;
  const int row0 = blockIdx.x * RT;
  const int col = blockIdx.y * 64 + cg;
  float a0 = 0.f, a1 = 0.f, a2 = 0.f, a3 = 0.f;
  for (int k0 = 0; k0 < K; k0 += CH) {
    const int kc = min(CH, K - k0);
    __syncthreads();
    for (int i = t; i < RT * CH; i += 256) {
      int kk = i & (CH - 1), r = i >> 6;
      if (kk < kc) {
        float v = A[(long)(row0 + r) * lda + k0 + kk];
        AT[kk * STR + r] = RELU_A ? relu_f(v) : v;
      }
    }
    __syncthreads();
    for (int kk = 0; kk < kc; ++kk) {
      const float4 x = *(const float4*)&AT[kk * STR + r0];
      const float w = W[(long)(k0 + kk) * ldw + col];
      a0 = fmaf(x.x, w, a0);
      a1 = fmaf(x.y, w, a1);
      a2 = fmaf(x.z, w, a2);
      a3 = fmaf(x.w, w, a3);
    }
  }
  const float bv = bias[col];
  C[(long)(row0 + r0 + 0) * ldc + coff + col] = relu_f(a0 + bv);
  C[(long)(row0 + r0 + 1) * ldc + coff + col] = relu_f(a1 + bv);
  C[(long)(row0 + r0 + 2) * ldc + coff + col] = relu_f(a2 + bv);
  C[(long)(row0 + r0 + 3) * ldc + coff + col] = relu_f(a3 + bv);
}

// ---------------- a2h branch: XA init with bias ----------------
__global__ __launch_bounds__(256) void bias_fill_kernel(const float* __restrict__ b,
                                                        float* __restrict__ XA) {
  int i = blockIdx.x * 256 + threadIdx.x;
  XA[i] = b[i & (HIDDEN - 1)];
}

// ---------------- a2h branch split-K gemm: XA += A@W (atomic), pre-relu ----------------
constexpr int A2H_K = 3000, A2H_SPLIT = 300, A2H_NSPLIT = 10;
__global__ __launch_bounds__(128) void a2h_gemm_kernel(const float* __restrict__ A,
    const float* __restrict__ W, float* __restrict__ XA) {
  constexpr int RT = 16, STR = RT + 4;   // LDS tile [300][20]
  __shared__ __align__(16) float xT[A2H_SPLIT * STR];  // 24 KB
  const int t = threadIdx.x;
  const int row0 = blockIdx.x * RT;
  const int k0 = blockIdx.y * A2H_SPLIT;

  constexpr int Q = A2H_SPLIT / 4;       // 75 float4 per row
  for (int i = t; i < RT * Q; i += 128) {
    const int r = i / Q, kq = i - r * Q;
    const float4 v = *(const float4*)&A[(long)(row0 + r) * A2H_K + k0 + kq * 4];
    xT[(kq * 4 + 0) * STR + r] = v.x;
    xT[(kq * 4 + 1) * STR + r] = v.y;
    xT[(kq * 4 + 2) * STR + r] = v.z;
    xT[(kq * 4 + 3) * STR + r] = v.w;
  }
  __syncthreads();

  const int rg = t >> 5, cg = t & 31;    // 4 row-groups x 32 col-groups
  const int r0 = rg * 4, j0 = cg * 4;
  float acc[4][4];
  for (int r = 0; r < 4; ++r)
    for (int c = 0; c < 4; ++c) acc[r][c] = 0.f;

  const float* Wp = W + (long)k0 * HIDDEN + j0;
  for (int k = 0; k < A2H_SPLIT; ++k) {
    const float4 w = *(const float4*)&Wp[(long)k * HIDDEN];
    const float4 x = *(const float4*)&xT[k * STR + r0];
    const float xa[4] = {x.x, x.y, x.z, x.w};
    const float wa[4] = {w.x, w.y, w.z, w.w};
    for (int r = 0; r < 4; ++r)
      for (int c = 0; c < 4; ++c)
        acc[r][c] = fmaf(xa[r], wa[c], acc[r][c]);
  }
  for (int r = 0; r < 4; ++r)
    for (int c = 0; c < 4; ++c)
      atomicAdd(&XA[(long)(row0 + r0 + r) * HIDDEN + j0 + c], acc[r][c]);
}

// ---------------- final projection to scalar ----------------
__global__ __launch_bounds__(256) void final_dot_kernel(const float* __restrict__ X,
    const float* __restrict__ Wo, const float* __restrict__ bo, float* __restrict__ out) {
  int t = threadIdx.x;
  int g = blockIdx.x * 4 + (t >> 6);
  int lane = t & 63;
  float2 x = *(const float2*)&X[g * HIDDEN + lane * 2];
  float2 w = *(const float2*)&Wo[lane * 2];
  float p = x.x * w.x + x.y * w.y;
  for (int off = 32; off >= 1; off >>= 1) p += __shfl_down(p, off);
  if (lane == 0) out[g] = p + bo[0];
}

extern "C" void kernel_launch(void* const* d_in, const int* in_sizes, int n_in,
                              void* d_out, int out_size, void* d_ws, size_t ws_size,
                              hipStream_t stream) {
  const float* x_lig = (const float*)d_in[0];
  const float* pseq  = (const float*)d_in[1];
  const float* a2h   = (const float*)d_in[2];
  const int*   ei    = (const int*)d_in[3];
  const int*   batch = (const int*)d_in[4];
  const float* ginW1[3] = {(const float*)d_in[5],  (const float*)d_in[11], (const float*)d_in[17]};
  const float* ginb1[3] = {(const float*)d_in[6],  (const float*)d_in[12], (const float*)d_in[18]};
  const float* ginW2[3] = {(const float*)d_in[7],  (const float*)d_in[13], (const float*)d_in[19]};
  const float* ginb2[3] = {(const float*)d_in[8],  (const float*)d_in[14], (const float*)d_in[20]};
  const float* bng[3]   = {(const float*)d_in[9],  (const float*)d_in[15], (const float*)d_in[21]};
  const float* bnb[3]   = {(const float*)d_in[10], (const float*)d_in[16], (const float*)d_in[22]};
  const float* ligW  = (const float*)d_in[23]; const float* ligb  = (const float*)d_in[24];
  const float* convk = (const float*)d_in[25]; const float* convb = (const float*)d_in[26];
  const float* protW = (const float*)d_in[27]; const float* protb = (const float*)d_in[28];
  const float* a1W   = (const float*)d_in[29]; const float* a1b   = (const float*)d_in[30];
  const float* a2W   = (const float*)d_in[31]; const float* a2b   = (const float*)d_in[32];
  const float* c1W   = (const float*)d_in[33]; const float* c1b   = (const float*)d_in[34];
  const float* c2W   = (const float*)d_in[35]; const float* c2b   = (const float*)d_in[36];
  const float* oW    = (const float*)d_in[37]; const float* ob    = (const float*)d_in[38];

  char* base = (char*)d_ws;
  size_t off = 0;
  auto alloc = [&](size_t bytes) -> char* {
    char* p = base + off;
    off = (off + bytes + 511) & ~size_t(511);
    return p;
  };
  int*   counts  = (int*)alloc(NNODES * 4);
  int*   gcounts = (int*)alloc(NGRAPHS * 4);
  float* bn_sum  = (float*)alloc(3 * 128 * 4);
  float* bn_sq   = (float*)alloc(3 * 128 * 4);
  const size_t zero_bytes = off;          // counts+gcounts+bn accumulators
  float* bn_scale = (float*)alloc(3 * 128 * 4);
  float* bn_shift = (float*)alloc(3 * 128 * 4);
  int*   row_ptr  = (int*)alloc((NNODES + 1) * 4);
  int*   nxt      = (int*)alloc(NNODES * 4);
  int*   gptr     = (int*)alloc((NGRAPHS + 1) * 4);
  int*   bsumsA   = (int*)alloc(401 * 4);
  int*   bsumsB   = (int*)alloc(9 * 4);
  int*   csr_src  = (int*)alloc(NEDGES * 4);
  unsigned char* csr_dstl = (unsigned char*)alloc(NEDGES);
  float* P        = (float*)alloc(NGRAPHS * 128 * 4);
  float* XA       = (float*)alloc(NGRAPHS * 128 * 4);
  float* XP32     = (float*)alloc(NGRAPHS * 32 * 4);
  float* XC       = (float*)alloc(NGRAPHS * 384 * 4);
  float* XC2      = (float*)alloc(NGRAPHS * 256 * 4);
  float* XC3      = (float*)alloc(NGRAPHS * 128 * 4);
  float* O0       = (float*)alloc((size_t)NNODES * 128 * 4);
  float* O1       = (float*)alloc((size_t)NNODES * 128 * 4);
  (void)ws_size; (void)in_sizes; (void)n_in; (void)out_size;

  hipMemsetAsync(d_ws, 0, zero_bytes, stream);

  // CSR over dst + graph segment ptrs
  hist_kernel<<<(NEDGES + 255) / 256, 256, 0, stream>>>(ei + NEDGES, NEDGES, counts);
  hist_kernel<<<(NNODES + 255) / 256, 256, 0, stream>>>(batch, NNODES, gcounts);
  scan_block_kernel<<<NNODES / 256, 256, 0, stream>>>(counts, NNODES, row_ptr, bsumsA);
  scan_block_kernel<<<NGRAPHS / 256, 256, 0, stream>>>(gcounts, NGRAPHS, gptr, bsumsB);
  scan_top_kernel<<<1, 1024, 0, stream>>>(bsumsA, NNODES / 256);
  scan_top_kernel<<<1, 1024, 0, stream>>>(bsumsB, NGRAPHS / 256);
  scan_add_kernel<<<NNODES / 256, 256, 0, stream>>>(row_ptr, bsumsA, NNODES, nxt);
  scan_add_kernel<<<NGRAPHS / 256, 256, 0, stream>>>(gptr, bsumsB, NGRAPHS, nullptr);
  scatter_kernel<<<(NEDGES + 255) / 256, 256, 0, stream>>>(ei, nxt, csr_src, csr_dstl);

  // a2h branch early (independent): bias fill + split-K atomic gemm
  bias_fill_kernel<<<NGRAPHS * HIDDEN / 256, 256, 0, stream>>>(a1b, XA);
  a2h_gemm_kernel<<<dim3(NGRAPHS / 16, A2H_NSPLIT), 128, 0, stream>>>(a2h, a1W, XA);

  // GIN layers (BN+relu of layer l folded into consumer of layer l)
  gin_kernel<78, false><<<NNODES / 32, 256, 0, stream>>>(x_lig, row_ptr, csr_src, csr_dstl,
      ginW1[0], ginb1[0], ginW2[0], ginb2[0], nullptr, nullptr, O0, bn_sum, bn_sq);
  bn_finalize_kernel<<<1, 128, 0, stream>>>(bn_sum, bn_sq, bng[0], bnb[0], bn_scale, bn_shift);
  gin_kernel<128, true><<<NNODES / 32, 256, 0, stream>>>(O0, row_ptr, csr_src, csr_dstl,
      ginW1[1], ginb1[1], ginW2[1], ginb2[1], bn_scale, bn_shift, O1, bn_sum + 128, bn_sq + 128);
  bn_finalize_kernel<<<1, 128, 0, stream>>>(bn_sum + 128, bn_sq + 128, bng[1], bnb[1],
                                            bn_scale + 128, bn_shift + 128);
  gin_kernel<128, true><<<NNODES / 32, 256, 0, stream>>>(O1, row_ptr, csr_src, csr_dstl,
      ginW1[2], ginb1[2], ginW2[2], ginb2[2], bn_scale + 128, bn_shift + 128, O0,
      bn_sum + 256, bn_sq + 256);
  bn_finalize_kernel<<<1, 128, 0, stream>>>(bn_sum + 256, bn_sq + 256, bng[2], bnb[2],
                                            bn_scale + 256, bn_shift + 256);

  // branches
  pool_kernel<<<NGRAPHS / 4, 256, 0, stream>>>(O0, gptr, bn_scale + 256, bn_shift + 256, P);
  conv_kernel<<<NGRAPHS, 256, 0, stream>>>(pseq, convk, convb, XP32);
  gemm2_kernel<false><<<dim3(NGRAPHS / 16, 2), 256, 0, stream>>>(P, 128, 128, ligW, 128, ligb, XC, 384, 0);
  gemm2_kernel<false><<<dim3(NGRAPHS / 16, 2), 256, 0, stream>>>(XP32, 32, 32, protW, 128, protb, XC, 384, 128);
  gemm2_kernel<true><<<dim3(NGRAPHS / 16, 2), 256, 0, stream>>>(XA, 128, 128, a2W, 128, a2b, XC, 384, 256);

  // head
  gemm2_kernel<false><<<dim3(NGRAPHS / 16, 4), 256, 0, stream>>>(XC, 384, 384, c1W, 256, c1b, XC2, 256, 0);
  gemm2_kernel<false><<<dim3(NGRAPHS / 16, 2), 256, 0, stream>>>(XC2, 256, 256, c2W, 128, c2b, XC3, 128, 0);
  final_dot_kernel<<<NGRAPHS / 4, 256, 0, stream>>>(XC3, oW, ob, (float*)d_out);
}

// Round 6
// 1121.045 us; speedup vs baseline: 1.2370x; 1.2370x over previous
//
#include <hip/hip_runtime.h>
#include <math.h>

constexpr int NNODES  = 102400;
constexpr int NEDGES  = 409600;
constexpr int NGRAPHS = 2048;
constexpr int HIDDEN  = 128;

__device__ __forceinline__ float relu_f(float v) { return fmaxf(v, 0.0f); }

// ---------------- histogram ----------------
__global__ void hist_kernel(const int* __restrict__ idx, int n, int* __restrict__ counts) {
  int i = blockIdx.x * blockDim.x + threadIdx.x;
  if (i < n) atomicAdd(&counts[idx[i]], 1);
}

// ---------------- scans (exclusive prefix over counts) ----------------
__global__ void scan_block_kernel(const int* __restrict__ in, int n,
                                  int* __restrict__ out_excl, int* __restrict__ bsums) {
  __shared__ int s[256];
  int t = threadIdx.x;
  int i = blockIdx.x * 256 + t;
  int v = (i < n) ? in[i] : 0;
  s[t] = v;
  __syncthreads();
  for (int off = 1; off < 256; off <<= 1) {
    int x = (t >= off) ? s[t - off] : 0;
    __syncthreads();
    s[t] += x;
    __syncthreads();
  }
  if (i < n) out_excl[i] = s[t] - v;
  if (t == 255) bsums[blockIdx.x] = s[255];
}

__global__ void scan_top_kernel(int* __restrict__ bsums, int nb) {
  __shared__ int s[1024];
  int t = threadIdx.x;
  int v = (t < nb) ? bsums[t] : 0;
  s[t] = v;
  __syncthreads();
  for (int off = 1; off < 1024; off <<= 1) {
    int x = (t >= off) ? s[t - off] : 0;
    __syncthreads();
    s[t] += x;
    __syncthreads();
  }
  if (t < nb) bsums[t] = s[t] - v;
  if (t == 1023) bsums[nb] = s[1023];  // total
}

__global__ void scan_add_kernel(int* __restrict__ arr, const int* __restrict__ bsums,
                                int n, int* __restrict__ nextcopy) {
  int i = blockIdx.x * 256 + threadIdx.x;
  if (i < n) {
    int v = arr[i] + bsums[blockIdx.x];
    arr[i] = v;
    if (nextcopy) nextcopy[i] = v;
  }
  if (i == 0) arr[n] = bsums[gridDim.x];
}

__global__ void scatter_kernel(const int* __restrict__ ei, int* __restrict__ nxt,
                               int* __restrict__ csr_src) {
  int e = blockIdx.x * blockDim.x + threadIdx.x;
  if (e < NEDGES) {
    int s = ei[e];            // src row
    int d = ei[NEDGES + e];   // dst row
    int pos = atomicAdd(&nxt[d], 1);
    csr_src[pos] = s;
  }
}

// ---------------- fused GIN layer ----------------
// Gather: 8 rows/wave jammed into one software-pipelined loop -> up to 8
// independent X-row loads in flight per wave (register accumulation, no LDS
// atomics). Then mm1/mm2 on 4x4 register tiles, single time-multiplexed LDS
// buffer (18.4 KB -> 8 blocks/CU).
template<int DIN, bool XF>
__global__ __launch_bounds__(256, 8) void gin_kernel(
    const float* __restrict__ X,
    const int* __restrict__ row_ptr, const int* __restrict__ csr_src,
    const float* __restrict__ W1, const float* __restrict__ b1,
    const float* __restrict__ W2, const float* __restrict__ b2,
    const float* __restrict__ scale, const float* __restrict__ shift,
    float* __restrict__ O, float* __restrict__ bn_sum, float* __restrict__ bn_sq) {
  constexpr int R = 32, STR = R + 4;   // pad 36: 16B-aligned b128 reads
  constexpr int KMAX = (DIN > HIDDEN) ? DIN : HIDDEN;
  __shared__ __align__(16) float buf[KMAX * STR];   // xT, then mT, then reduction
  const int t = threadIdx.x;
  const int wv = t >> 6, lane = t & 63;
  const int base = blockIdx.x * R;

  const int fp = 2 * lane;     // feature pair for aggregation
  if (fp < DIN) {
    float sc0 = 1.f, sh0 = 0.f, sc1 = 1.f, sh1 = 0.f;
    if (XF) { sc0 = scale[fp]; sh0 = shift[fp]; sc1 = scale[fp + 1]; sh1 = shift[fp + 1]; }

    float a0[8], a1[8];
    int ecur[8], eend[8], idx[8];
#pragma unroll
    for (int r = 0; r < 8; ++r) {
      const int node = base + wv * 8 + r;
      ecur[r] = row_ptr[node];
      eend[r] = row_ptr[node + 1];
      const float2 s = *(const float2*)&X[(long)node * DIN + fp];
      a0[r] = XF ? relu_f(fmaf(s.x, sc0, sh0)) : s.x;
      a1[r] = XF ? relu_f(fmaf(s.y, sc1, sh1)) : s.y;
      idx[r] = (ecur[r] < eend[r]) ? csr_src[ecur[r]] : 0;
    }
    bool any = false;
#pragma unroll
    for (int r = 0; r < 8; ++r) any = any || (ecur[r] < eend[r]);
    while (any) {
      any = false;
      bool act[8];
      float2 u[8];
      // pass 1: issue all independent row loads
#pragma unroll
      for (int r = 0; r < 8; ++r) {
        act[r] = (ecur[r] < eend[r]);
        if (act[r]) u[r] = *(const float2*)&X[(long)idx[r] * DIN + fp];
      }
      // pass 2: advance + prefetch next index + accumulate
#pragma unroll
      for (int r = 0; r < 8; ++r) {
        if (act[r]) {
          ++ecur[r];
          if (ecur[r] < eend[r]) { idx[r] = csr_src[ecur[r]]; any = true; }
          a0[r] += XF ? relu_f(fmaf(u[r].x, sc0, sh0)) : u[r].x;
          a1[r] += XF ? relu_f(fmaf(u[r].y, sc1, sh1)) : u[r].y;
        }
      }
    }
#pragma unroll
    for (int r = 0; r < 8; ++r) {
      buf[fp * STR + wv * 8 + r] = a0[r];
      buf[(fp + 1) * STR + wv * 8 + r] = a1[r];
    }
  }
  __syncthreads();

  const int rg = t >> 5, cg = t & 31;     // 8 row-groups x 32 col-groups
  const int r0 = rg * 4, j0 = cg * 4;     // 4x4 tile per thread

  // ---- mm1: acc = h @ W1 + b1 (keep in regs; buf still holds xT)
  float acc[4][4];
  {
    const float4 bb = *(const float4*)&b1[j0];
    for (int r = 0; r < 4; ++r) { acc[r][0]=bb.x; acc[r][1]=bb.y; acc[r][2]=bb.z; acc[r][3]=bb.w; }
    for (int k = 0; k < DIN; ++k) {
      const float4 w = *(const float4*)&W1[k * HIDDEN + j0];
      const float4 x = *(const float4*)&buf[k * STR + r0];
      const float xa[4] = {x.x, x.y, x.z, x.w};
      const float wa[4] = {w.x, w.y, w.z, w.w};
      for (int r = 0; r < 4; ++r)
        for (int c = 0; c < 4; ++c)
          acc[r][c] = fmaf(xa[r], wa[c], acc[r][c]);
    }
  }
  __syncthreads();   // all xT reads done -> buf reusable as mT

  // ---- write mid = relu(acc) transposed into buf
  for (int c = 0; c < 4; ++c) {
    float4 m = { relu_f(acc[0][c]), relu_f(acc[1][c]), relu_f(acc[2][c]), relu_f(acc[3][c]) };
    *(float4*)&buf[(j0 + c) * STR + r0] = m;
  }
  __syncthreads();

  // ---- mm2: o = mid @ W2 + b2; store pre-BN + BN partials
  float csum[4] = {0,0,0,0}, csq[4] = {0,0,0,0};
  {
    const float4 bb = *(const float4*)&b2[j0];
    for (int r = 0; r < 4; ++r) { acc[r][0]=bb.x; acc[r][1]=bb.y; acc[r][2]=bb.z; acc[r][3]=bb.w; }
    for (int k = 0; k < HIDDEN; ++k) {
      const float4 w = *(const float4*)&W2[k * HIDDEN + j0];
      const float4 x = *(const float4*)&buf[k * STR + r0];
      const float xa[4] = {x.x, x.y, x.z, x.w};
      const float wa[4] = {w.x, w.y, w.z, w.w};
      for (int r = 0; r < 4; ++r)
        for (int c = 0; c < 4; ++c)
          acc[r][c] = fmaf(xa[r], wa[c], acc[r][c]);
    }
    for (int r = 0; r < 4; ++r) {
      float4 o = { acc[r][0], acc[r][1], acc[r][2], acc[r][3] };
      *(float4*)&O[(long)(base + r0 + r) * HIDDEN + j0] = o;
      for (int c = 0; c < 4; ++c) {
        csum[c] += acc[r][c];
        csq[c] = fmaf(acc[r][c], acc[r][c], csq[c]);
      }
    }
  }
  __syncthreads();  // all mm2 reads done -> buf reusable as reduction scratch
  for (int c = 0; c < 4; ++c) {
    buf[(j0 + c) * 8 + rg] = csum[c];
    buf[1024 + (j0 + c) * 8 + rg] = csq[c];
  }
  __syncthreads();
  if (t < HIDDEN) {
    float s = 0.f, q = 0.f;
    for (int g = 0; g < 8; ++g) { s += buf[t * 8 + g]; q += buf[1024 + t * 8 + g]; }
    atomicAdd(&bn_sum[t], s);
    atomicAdd(&bn_sq[t], q);
  }
}

__global__ void bn_finalize_kernel(const float* __restrict__ bn_sum, const float* __restrict__ bn_sq,
                                   const float* __restrict__ g, const float* __restrict__ b,
                                   float* __restrict__ scale, float* __restrict__ shift) {
  int j = threadIdx.x;
  float mu  = bn_sum[j] * (1.0f / NNODES);
  float var = fmaxf(bn_sq[j] * (1.0f / NNODES) - mu * mu, 0.0f);
  float sc  = g[j] / sqrtf(var + 1e-5f);
  scale[j] = sc;
  shift[j] = b[j] - mu * sc;
}

// ---------------- global add pool (with final BN+relu fold) ----------------
__global__ __launch_bounds__(256) void pool_kernel(const float* __restrict__ O,
    const int* __restrict__ gp, const float* __restrict__ scale, const float* __restrict__ shift,
    float* __restrict__ P) {
  int t = threadIdx.x;
  int g = blockIdx.x * 4 + (t >> 6);
  int lane = t & 63;
  int f0 = lane, f1 = lane + 64;
  float sc0 = scale[f0], sh0 = shift[f0], sc1 = scale[f1], sh1 = shift[f1];
  int n0 = gp[g], n1 = gp[g + 1];
  float a0 = 0.f, a1 = 0.f;
  for (int n = n0; n < n1; ++n) {
    a0 += relu_f(fmaf(O[(long)n * HIDDEN + f0], sc0, sh0));
    a1 += relu_f(fmaf(O[(long)n * HIDDEN + f1], sc1, sh1));
  }
  P[g * HIDDEN + f0] = a0;
  P[g * HIDDEN + f1] = a1;
}

// ---------------- protein conv1d(1->32,k=8) + relu + global max ----------------
__global__ __launch_bounds__(256) void conv_kernel(const float* __restrict__ PS,
    const float* __restrict__ CK, const float* __restrict__ CB, float* __restrict__ XP) {
  __shared__ float seq[1000];
  const int t = threadIdx.x, g = blockIdx.x;
  for (int i = t; i < 1000; i += 256) seq[i] = PS[g * 1000 + i];
  __syncthreads();
  const int pl = t & 31, cgp = t >> 5;   // 32 position lanes x 8 channel-groups(4 ch)
  float kr[4][8];
  for (int cc = 0; cc < 4; ++cc)
    for (int k = 0; k < 8; ++k) kr[cc][k] = CK[(cgp * 4 + cc) * 8 + k];
  float m[4] = {-1e30f, -1e30f, -1e30f, -1e30f};
  for (int i = 0; i < 32; ++i) {
    int p = pl + 32 * i;
    if (p < 993) {
      float sv[8];
      for (int k = 0; k < 8; ++k) sv[k] = seq[p + k];
      for (int cc = 0; cc < 4; ++cc) {
        float s = 0.f;
        for (int k = 0; k < 8; ++k) s = fmaf(sv[k], kr[cc][k], s);
        m[cc] = fmaxf(m[cc], s);
      }
    }
  }
  for (int off = 16; off >= 1; off >>= 1)
    for (int cc = 0; cc < 4; ++cc) m[cc] = fmaxf(m[cc], __shfl_xor(m[cc], off));
  if (pl == 0)
    for (int cc = 0; cc < 4; ++cc)
      XP[g * 32 + cgp * 4 + cc] = relu_f(m[cc] + CB[cgp * 4 + cc]);
}

// ---------------- tail gemm: C = relu(A@W + b), 16 rows x 64 cols per block ----------------
template<bool RELU_A>
__global__ __launch_bounds__(256) void gemm2_kernel(const float* __restrict__ A, int lda, int K,
    const float* __restrict__ W, int ldw, const float* __restrict__ bias,
    float* __restrict__ C, int ldc, int coff) {
  constexpr int RT = 16, CH = 64, STR = RT + 4;
  __shared__ __align__(16) float AT[CH * STR];
  const int t = threadIdx.x;
  const int rg = t >> 6, cg = t & 63;
  const int r0 = rg * 4;
  const int row0 = blockIdx.x * RT;
  const int col = blockIdx.y * 64 + cg;
  float a0 = 0.f, a1 = 0.f, a2 = 0.f, a3 = 0.f;
  for (int k0 = 0; k0 < K; k0 += CH) {
    const int kc = min(CH, K - k0);
    __syncthreads();
    for (int i = t; i < RT * CH; i += 256) {
      int kk = i & (CH - 1), r = i >> 6;
      if (kk < kc) {
        float v = A[(long)(row0 + r) * lda + k0 + kk];
        AT[kk * STR + r] = RELU_A ? relu_f(v) : v;
      }
    }
    __syncthreads();
    for (int kk = 0; kk < kc; ++kk) {
      const float4 x = *(const float4*)&AT[kk * STR + r0];
      const float w = W[(long)(k0 + kk) * ldw + col];
      a0 = fmaf(x.x, w, a0);
      a1 = fmaf(x.y, w, a1);
      a2 = fmaf(x.z, w, a2);
      a3 = fmaf(x.w, w, a3);
    }
  }
  const float bv = bias[col];
  C[(long)(row0 + r0 + 0) * ldc + coff + col] = relu_f(a0 + bv);
  C[(long)(row0 + r0 + 1) * ldc + coff + col] = relu_f(a1 + bv);
  C[(long)(row0 + r0 + 2) * ldc + coff + col] = relu_f(a2 + bv);
  C[(long)(row0 + r0 + 3) * ldc + coff + col] = relu_f(a3 + bv);
}

// ---------------- a2h branch: XA init with bias ----------------
__global__ __launch_bounds__(256) void bias_fill_kernel(const float* __restrict__ b,
                                                        float* __restrict__ XA) {
  int i = blockIdx.x * 256 + threadIdx.x;
  XA[i] = b[i & (HIDDEN - 1)];
}

// ---------------- a2h branch split-K gemm: XA += A@W (atomic), pre-relu ----------------
constexpr int A2H_K = 3000, A2H_SPLIT = 300, A2H_NSPLIT = 10;
__global__ __launch_bounds__(128) void a2h_gemm_kernel(const float* __restrict__ A,
    const float* __restrict__ W, float* __restrict__ XA) {
  constexpr int RT = 16, STR = RT + 4;   // LDS tile [300][20]
  __shared__ __align__(16) float xT[A2H_SPLIT * STR];  // 24 KB
  const int t = threadIdx.x;
  const int row0 = blockIdx.x * RT;
  const int k0 = blockIdx.y * A2H_SPLIT;

  constexpr int Q = A2H_SPLIT / 4;       // 75 float4 per row
  for (int i = t; i < RT * Q; i += 128) {
    const int r = i / Q, kq = i - r * Q;
    const float4 v = *(const float4*)&A[(long)(row0 + r) * A2H_K + k0 + kq * 4];
    xT[(kq * 4 + 0) * STR + r] = v.x;
    xT[(kq * 4 + 1) * STR + r] = v.y;
    xT[(kq * 4 + 2) * STR + r] = v.z;
    xT[(kq * 4 + 3) * STR + r] = v.w;
  }
  __syncthreads();

  const int rg = t >> 5, cg = t & 31;    // 4 row-groups x 32 col-groups
  const int r0 = rg * 4, j0 = cg * 4;
  float acc[4][4];
  for (int r = 0; r < 4; ++r)
    for (int c = 0; c < 4; ++c) acc[r][c] = 0.f;

  const float* Wp = W + (long)k0 * HIDDEN + j0;
  for (int k = 0; k < A2H_SPLIT; ++k) {
    const float4 w = *(const float4*)&Wp[(long)k * HIDDEN];
    const float4 x = *(const float4*)&xT[k * STR + r0];
    const float xa[4] = {x.x, x.y, x.z, x.w};
    const float wa[4] = {w.x, w.y, w.z, w.w};
    for (int r = 0; r < 4; ++r)
      for (int c = 0; c < 4; ++c)
        acc[r][c] = fmaf(xa[r], wa[c], acc[r][c]);
  }
  for (int r = 0; r < 4; ++r)
    for (int c = 0; c < 4; ++c)
      atomicAdd(&XA[(long)(row0 + r0 + r) * HIDDEN + j0 + c], acc[r][c]);
}

// ---------------- final projection to scalar ----------------
__global__ __launch_bounds__(256) void final_dot_kernel(const float* __restrict__ X,
    const float* __restrict__ Wo, const float* __restrict__ bo, float* __restrict__ out) {
  int t = threadIdx.x;
  int g = blockIdx.x * 4 + (t >> 6);
  int lane = t & 63;
  float2 x = *(const float2*)&X[g * HIDDEN + lane * 2];
  float2 w = *(const float2*)&Wo[lane * 2];
  float p = x.x * w.x + x.y * w.y;
  for (int off = 32; off >= 1; off >>= 1) p += __shfl_down(p, off);
  if (lane == 0) out[g] = p + bo[0];
}

extern "C" void kernel_launch(void* const* d_in, const int* in_sizes, int n_in,
                              void* d_out, int out_size, void* d_ws, size_t ws_size,
                              hipStream_t stream) {
  const float* x_lig = (const float*)d_in[0];
  const float* pseq  = (const float*)d_in[1];
  const float* a2h   = (const float*)d_in[2];
  const int*   ei    = (const int*)d_in[3];
  const int*   batch = (const int*)d_in[4];
  const float* ginW1[3] = {(const float*)d_in[5],  (const float*)d_in[11], (const float*)d_in[17]};
  const float* ginb1[3] = {(const float*)d_in[6],  (const float*)d_in[12], (const float*)d_in[18]};
  const float* ginW2[3] = {(const float*)d_in[7],  (const float*)d_in[13], (const float*)d_in[19]};
  const float* ginb2[3] = {(const float*)d_in[8],  (const float*)d_in[14], (const float*)d_in[20]};
  const float* bng[3]   = {(const float*)d_in[9],  (const float*)d_in[15], (const float*)d_in[21]};
  const float* bnb[3]   = {(const float*)d_in[10], (const float*)d_in[16], (const float*)d_in[22]};
  const float* ligW  = (const float*)d_in[23]; const float* ligb  = (const float*)d_in[24];
  const float* convk = (const float*)d_in[25]; const float* convb = (const float*)d_in[26];
  const float* protW = (const float*)d_in[27]; const float* protb = (const float*)d_in[28];
  const float* a1W   = (const float*)d_in[29]; const float* a1b   = (const float*)d_in[30];
  const float* a2W   = (const float*)d_in[31]; const float* a2b   = (const float*)d_in[32];
  const float* c1W   = (const float*)d_in[33]; const float* c1b   = (const float*)d_in[34];
  const float* c2W   = (const float*)d_in[35]; const float* c2b   = (const float*)d_in[36];
  const float* oW    = (const float*)d_in[37]; const float* ob    = (const float*)d_in[38];

  char* base = (char*)d_ws;
  size_t off = 0;
  auto alloc = [&](size_t bytes) -> char* {
    char* p = base + off;
    off = (off + bytes + 511) & ~size_t(511);
    return p;
  };
  int*   counts  = (int*)alloc(NNODES * 4);
  int*   gcounts = (int*)alloc(NGRAPHS * 4);
  float* bn_sum  = (float*)alloc(3 * 128 * 4);
  float* bn_sq   = (float*)alloc(3 * 128 * 4);
  const size_t zero_bytes = off;          // counts+gcounts+bn accumulators
  float* bn_scale = (float*)alloc(3 * 128 * 4);
  float* bn_shift = (float*)alloc(3 * 128 * 4);
  int*   row_ptr  = (int*)alloc((NNODES + 1) * 4);
  int*   nxt      = (int*)alloc(NNODES * 4);
  int*   gptr     = (int*)alloc((NGRAPHS + 1) * 4);
  int*   bsumsA   = (int*)alloc(401 * 4);
  int*   bsumsB   = (int*)alloc(9 * 4);
  int*   csr_src  = (int*)alloc(NEDGES * 4);
  float* P        = (float*)alloc(NGRAPHS * 128 * 4);
  float* XA       = (float*)alloc(NGRAPHS * 128 * 4);
  float* XP32     = (float*)alloc(NGRAPHS * 32 * 4);
  float* XC       = (float*)alloc(NGRAPHS * 384 * 4);
  float* XC2      = (float*)alloc(NGRAPHS * 256 * 4);
  float* XC3      = (float*)alloc(NGRAPHS * 128 * 4);
  float* O0       = (float*)alloc((size_t)NNODES * 128 * 4);
  float* O1       = (float*)alloc((size_t)NNODES * 128 * 4);
  (void)ws_size; (void)in_sizes; (void)n_in; (void)out_size;

  hipMemsetAsync(d_ws, 0, zero_bytes, stream);

  // CSR over dst + graph segment ptrs
  hist_kernel<<<(NEDGES + 255) / 256, 256, 0, stream>>>(ei + NEDGES, NEDGES, counts);
  hist_kernel<<<(NNODES + 255) / 256, 256, 0, stream>>>(batch, NNODES, gcounts);
  scan_block_kernel<<<NNODES / 256, 256, 0, stream>>>(counts, NNODES, row_ptr, bsumsA);
  scan_block_kernel<<<NGRAPHS / 256, 256, 0, stream>>>(gcounts, NGRAPHS, gptr, bsumsB);
  scan_top_kernel<<<1, 1024, 0, stream>>>(bsumsA, NNODES / 256);
  scan_top_kernel<<<1, 1024, 0, stream>>>(bsumsB, NGRAPHS / 256);
  scan_add_kernel<<<NNODES / 256, 256, 0, stream>>>(row_ptr, bsumsA, NNODES, nxt);
  scan_add_kernel<<<NGRAPHS / 256, 256, 0, stream>>>(gptr, bsumsB, NGRAPHS, nullptr);
  scatter_kernel<<<(NEDGES + 255) / 256, 256, 0, stream>>>(ei, nxt, csr_src);

  // a2h branch early (independent): bias fill + split-K atomic gemm
  bias_fill_kernel<<<NGRAPHS * HIDDEN / 256, 256, 0, stream>>>(a1b, XA);
  a2h_gemm_kernel<<<dim3(NGRAPHS / 16, A2H_NSPLIT), 128, 0, stream>>>(a2h, a1W, XA);

  // GIN layers (BN+relu of layer l folded into consumer of layer l)
  gin_kernel<78, false><<<NNODES / 32, 256, 0, stream>>>(x_lig, row_ptr, csr_src,
      ginW1[0], ginb1[0], ginW2[0], ginb2[0], nullptr, nullptr, O0, bn_sum, bn_sq);
  bn_finalize_kernel<<<1, 128, 0, stream>>>(bn_sum, bn_sq, bng[0], bnb[0], bn_scale, bn_shift);
  gin_kernel<128, true><<<NNODES / 32, 256, 0, stream>>>(O0, row_ptr, csr_src,
      ginW1[1], ginb1[1], ginW2[1], ginb2[1], bn_scale, bn_shift, O1, bn_sum + 128, bn_sq + 128);
  bn_finalize_kernel<<<1, 128, 0, stream>>>(bn_sum + 128, bn_sq + 128, bng[1], bnb[1],
                                            bn_scale + 128, bn_shift + 128);
  gin_kernel<128, true><<<NNODES / 32, 256, 0, stream>>>(O1, row_ptr, csr_src,
      ginW1[2], ginb1[2], ginW2[2], ginb2[2], bn_scale + 128, bn_shift + 128, O0,
      bn_sum + 256, bn_sq + 256);
  bn_finalize_kernel<<<1, 128, 0, stream>>>(bn_sum + 256, bn_sq + 256, bng[2], bnb[2],
                                            bn_scale + 256, bn_shift + 256);

  // branches
  pool_kernel<<<NGRAPHS / 4, 256, 0, stream>>>(O0, gptr, bn_scale + 256, bn_shift + 256, P);
  conv_kernel<<<NGRAPHS, 256, 0, stream>>>(pseq, convk, convb, XP32);
  gemm2_kernel<false><<<dim3(NGRAPHS / 16, 2), 256, 0, stream>>>(P, 128, 128, ligW, 128, ligb, XC, 384, 0);
  gemm2_kernel<false><<<dim3(NGRAPHS / 16, 2), 256, 0, stream>>>(XP32, 32, 32, protW, 128, protb, XC, 384, 128);
  gemm2_kernel<true><<<dim3(NGRAPHS / 16, 2), 256, 0, stream>>>(XA, 128, 128, a2W, 128, a2b, XC, 384, 256);

  // head
  gemm2_kernel<false><<<dim3(NGRAPHS / 16, 4), 256, 0, stream>>>(XC, 384, 384, c1W, 256, c1b, XC2, 256, 0);
  gemm2_kernel<false><<<dim3(NGRAPHS / 16, 2), 256, 0, stream>>>(XC2, 256, 256, c2W, 128, c2b, XC3, 128, 0);
  final_dot_kernel<<<NGRAPHS / 4, 256, 0, stream>>>(XC3, oW, ob, (float*)d_out);
}

// Round 7
// 976.470 us; speedup vs baseline: 1.4202x; 1.1481x over previous
//
#include <hip/hip_runtime.h>
#include <math.h>

constexpr int NNODES  = 102400;
constexpr int NEDGES  = 409600;
constexpr int NGRAPHS = 2048;
constexpr int HIDDEN  = 128;

__device__ __forceinline__ float relu_f(float v) { return fmaxf(v, 0.0f); }

// ---------------- histogram ----------------
__global__ void hist_kernel(const int* __restrict__ idx, int n, int* __restrict__ counts) {
  int i = blockIdx.x * blockDim.x + threadIdx.x;
  if (i < n) atomicAdd(&counts[idx[i]], 1);
}

// ---------------- scans (exclusive prefix over counts) ----------------
__global__ void scan_block_kernel(const int* __restrict__ in, int n,
                                  int* __restrict__ out_excl, int* __restrict__ bsums) {
  __shared__ int s[256];
  int t = threadIdx.x;
  int i = blockIdx.x * 256 + t;
  int v = (i < n) ? in[i] : 0;
  s[t] = v;
  __syncthreads();
  for (int off = 1; off < 256; off <<= 1) {
    int x = (t >= off) ? s[t - off] : 0;
    __syncthreads();
    s[t] += x;
    __syncthreads();
  }
  if (i < n) out_excl[i] = s[t] - v;
  if (t == 255) bsums[blockIdx.x] = s[255];
}

__global__ void scan_top_kernel(int* __restrict__ bsums, int nb) {
  __shared__ int s[1024];
  int t = threadIdx.x;
  int v = (t < nb) ? bsums[t] : 0;
  s[t] = v;
  __syncthreads();
  for (int off = 1; off < 1024; off <<= 1) {
    int x = (t >= off) ? s[t - off] : 0;
    __syncthreads();
    s[t] += x;
    __syncthreads();
  }
  if (t < nb) bsums[t] = s[t] - v;
  if (t == 1023) bsums[nb] = s[1023];  // total
}

__global__ void scan_add_kernel(int* __restrict__ arr, const int* __restrict__ bsums,
                                int n, int* __restrict__ nextcopy) {
  int i = blockIdx.x * 256 + threadIdx.x;
  if (i < n) {
    int v = arr[i] + bsums[blockIdx.x];
    arr[i] = v;
    if (nextcopy) nextcopy[i] = v;
  }
  if (i == 0) arr[n] = bsums[gridDim.x];
}

__global__ void scatter_kernel(const int* __restrict__ ei, int* __restrict__ nxt,
                               int* __restrict__ csr_src) {
  int e = blockIdx.x * blockDim.x + threadIdx.x;
  if (e < NEDGES) {
    int s = ei[e];            // src row
    int d = ei[NEDGES + e];   // dst row
    int pos = atomicAdd(&nxt[d], 1);
    csr_src[pos] = s;
  }
}

// ---------------- fused GIN layer ----------------
// Gather: depth-4 software pipeline (2 sequential groups of 4 rows per wave);
// 4 independent X-row loads in flight, register accumulation, idx=-1 doubles
// as active flag (state fits the 64-VGPR cap of launch_bounds(256,8) -> no
// spill; R5's depth-8 spilled to scratch: WRITE_SIZE 54->275MB). Then mm1/mm2
// on 4x4 register tiles, single time-multiplexed LDS buffer (18.4 KB).
template<int DIN, bool XF>
__global__ __launch_bounds__(256, 8) void gin_kernel(
    const float* __restrict__ X,
    const int* __restrict__ row_ptr, const int* __restrict__ csr_src,
    const float* __restrict__ W1, const float* __restrict__ b1,
    const float* __restrict__ W2, const float* __restrict__ b2,
    const float* __restrict__ scale, const float* __restrict__ shift,
    float* __restrict__ O, float* __restrict__ bn_sum, float* __restrict__ bn_sq) {
  constexpr int R = 32, STR = R + 4;   // pad 36: 16B-aligned b128 reads
  constexpr int KMAX = (DIN > HIDDEN) ? DIN : HIDDEN;
  __shared__ __align__(16) float buf[KMAX * STR];   // xT, then mT, then reduction
  const int t = threadIdx.x;
  const int wv = t >> 6, lane = t & 63;
  const int base = blockIdx.x * R;

  const int fp = 2 * lane;     // feature pair for aggregation
  if (fp < DIN) {
    float sc0 = 1.f, sh0 = 0.f, sc1 = 1.f, sh1 = 0.f;
    if (XF) { sc0 = scale[fp]; sh0 = shift[fp]; sc1 = scale[fp + 1]; sh1 = shift[fp + 1]; }

    for (int g = 0; g < 2; ++g) {        // 2 groups of 4 rows -> small live state
      const int rbase = wv * 8 + g * 4;
      float a0[4], a1[4];
      int ecur[4], eend[4], idx[4];
#pragma unroll
      for (int r = 0; r < 4; ++r) {
        const int node = base + rbase + r;
        ecur[r] = row_ptr[node];
        eend[r] = row_ptr[node + 1];
        const float2 s = *(const float2*)&X[(long)node * DIN + fp];
        a0[r] = XF ? relu_f(fmaf(s.x, sc0, sh0)) : s.x;
        a1[r] = XF ? relu_f(fmaf(s.y, sc1, sh1)) : s.y;
        idx[r] = (ecur[r] < eend[r]) ? csr_src[ecur[r]] : -1;
      }
      bool any = (idx[0] >= 0) || (idx[1] >= 0) || (idx[2] >= 0) || (idx[3] >= 0);
      while (any) {
        float2 uu[4];
        // pass 1: issue all independent row loads
#pragma unroll
        for (int r = 0; r < 4; ++r)
          if (idx[r] >= 0) uu[r] = *(const float2*)&X[(long)idx[r] * DIN + fp];
        any = false;
        // pass 2: accumulate + prefetch next index
#pragma unroll
        for (int r = 0; r < 4; ++r) {
          if (idx[r] >= 0) {
            a0[r] += XF ? relu_f(fmaf(uu[r].x, sc0, sh0)) : uu[r].x;
            a1[r] += XF ? relu_f(fmaf(uu[r].y, sc1, sh1)) : uu[r].y;
            ++ecur[r];
            idx[r] = (ecur[r] < eend[r]) ? csr_src[ecur[r]] : -1;
          }
          any = any || (idx[r] >= 0);
        }
      }
#pragma unroll
      for (int r = 0; r < 4; ++r) {
        buf[fp * STR + rbase + r] = a0[r];
        buf[(fp + 1) * STR + rbase + r] = a1[r];
      }
    }
  }
  __syncthreads();

  const int rg = t >> 5, cg = t & 31;     // 8 row-groups x 32 col-groups
  const int r0 = rg * 4, j0 = cg * 4;     // 4x4 tile per thread

  // ---- mm1: acc = h @ W1 + b1 (keep in regs; buf still holds xT)
  float acc[4][4];
  {
    const float4 bb = *(const float4*)&b1[j0];
    for (int r = 0; r < 4; ++r) { acc[r][0]=bb.x; acc[r][1]=bb.y; acc[r][2]=bb.z; acc[r][3]=bb.w; }
    for (int k = 0; k < DIN; ++k) {
      const float4 w = *(const float4*)&W1[k * HIDDEN + j0];
      const float4 x = *(const float4*)&buf[k * STR + r0];
      const float xa[4] = {x.x, x.y, x.z, x.w};
      const float wa[4] = {w.x, w.y, w.z, w.w};
      for (int r = 0; r < 4; ++r)
        for (int c = 0; c < 4; ++c)
          acc[r][c] = fmaf(xa[r], wa[c], acc[r][c]);
    }
  }
  __syncthreads();   // all xT reads done -> buf reusable as mT

  // ---- write mid = relu(acc) transposed into buf
  for (int c = 0; c < 4; ++c) {
    float4 m = { relu_f(acc[0][c]), relu_f(acc[1][c]), relu_f(acc[2][c]), relu_f(acc[3][c]) };
    *(float4*)&buf[(j0 + c) * STR + r0] = m;
  }
  __syncthreads();

  // ---- mm2: o = mid @ W2 + b2; store pre-BN + BN partials
  float csum[4] = {0,0,0,0}, csq[4] = {0,0,0,0};
  {
    const float4 bb = *(const float4*)&b2[j0];
    for (int r = 0; r < 4; ++r) { acc[r][0]=bb.x; acc[r][1]=bb.y; acc[r][2]=bb.z; acc[r][3]=bb.w; }
    for (int k = 0; k < HIDDEN; ++k) {
      const float4 w = *(const float4*)&W2[k * HIDDEN + j0];
      const float4 x = *(const float4*)&buf[k * STR + r0];
      const float xa[4] = {x.x, x.y, x.z, x.w};
      const float wa[4] = {w.x, w.y, w.z, w.w};
      for (int r = 0; r < 4; ++r)
        for (int c = 0; c < 4; ++c)
          acc[r][c] = fmaf(xa[r], wa[c], acc[r][c]);
    }
    for (int r = 0; r < 4; ++r) {
      float4 o = { acc[r][0], acc[r][1], acc[r][2], acc[r][3] };
      *(float4*)&O[(long)(base + r0 + r) * HIDDEN + j0] = o;
      for (int c = 0; c < 4; ++c) {
        csum[c] += acc[r][c];
        csq[c] = fmaf(acc[r][c], acc[r][c], csq[c]);
      }
    }
  }
  __syncthreads();  // all mm2 reads done -> buf reusable as reduction scratch
  for (int c = 0; c < 4; ++c) {
    buf[(j0 + c) * 8 + rg] = csum[c];
    buf[1024 + (j0 + c) * 8 + rg] = csq[c];
  }
  __syncthreads();
  if (t < HIDDEN) {
    float s = 0.f, q = 0.f;
    for (int g = 0; g < 8; ++g) { s += buf[t * 8 + g]; q += buf[1024 + t * 8 + g]; }
    atomicAdd(&bn_sum[t], s);
    atomicAdd(&bn_sq[t], q);
  }
}

__global__ void bn_finalize_kernel(const float* __restrict__ bn_sum, const float* __restrict__ bn_sq,
                                   const float* __restrict__ g, const float* __restrict__ b,
                                   float* __restrict__ scale, float* __restrict__ shift) {
  int j = threadIdx.x;
  float mu  = bn_sum[j] * (1.0f / NNODES);
  float var = fmaxf(bn_sq[j] * (1.0f / NNODES) - mu * mu, 0.0f);
  float sc  = g[j] / sqrtf(var + 1e-5f);
  scale[j] = sc;
  shift[j] = b[j] - mu * sc;
}

// ---------------- global add pool (with final BN+relu fold) ----------------
__global__ __launch_bounds__(256) void pool_kernel(const float* __restrict__ O,
    const int* __restrict__ gp, const float* __restrict__ scale, const float* __restrict__ shift,
    float* __restrict__ P) {
  int t = threadIdx.x;
  int g = blockIdx.x * 4 + (t >> 6);
  int lane = t & 63;
  int f0 = lane, f1 = lane + 64;
  float sc0 = scale[f0], sh0 = shift[f0], sc1 = scale[f1], sh1 = shift[f1];
  int n0 = gp[g], n1 = gp[g + 1];
  float a0 = 0.f, a1 = 0.f;
  for (int n = n0; n < n1; ++n) {
    a0 += relu_f(fmaf(O[(long)n * HIDDEN + f0], sc0, sh0));
    a1 += relu_f(fmaf(O[(long)n * HIDDEN + f1], sc1, sh1));
  }
  P[g * HIDDEN + f0] = a0;
  P[g * HIDDEN + f1] = a1;
}

// ---------------- protein conv1d(1->32,k=8) + relu + global max ----------------
__global__ __launch_bounds__(256) void conv_kernel(const float* __restrict__ PS,
    const float* __restrict__ CK, const float* __restrict__ CB, float* __restrict__ XP) {
  __shared__ float seq[1000];
  const int t = threadIdx.x, g = blockIdx.x;
  for (int i = t; i < 1000; i += 256) seq[i] = PS[g * 1000 + i];
  __syncthreads();
  const int pl = t & 31, cgp = t >> 5;   // 32 position lanes x 8 channel-groups(4 ch)
  float kr[4][8];
  for (int cc = 0; cc < 4; ++cc)
    for (int k = 0; k < 8; ++k) kr[cc][k] = CK[(cgp * 4 + cc) * 8 + k];
  float m[4] = {-1e30f, -1e30f, -1e30f, -1e30f};
  for (int i = 0; i < 32; ++i) {
    int p = pl + 32 * i;
    if (p < 993) {
      float sv[8];
      for (int k = 0; k < 8; ++k) sv[k] = seq[p + k];
      for (int cc = 0; cc < 4; ++cc) {
        float s = 0.f;
        for (int k = 0; k < 8; ++k) s = fmaf(sv[k], kr[cc][k], s);
        m[cc] = fmaxf(m[cc], s);
      }
    }
  }
  for (int off = 16; off >= 1; off >>= 1)
    for (int cc = 0; cc < 4; ++cc) m[cc] = fmaxf(m[cc], __shfl_xor(m[cc], off));
  if (pl == 0)
    for (int cc = 0; cc < 4; ++cc)
      XP[g * 32 + cgp * 4 + cc] = relu_f(m[cc] + CB[cgp * 4 + cc]);
}

// ---------------- tail gemm: C = relu(A@W + b), 16 rows x 64 cols per block ----------------
template<bool RELU_A>
__global__ __launch_bounds__(256) void gemm2_kernel(const float* __restrict__ A, int lda, int K,
    const float* __restrict__ W, int ldw, const float* __restrict__ bias,
    float* __restrict__ C, int ldc, int coff) {
  constexpr int RT = 16, CH = 64, STR = RT + 4;
  __shared__ __align__(16) float AT[CH * STR];
  const int t = threadIdx.x;
  const int rg = t >> 6, cg = t & 63;
  const int r0 = rg * 4;
  const int row0 = blockIdx.x * RT;
  const int col = blockIdx.y * 64 + cg;
  float a0 = 0.f, a1 = 0.f, a2 = 0.f, a3 = 0.f;
  for (int k0 = 0; k0 < K; k0 += CH) {
    const int kc = min(CH, K - k0);
    __syncthreads();
    for (int i = t; i < RT * CH; i += 256) {
      int kk = i & (CH - 1), r = i >> 6;
      if (kk < kc) {
        float v = A[(long)(row0 + r) * lda + k0 + kk];
        AT[kk * STR + r] = RELU_A ? relu_f(v) : v;
      }
    }
    __syncthreads();
    for (int kk = 0; kk < kc; ++kk) {
      const float4 x = *(const float4*)&AT[kk * STR + r0];
      const float w = W[(long)(k0 + kk) * ldw + col];
      a0 = fmaf(x.x, w, a0);
      a1 = fmaf(x.y, w, a1);
      a2 = fmaf(x.z, w, a2);
      a3 = fmaf(x.w, w, a3);
    }
  }
  const float bv = bias[col];
  C[(long)(row0 + r0 + 0) * ldc + coff + col] = relu_f(a0 + bv);
  C[(long)(row0 + r0 + 1) * ldc + coff + col] = relu_f(a1 + bv);
  C[(long)(row0 + r0 + 2) * ldc + coff + col] = relu_f(a2 + bv);
  C[(long)(row0 + r0 + 3) * ldc + coff + col] = relu_f(a3 + bv);
}

// ---------------- a2h branch: XA init with bias ----------------
__global__ __launch_bounds__(256) void bias_fill_kernel(const float* __restrict__ b,
                                                        float* __restrict__ XA) {
  int i = blockIdx.x * 256 + threadIdx.x;
  XA[i] = b[i & (HIDDEN - 1)];
}

// ---------------- a2h branch split-K gemm: XA += A@W (atomic), pre-relu ----------------
constexpr int A2H_K = 3000, A2H_SPLIT = 300, A2H_NSPLIT = 10;
__global__ __launch_bounds__(128) void a2h_gemm_kernel(const float* __restrict__ A,
    const float* __restrict__ W, float* __restrict__ XA) {
  constexpr int RT = 16, STR = RT + 4;   // LDS tile [300][20]
  __shared__ __align__(16) float xT[A2H_SPLIT * STR];  // 24 KB
  const int t = threadIdx.x;
  const int row0 = blockIdx.x * RT;
  const int k0 = blockIdx.y * A2H_SPLIT;

  constexpr int Q = A2H_SPLIT / 4;       // 75 float4 per row
  for (int i = t; i < RT * Q; i += 128) {
    const int r = i / Q, kq = i - r * Q;
    const float4 v = *(const float4*)&A[(long)(row0 + r) * A2H_K + k0 + kq * 4];
    xT[(kq * 4 + 0) * STR + r] = v.x;
    xT[(kq * 4 + 1) * STR + r] = v.y;
    xT[(kq * 4 + 2) * STR + r] = v.z;
    xT[(kq * 4 + 3) * STR + r] = v.w;
  }
  __syncthreads();

  const int rg = t >> 5, cg = t & 31;    // 4 row-groups x 32 col-groups
  const int r0 = rg * 4, j0 = cg * 4;
  float acc[4][4];
  for (int r = 0; r < 4; ++r)
    for (int c = 0; c < 4; ++c) acc[r][c] = 0.f;

  const float* Wp = W + (long)k0 * HIDDEN + j0;
  for (int k = 0; k < A2H_SPLIT; ++k) {
    const float4 w = *(const float4*)&Wp[(long)k * HIDDEN];
    const float4 x = *(const float4*)&xT[k * STR + r0];
    const float xa[4] = {x.x, x.y, x.z, x.w};
    const float wa[4] = {w.x, w.y, w.z, w.w};
    for (int r = 0; r < 4; ++r)
      for (int c = 0; c < 4; ++c)
        acc[r][c] = fmaf(xa[r], wa[c], acc[r][c]);
  }
  for (int r = 0; r < 4; ++r)
    for (int c = 0; c < 4; ++c)
      atomicAdd(&XA[(long)(row0 + r0 + r) * HIDDEN + j0 + c], acc[r][c]);
}

// ---------------- final projection to scalar ----------------
__global__ __launch_bounds__(256) void final_dot_kernel(const float* __restrict__ X,
    const float* __restrict__ Wo, const float* __restrict__ bo, float* __restrict__ out) {
  int t = threadIdx.x;
  int g = blockIdx.x * 4 + (t >> 6);
  int lane = t & 63;
  float2 x = *(const float2*)&X[g * HIDDEN + lane * 2];
  float2 w = *(const float2*)&Wo[lane * 2];
  float p = x.x * w.x + x.y * w.y;
  for (int off = 32; off >= 1; off >>= 1) p += __shfl_down(p, off);
  if (lane == 0) out[g] = p + bo[0];
}

extern "C" void kernel_launch(void* const* d_in, const int* in_sizes, int n_in,
                              void* d_out, int out_size, void* d_ws, size_t ws_size,
                              hipStream_t stream) {
  const float* x_lig = (const float*)d_in[0];
  const float* pseq  = (const float*)d_in[1];
  const float* a2h   = (const float*)d_in[2];
  const int*   ei    = (const int*)d_in[3];
  const int*   batch = (const int*)d_in[4];
  const float* ginW1[3] = {(const float*)d_in[5],  (const float*)d_in[11], (const float*)d_in[17]};
  const float* ginb1[3] = {(const float*)d_in[6],  (const float*)d_in[12], (const float*)d_in[18]};
  const float* ginW2[3] = {(const float*)d_in[7],  (const float*)d_in[13], (const float*)d_in[19]};
  const float* ginb2[3] = {(const float*)d_in[8],  (const float*)d_in[14], (const float*)d_in[20]};
  const float* bng[3]   = {(const float*)d_in[9],  (const float*)d_in[15], (const float*)d_in[21]};
  const float* bnb[3]   = {(const float*)d_in[10], (const float*)d_in[16], (const float*)d_in[22]};
  const float* ligW  = (const float*)d_in[23]; const float* ligb  = (const float*)d_in[24];
  const float* convk = (const float*)d_in[25]; const float* convb = (const float*)d_in[26];
  const float* protW = (const float*)d_in[27]; const float* protb = (const float*)d_in[28];
  const float* a1W   = (const float*)d_in[29]; const float* a1b   = (const float*)d_in[30];
  const float* a2W   = (const float*)d_in[31]; const float* a2b   = (const float*)d_in[32];
  const float* c1W   = (const float*)d_in[33]; const float* c1b   = (const float*)d_in[34];
  const float* c2W   = (const float*)d_in[35]; const float* c2b   = (const float*)d_in[36];
  const float* oW    = (const float*)d_in[37]; const float* ob    = (const float*)d_in[38];

  char* base = (char*)d_ws;
  size_t off = 0;
  auto alloc = [&](size_t bytes) -> char* {
    char* p = base + off;
    off = (off + bytes + 511) & ~size_t(511);
    return p;
  };
  int*   counts  = (int*)alloc(NNODES * 4);
  int*   gcounts = (int*)alloc(NGRAPHS * 4);
  float* bn_sum  = (float*)alloc(3 * 128 * 4);
  float* bn_sq   = (float*)alloc(3 * 128 * 4);
  const size_t zero_bytes = off;          // counts+gcounts+bn accumulators
  float* bn_scale = (float*)alloc(3 * 128 * 4);
  float* bn_shift = (float*)alloc(3 * 128 * 4);
  int*   row_ptr  = (int*)alloc((NNODES + 1) * 4);
  int*   nxt      = (int*)alloc(NNODES * 4);
  int*   gptr     = (int*)alloc((NGRAPHS + 1) * 4);
  int*   bsumsA   = (int*)alloc(401 * 4);
  int*   bsumsB   = (int*)alloc(9 * 4);
  int*   csr_src  = (int*)alloc(NEDGES * 4);
  float* P        = (float*)alloc(NGRAPHS * 128 * 4);
  float* XA       = (float*)alloc(NGRAPHS * 128 * 4);
  float* XP32     = (float*)alloc(NGRAPHS * 32 * 4);
  float* XC       = (float*)alloc(NGRAPHS * 384 * 4);
  float* XC2      = (float*)alloc(NGRAPHS * 256 * 4);
  float* XC3      = (float*)alloc(NGRAPHS * 128 * 4);
  float* O0       = (float*)alloc((size_t)NNODES * 128 * 4);
  float* O1       = (float*)alloc((size_t)NNODES * 128 * 4);
  (void)ws_size; (void)in_sizes; (void)n_in; (void)out_size;

  hipMemsetAsync(d_ws, 0, zero_bytes, stream);

  // CSR over dst + graph segment ptrs
  hist_kernel<<<(NEDGES + 255) / 256, 256, 0, stream>>>(ei + NEDGES, NEDGES, counts);
  hist_kernel<<<(NNODES + 255) / 256, 256, 0, stream>>>(batch, NNODES, gcounts);
  scan_block_kernel<<<NNODES / 256, 256, 0, stream>>>(counts, NNODES, row_ptr, bsumsA);
  scan_block_kernel<<<NGRAPHS / 256, 256, 0, stream>>>(gcounts, NGRAPHS, gptr, bsumsB);
  scan_top_kernel<<<1, 1024, 0, stream>>>(bsumsA, NNODES / 256);
  scan_top_kernel<<<1, 1024, 0, stream>>>(bsumsB, NGRAPHS / 256);
  scan_add_kernel<<<NNODES / 256, 256, 0, stream>>>(row_ptr, bsumsA, NNODES, nxt);
  scan_add_kernel<<<NGRAPHS / 256, 256, 0, stream>>>(gptr, bsumsB, NGRAPHS, nullptr);
  scatter_kernel<<<(NEDGES + 255) / 256, 256, 0, stream>>>(ei, nxt, csr_src);

  // a2h branch early (independent): bias fill + split-K atomic gemm
  bias_fill_kernel<<<NGRAPHS * HIDDEN / 256, 256, 0, stream>>>(a1b, XA);
  a2h_gemm_kernel<<<dim3(NGRAPHS / 16, A2H_NSPLIT), 128, 0, stream>>>(a2h, a1W, XA);

  // GIN layers (BN+relu of layer l folded into consumer of layer l)
  gin_kernel<78, false><<<NNODES / 32, 256, 0, stream>>>(x_lig, row_ptr, csr_src,
      ginW1[0], ginb1[0], ginW2[0], ginb2[0], nullptr, nullptr, O0, bn_sum, bn_sq);
  bn_finalize_kernel<<<1, 128, 0, stream>>>(bn_sum, bn_sq, bng[0], bnb[0], bn_scale, bn_shift);
  gin_kernel<128, true><<<NNODES / 32, 256, 0, stream>>>(O0, row_ptr, csr_src,
      ginW1[1], ginb1[1], ginW2[1], ginb2[1], bn_scale, bn_shift, O1, bn_sum + 128, bn_sq + 128);
  bn_finalize_kernel<<<1, 128, 0, stream>>>(bn_sum + 128, bn_sq + 128, bng[1], bnb[1],
                                            bn_scale + 128, bn_shift + 128);
  gin_kernel<128, true><<<NNODES / 32, 256, 0, stream>>>(O1, row_ptr, csr_src,
      ginW1[2], ginb1[2], ginW2[2], ginb2[2], bn_scale + 128, bn_shift + 128, O0,
      bn_sum + 256, bn_sq + 256);
  bn_finalize_kernel<<<1, 128, 0, stream>>>(bn_sum + 256, bn_sq + 256, bng[2], bnb[2],
                                            bn_scale + 256, bn_shift + 256);

  // branches
  pool_kernel<<<NGRAPHS / 4, 256, 0, stream>>>(O0, gptr, bn_scale + 256, bn_shift + 256, P);
  conv_kernel<<<NGRAPHS, 256, 0, stream>>>(pseq, convk, convb, XP32);
  gemm2_kernel<false><<<dim3(NGRAPHS / 16, 2), 256, 0, stream>>>(P, 128, 128, ligW, 128, ligb, XC, 384, 0);
  gemm2_kernel<false><<<dim3(NGRAPHS / 16, 2), 256, 0, stream>>>(XP32, 32, 32, protW, 128, protb, XC, 384, 128);
  gemm2_kernel<true><<<dim3(NGRAPHS / 16, 2), 256, 0, stream>>>(XA, 128, 128, a2W, 128, a2b, XC, 384, 256);

  // head
  gemm2_kernel<false><<<dim3(NGRAPHS / 16, 4), 256, 0, stream>>>(XC, 384, 384, c1W, 256, c1b, XC2, 256, 0);
  gemm2_kernel<false><<<dim3(NGRAPHS / 16, 2), 256, 0, stream>>>(XC2, 256, 256, c2W, 128, c2b, XC3, 128, 0);
  final_dot_kernel<<<NGRAPHS / 4, 256, 0, stream>>>(XC3, oW, ob, (float*)d_out);
}

// Round 8
// 880.896 us; speedup vs baseline: 1.5743x; 1.1085x over previous
//
#include <hip/hip_runtime.h>
#include <math.h>

constexpr int NNODES  = 102400;
constexpr int NEDGES  = 409600;
constexpr int NGRAPHS = 2048;
constexpr int HIDDEN  = 128;

__device__ __forceinline__ float relu_f(float v) { return fmaxf(v, 0.0f); }

// ---------------- merged histograms: [0,1600) edge-dst, [1600,2000) batch ----------------
__global__ void hist2_kernel(const int* __restrict__ ei, const int* __restrict__ batch,
                             int* __restrict__ counts, int* __restrict__ gcounts) {
  int b = blockIdx.x;
  if (b < NEDGES / 256) {
    int e = b * 256 + threadIdx.x;
    atomicAdd(&counts[ei[NEDGES + e]], 1);
  } else {
    int i = (b - NEDGES / 256) * 256 + threadIdx.x;
    atomicAdd(&gcounts[batch[i]], 1);
  }
}

// ---------------- merged block scans: [0,400) counts, [400,408) gcounts ----------------
__device__ __forceinline__ void scan_block_body(const int* in, int n, int* out_excl,
                                                int* bsums, int lb) {
  __shared__ int s[256];
  int t = threadIdx.x;
  int i = lb * 256 + t;
  int v = (i < n) ? in[i] : 0;
  s[t] = v;
  __syncthreads();
  for (int off = 1; off < 256; off <<= 1) {
    int x = (t >= off) ? s[t - off] : 0;
    __syncthreads();
    s[t] += x;
    __syncthreads();
  }
  if (i < n) out_excl[i] = s[t] - v;
  if (t == 255) bsums[lb] = s[255];
}

__global__ void scan_block2_kernel(const int* __restrict__ counts, int* __restrict__ row_ptr,
                                   int* __restrict__ bsumsA, const int* __restrict__ gcounts,
                                   int* __restrict__ gptr, int* __restrict__ bsumsB) {
  int b = blockIdx.x;
  if (b < NNODES / 256) scan_block_body(counts, NNODES, row_ptr, bsumsA, b);
  else scan_block_body(gcounts, NGRAPHS, gptr, bsumsB, b - NNODES / 256);
}

// ---------------- merged top scans: block0 bsumsA(400), block1 bsumsB(8) ----------------
__global__ void scan_top2_kernel(int* __restrict__ bsumsA, int* __restrict__ bsumsB) {
  __shared__ int s[1024];
  int* bs = (blockIdx.x == 0) ? bsumsA : bsumsB;
  int nb  = (blockIdx.x == 0) ? (NNODES / 256) : (NGRAPHS / 256);
  int t = threadIdx.x;
  int v = (t < nb) ? bs[t] : 0;
  s[t] = v;
  __syncthreads();
  for (int off = 1; off < 1024; off <<= 1) {
    int x = (t >= off) ? s[t - off] : 0;
    __syncthreads();
    s[t] += x;
    __syncthreads();
  }
  if (t < nb) bs[t] = s[t] - v;
  if (t == 1023) bs[nb] = s[1023];  // total
}

// ---------------- merged scan_add ----------------
__global__ void scan_add2_kernel(int* __restrict__ row_ptr, const int* __restrict__ bsumsA,
                                 int* __restrict__ nxt, int* __restrict__ gptr,
                                 const int* __restrict__ bsumsB) {
  int b = blockIdx.x, t = threadIdx.x;
  if (b < NNODES / 256) {
    int i = b * 256 + t;
    int v = row_ptr[i] + bsumsA[b];
    row_ptr[i] = v;
    nxt[i] = v;
    if (i == 0) row_ptr[NNODES] = bsumsA[NNODES / 256];
  } else {
    int lb = b - NNODES / 256;
    int i = lb * 256 + t;
    gptr[i] += bsumsB[lb];
    if (i == 0) gptr[NGRAPHS] = bsumsB[NGRAPHS / 256];
  }
}

__global__ void scatter_kernel(const int* __restrict__ ei, int* __restrict__ nxt,
                               int* __restrict__ csr_src) {
  int e = blockIdx.x * blockDim.x + threadIdx.x;
  if (e < NEDGES) {
    int s = ei[e];
    int d = ei[NEDGES + e];
    int pos = atomicAdd(&nxt[d], 1);
    csr_src[pos] = s;
  }
}

// ---------------- GIN block body (R6-proven: depth-4 pipelined gather, 4x4 mm tiles,
// time-multiplexed 18.4 KB LDS). XF: BN scale/shift computed inline per lane. ----------------
template<int DIN, bool XF>
__device__ __forceinline__ void gin_block(
    int bid, const float* __restrict__ X,
    const int* __restrict__ row_ptr, const int* __restrict__ csr_src,
    const float* __restrict__ W1, const float* __restrict__ b1,
    const float* __restrict__ W2, const float* __restrict__ b2,
    const float* __restrict__ psum, const float* __restrict__ psq,
    const float* __restrict__ bg, const float* __restrict__ bb2,
    float* __restrict__ O, float* __restrict__ bn_sum, float* __restrict__ bn_sq,
    float* buf) {
  constexpr int R = 32, STR = R + 4;
  const int t = threadIdx.x;
  const int wv = t >> 6, lane = t & 63;
  const int base = bid * R;

  const int fp = 2 * lane;
  if (fp < DIN) {
    float sc0 = 1.f, sh0 = 0.f, sc1 = 1.f, sh1 = 0.f;
    if (XF) {
      float mu0 = psum[fp] * (1.0f / NNODES);
      float va0 = fmaxf(psq[fp] * (1.0f / NNODES) - mu0 * mu0, 0.0f);
      sc0 = bg[fp] / sqrtf(va0 + 1e-5f);
      sh0 = bb2[fp] - mu0 * sc0;
      float mu1 = psum[fp + 1] * (1.0f / NNODES);
      float va1 = fmaxf(psq[fp + 1] * (1.0f / NNODES) - mu1 * mu1, 0.0f);
      sc1 = bg[fp + 1] / sqrtf(va1 + 1e-5f);
      sh1 = bb2[fp + 1] - mu1 * sc1;
    }
    for (int g = 0; g < 2; ++g) {
      const int rbase = wv * 8 + g * 4;
      float a0[4], a1[4];
      int ecur[4], eend[4], idx[4];
#pragma unroll
      for (int r = 0; r < 4; ++r) {
        const int node = base + rbase + r;
        ecur[r] = row_ptr[node];
        eend[r] = row_ptr[node + 1];
        const float2 s = *(const float2*)&X[(long)node * DIN + fp];
        a0[r] = XF ? relu_f(fmaf(s.x, sc0, sh0)) : s.x;
        a1[r] = XF ? relu_f(fmaf(s.y, sc1, sh1)) : s.y;
        idx[r] = (ecur[r] < eend[r]) ? csr_src[ecur[r]] : -1;
      }
      bool any = (idx[0] >= 0) || (idx[1] >= 0) || (idx[2] >= 0) || (idx[3] >= 0);
      while (any) {
        float2 uu[4];
#pragma unroll
        for (int r = 0; r < 4; ++r)
          if (idx[r] >= 0) uu[r] = *(const float2*)&X[(long)idx[r] * DIN + fp];
        any = false;
#pragma unroll
        for (int r = 0; r < 4; ++r) {
          if (idx[r] >= 0) {
            a0[r] += XF ? relu_f(fmaf(uu[r].x, sc0, sh0)) : uu[r].x;
            a1[r] += XF ? relu_f(fmaf(uu[r].y, sc1, sh1)) : uu[r].y;
            ++ecur[r];
            idx[r] = (ecur[r] < eend[r]) ? csr_src[ecur[r]] : -1;
          }
          any = any || (idx[r] >= 0);
        }
      }
#pragma unroll
      for (int r = 0; r < 4; ++r) {
        buf[fp * STR + rbase + r] = a0[r];
        buf[(fp + 1) * STR + rbase + r] = a1[r];
      }
    }
  }
  __syncthreads();

  const int rg = t >> 5, cg = t & 31;
  const int r0 = rg * 4, j0 = cg * 4;

  float acc[4][4];
  {
    const float4 bbv = *(const float4*)&b1[j0];
    for (int r = 0; r < 4; ++r) { acc[r][0]=bbv.x; acc[r][1]=bbv.y; acc[r][2]=bbv.z; acc[r][3]=bbv.w; }
    for (int k = 0; k < DIN; ++k) {
      const float4 w = *(const float4*)&W1[k * HIDDEN + j0];
      const float4 x = *(const float4*)&buf[k * STR + r0];
      const float xa[4] = {x.x, x.y, x.z, x.w};
      const float wa[4] = {w.x, w.y, w.z, w.w};
      for (int r = 0; r < 4; ++r)
        for (int c = 0; c < 4; ++c)
          acc[r][c] = fmaf(xa[r], wa[c], acc[r][c]);
    }
  }
  __syncthreads();

  for (int c = 0; c < 4; ++c) {
    float4 m = { relu_f(acc[0][c]), relu_f(acc[1][c]), relu_f(acc[2][c]), relu_f(acc[3][c]) };
    *(float4*)&buf[(j0 + c) * STR + r0] = m;
  }
  __syncthreads();

  float csum[4] = {0,0,0,0}, csq[4] = {0,0,0,0};
  {
    const float4 bbv = *(const float4*)&b2[j0];
    for (int r = 0; r < 4; ++r) { acc[r][0]=bbv.x; acc[r][1]=bbv.y; acc[r][2]=bbv.z; acc[r][3]=bbv.w; }
    for (int k = 0; k < HIDDEN; ++k) {
      const float4 w = *(const float4*)&W2[k * HIDDEN + j0];
      const float4 x = *(const float4*)&buf[k * STR + r0];
      const float xa[4] = {x.x, x.y, x.z, x.w};
      const float wa[4] = {w.x, w.y, w.z, w.w};
      for (int r = 0; r < 4; ++r)
        for (int c = 0; c < 4; ++c)
          acc[r][c] = fmaf(xa[r], wa[c], acc[r][c]);
    }
    for (int r = 0; r < 4; ++r) {
      float4 o = { acc[r][0], acc[r][1], acc[r][2], acc[r][3] };
      *(float4*)&O[(long)(base + r0 + r) * HIDDEN + j0] = o;
      for (int c = 0; c < 4; ++c) {
        csum[c] += acc[r][c];
        csq[c] = fmaf(acc[r][c], acc[r][c], csq[c]);
      }
    }
  }
  __syncthreads();
  for (int c = 0; c < 4; ++c) {
    buf[(j0 + c) * 8 + rg] = csum[c];
    buf[1024 + (j0 + c) * 8 + rg] = csq[c];
  }
  __syncthreads();
  if (t < HIDDEN) {
    float s = 0.f, q = 0.f;
    for (int g = 0; g < 8; ++g) { s += buf[t * 8 + g]; q += buf[1024 + t * 8 + g]; }
    atomicAdd(&bn_sum[t], s);
    atomicAdd(&bn_sq[t], q);
  }
}

// ---------------- a2h split-K block (256 thr, 16 rows x 200 K; 14.4 KB LDS) ----------------
constexpr int A2H_K = 3000, A2H_SPLIT = 200, A2H_NSPLIT = 15;
__device__ __forceinline__ void a2h_block(int rb, int sp, const float* __restrict__ A,
    const float* __restrict__ W, const float* __restrict__ bias, float* __restrict__ XA,
    float* xT) {
  constexpr int STR = 18;              // [200][18] -> 72B rows keep float2 reads 8B-aligned
  const int t = threadIdx.x;
  const int row0 = rb * 16;
  const int k0 = sp * A2H_SPLIT;
  for (int i = t; i < 16 * 50; i += 256) {
    const int r = i / 50, kq = i - r * 50;
    const float4 v = *(const float4*)&A[(long)(row0 + r) * A2H_K + k0 + kq * 4];
    xT[(kq * 4 + 0) * STR + r] = v.x;
    xT[(kq * 4 + 1) * STR + r] = v.y;
    xT[(kq * 4 + 2) * STR + r] = v.z;
    xT[(kq * 4 + 3) * STR + r] = v.w;
  }
  __syncthreads();
  const int rg = t >> 5, cg = t & 31;  // 8 row-groups x 32 col-groups, 2x4 tile
  const int r0 = rg * 2, j0 = cg * 4;
  float acc[2][4];
  for (int r = 0; r < 2; ++r)
    for (int c = 0; c < 4; ++c) acc[r][c] = 0.f;
  const float* Wp = W + (long)k0 * HIDDEN + j0;
  for (int k = 0; k < A2H_SPLIT; ++k) {
    const float4 w = *(const float4*)&Wp[(long)k * HIDDEN];
    const float2 x = *(const float2*)&xT[k * STR + r0];
    const float wa[4] = {w.x, w.y, w.z, w.w};
    for (int c = 0; c < 4; ++c) {
      acc[0][c] = fmaf(x.x, wa[c], acc[0][c]);
      acc[1][c] = fmaf(x.y, wa[c], acc[1][c]);
    }
  }
  if (sp == 0)
    for (int c = 0; c < 4; ++c) { acc[0][c] += bias[j0 + c]; acc[1][c] += bias[j0 + c]; }
  for (int r = 0; r < 2; ++r)
    for (int c = 0; c < 4; ++c)
      atomicAdd(&XA[(long)(row0 + r0 + r) * HIDDEN + j0 + c], acc[r][c]);
}

// ---------------- conv block ----------------
__device__ __forceinline__ void conv_block(int g, const float* __restrict__ PS,
    const float* __restrict__ CK, const float* __restrict__ CB, float* __restrict__ XP,
    float* seq) {
  const int t = threadIdx.x;
  for (int i = t; i < 1000; i += 256) seq[i] = PS[g * 1000 + i];
  __syncthreads();
  const int pl = t & 31, cgp = t >> 5;
  float kr[4][8];
  for (int cc = 0; cc < 4; ++cc)
    for (int k = 0; k < 8; ++k) kr[cc][k] = CK[(cgp * 4 + cc) * 8 + k];
  float m[4] = {-1e30f, -1e30f, -1e30f, -1e30f};
  for (int i = 0; i < 32; ++i) {
    int p = pl + 32 * i;
    if (p < 993) {
      float sv[8];
      for (int k = 0; k < 8; ++k) sv[k] = seq[p + k];
      for (int cc = 0; cc < 4; ++cc) {
        float s = 0.f;
        for (int k = 0; k < 8; ++k) s = fmaf(sv[k], kr[cc][k], s);
        m[cc] = fmaxf(m[cc], s);
      }
    }
  }
  for (int off = 16; off >= 1; off >>= 1)
    for (int cc = 0; cc < 4; ++cc) m[cc] = fmaxf(m[cc], __shfl_xor(m[cc], off));
  if (pl == 0)
    for (int cc = 0; cc < 4; ++cc)
      XP[g * 32 + cgp * 4 + cc] = relu_f(m[cc] + CB[cgp * 4 + cc]);
}

// ---------------- fat0: gin0 [0,3200) + a2h [3200,5120) + conv [5120,7168) ----------------
__global__ __launch_bounds__(256, 8) void fat0_kernel(
    const float* __restrict__ x_lig, const int* __restrict__ row_ptr,
    const int* __restrict__ csr_src,
    const float* __restrict__ W1, const float* __restrict__ b1,
    const float* __restrict__ W2, const float* __restrict__ b2,
    float* __restrict__ O0, float* __restrict__ bn_sum, float* __restrict__ bn_sq,
    const float* __restrict__ a2h, const float* __restrict__ a1W,
    const float* __restrict__ a1b, float* __restrict__ XA,
    const float* __restrict__ pseq, const float* __restrict__ convk,
    const float* __restrict__ convb, float* __restrict__ XP32) {
  __shared__ __align__(16) float buf[128 * 36];   // 18432 B, shared by all roles
  const int b = blockIdx.x;
  if (b < NNODES / 32) {
    gin_block<78, false>(b, x_lig, row_ptr, csr_src, W1, b1, W2, b2,
                         nullptr, nullptr, nullptr, nullptr, O0, bn_sum, bn_sq, buf);
  } else if (b < NNODES / 32 + (NGRAPHS / 16) * A2H_NSPLIT) {
    const int q = b - NNODES / 32;
    a2h_block(q & 127, q >> 7, a2h, a1W, a1b, XA, buf);
  } else {
    conv_block(b - (NNODES / 32 + (NGRAPHS / 16) * A2H_NSPLIT), pseq, convk, convb, XP32, buf);
  }
}

// ---------------- gin wrapper (layers 1,2 with inline BN of previous layer) ----------------
template<int DIN, bool XF>
__global__ __launch_bounds__(256, 8) void gin_kernel(
    const float* __restrict__ X, const int* __restrict__ row_ptr,
    const int* __restrict__ csr_src,
    const float* __restrict__ W1, const float* __restrict__ b1,
    const float* __restrict__ W2, const float* __restrict__ b2,
    const float* __restrict__ psum, const float* __restrict__ psq,
    const float* __restrict__ bg, const float* __restrict__ bb2,
    float* __restrict__ O, float* __restrict__ bn_sum, float* __restrict__ bn_sq) {
  __shared__ __align__(16) float buf[128 * 36];
  gin_block<DIN, XF>(blockIdx.x, X, row_ptr, csr_src, W1, b1, W2, b2,
                     psum, psq, bg, bb2, O, bn_sum, bn_sq, buf);
}

// ---------------- pool with inline BN finalize of layer 2 ----------------
__global__ __launch_bounds__(256) void pool_kernel(const float* __restrict__ O,
    const int* __restrict__ gp, const float* __restrict__ psum, const float* __restrict__ psq,
    const float* __restrict__ bg, const float* __restrict__ bb2, float* __restrict__ P) {
  int t = threadIdx.x;
  int g = blockIdx.x * 4 + (t >> 6);
  int lane = t & 63;
  int f0 = lane, f1 = lane + 64;
  float mu0 = psum[f0] * (1.0f / NNODES);
  float va0 = fmaxf(psq[f0] * (1.0f / NNODES) - mu0 * mu0, 0.0f);
  float sc0 = bg[f0] / sqrtf(va0 + 1e-5f);
  float sh0 = bb2[f0] - mu0 * sc0;
  float mu1 = psum[f1] * (1.0f / NNODES);
  float va1 = fmaxf(psq[f1] * (1.0f / NNODES) - mu1 * mu1, 0.0f);
  float sc1 = bg[f1] / sqrtf(va1 + 1e-5f);
  float sh1 = bb2[f1] - mu1 * sc1;
  int n0 = gp[g], n1 = gp[g + 1];
  float a0 = 0.f, a1 = 0.f;
  for (int n = n0; n < n1; ++n) {
    a0 += relu_f(fmaf(O[(long)n * HIDDEN + f0], sc0, sh0));
    a1 += relu_f(fmaf(O[(long)n * HIDDEN + f1], sc1, sh1));
  }
  P[g * HIDDEN + f0] = a0;
  P[g * HIDDEN + f1] = a1;
}

// ---------------- generic 16-row x 64-col gemm body ----------------
__device__ __forceinline__ void gemm16_body(const float* __restrict__ A, int lda, int K,
    const float* __restrict__ W, int ldw, const float* __restrict__ bias,
    float* __restrict__ C, int ldc, int coff, int yc, bool reluA, float* AT) {
  constexpr int RT = 16, CH = 64, STR = RT + 4;
  const int t = threadIdx.x;
  const int rg = t >> 6, cg = t & 63;
  const int r0 = rg * 4;
  const int row0 = blockIdx.x * RT;
  const int col = yc * 64 + cg;
  float a0 = 0.f, a1 = 0.f, a2 = 0.f, a3 = 0.f;
  for (int k0 = 0; k0 < K; k0 += CH) {
    const int kc = min(CH, K - k0);
    __syncthreads();
    for (int i = t; i < RT * CH; i += 256) {
      int kk = i & (CH - 1), r = i >> 6;
      if (kk < kc) {
        float v = A[(long)(row0 + r) * lda + k0 + kk];
        AT[kk * STR + r] = reluA ? relu_f(v) : v;
      }
    }
    __syncthreads();
    for (int kk = 0; kk < kc; ++kk) {
      const float4 x = *(const float4*)&AT[kk * STR + r0];
      const float w = W[(long)(k0 + kk) * ldw + col];
      a0 = fmaf(x.x, w, a0);
      a1 = fmaf(x.y, w, a1);
      a2 = fmaf(x.z, w, a2);
      a3 = fmaf(x.w, w, a3);
    }
  }
  const float bv = bias[col];
  C[(long)(row0 + r0 + 0) * ldc + coff + col] = relu_f(a0 + bv);
  C[(long)(row0 + r0 + 1) * ldc + coff + col] = relu_f(a1 + bv);
  C[(long)(row0 + r0 + 2) * ldc + coff + col] = relu_f(a2 + bv);
  C[(long)(row0 + r0 + 3) * ldc + coff + col] = relu_f(a3 + bv);
}

// ---------------- three branch gemms fused (lig / prot / a2W -> XC cols) ----------------
__global__ __launch_bounds__(256) void branches_kernel(
    const float* __restrict__ P, const float* __restrict__ XP32, const float* __restrict__ XA,
    const float* __restrict__ ligW, const float* __restrict__ ligb,
    const float* __restrict__ protW, const float* __restrict__ protb,
    const float* __restrict__ a2W, const float* __restrict__ a2b, float* __restrict__ XC) {
  __shared__ __align__(16) float AT[64 * 20];
  const int cfg = blockIdx.y >> 1, yc = blockIdx.y & 1;
  if (cfg == 0)      gemm16_body(P,    128, 128, ligW,  128, ligb,  XC, 384, 0,   yc, false, AT);
  else if (cfg == 1) gemm16_body(XP32, 32,  32,  protW, 128, protb, XC, 384, 128, yc, false, AT);
  else               gemm16_body(XA,   128, 128, a2W,   128, a2b,   XC, 384, 256, yc, true,  AT);
}

// ---------------- head gemm ----------------
__global__ __launch_bounds__(256) void gemm2_kernel(const float* __restrict__ A, int lda, int K,
    const float* __restrict__ W, int ldw, const float* __restrict__ bias,
    float* __restrict__ C, int ldc) {
  __shared__ __align__(16) float AT[64 * 20];
  gemm16_body(A, lda, K, W, ldw, bias, C, ldc, 0, blockIdx.y, false, AT);
}

// ---------------- final projection to scalar ----------------
__global__ __launch_bounds__(256) void final_dot_kernel(const float* __restrict__ X,
    const float* __restrict__ Wo, const float* __restrict__ bo, float* __restrict__ out) {
  int t = threadIdx.x;
  int g = blockIdx.x * 4 + (t >> 6);
  int lane = t & 63;
  float2 x = *(const float2*)&X[g * HIDDEN + lane * 2];
  float2 w = *(const float2*)&Wo[lane * 2];
  float p = x.x * w.x + x.y * w.y;
  for (int off = 32; off >= 1; off >>= 1) p += __shfl_down(p, off);
  if (lane == 0) out[g] = p + bo[0];
}

extern "C" void kernel_launch(void* const* d_in, const int* in_sizes, int n_in,
                              void* d_out, int out_size, void* d_ws, size_t ws_size,
                              hipStream_t stream) {
  const float* x_lig = (const float*)d_in[0];
  const float* pseq  = (const float*)d_in[1];
  const float* a2h   = (const float*)d_in[2];
  const int*   ei    = (const int*)d_in[3];
  const int*   batch = (const int*)d_in[4];
  const float* ginW1[3] = {(const float*)d_in[5],  (const float*)d_in[11], (const float*)d_in[17]};
  const float* ginb1[3] = {(const float*)d_in[6],  (const float*)d_in[12], (const float*)d_in[18]};
  const float* ginW2[3] = {(const float*)d_in[7],  (const float*)d_in[13], (const float*)d_in[19]};
  const float* ginb2[3] = {(const float*)d_in[8],  (const float*)d_in[14], (const float*)d_in[20]};
  const float* bng[3]   = {(const float*)d_in[9],  (const float*)d_in[15], (const float*)d_in[21]};
  const float* bnb[3]   = {(const float*)d_in[10], (const float*)d_in[16], (const float*)d_in[22]};
  const float* ligW  = (const float*)d_in[23]; const float* ligb  = (const float*)d_in[24];
  const float* convk = (const float*)d_in[25]; const float* convb = (const float*)d_in[26];
  const float* protW = (const float*)d_in[27]; const float* protb = (const float*)d_in[28];
  const float* a1W   = (const float*)d_in[29]; const float* a1b   = (const float*)d_in[30];
  const float* a2W   = (const float*)d_in[31]; const float* a2b   = (const float*)d_in[32];
  const float* c1W   = (const float*)d_in[33]; const float* c1b   = (const float*)d_in[34];
  const float* c2W   = (const float*)d_in[35]; const float* c2b   = (const float*)d_in[36];
  const float* oW    = (const float*)d_in[37]; const float* ob    = (const float*)d_in[38];

  char* base = (char*)d_ws;
  size_t off = 0;
  auto alloc = [&](size_t bytes) -> char* {
    char* p = base + off;
    off = (off + bytes + 511) & ~size_t(511);
    return p;
  };
  // zeroed prefix: counts, gcounts, bn accumulators, XA (a2h atomic target)
  int*   counts  = (int*)alloc(NNODES * 4);
  int*   gcounts = (int*)alloc(NGRAPHS * 4);
  float* bn_sum  = (float*)alloc(3 * 128 * 4);
  float* bn_sq   = (float*)alloc(3 * 128 * 4);
  float* XA      = (float*)alloc(NGRAPHS * 128 * 4);
  const size_t zero_bytes = off;
  int*   row_ptr  = (int*)alloc((NNODES + 1) * 4);
  int*   nxt      = (int*)alloc(NNODES * 4);
  int*   gptr     = (int*)alloc((NGRAPHS + 1) * 4);
  int*   bsumsA   = (int*)alloc(401 * 4);
  int*   bsumsB   = (int*)alloc(9 * 4);
  int*   csr_src  = (int*)alloc(NEDGES * 4);
  float* P        = (float*)alloc(NGRAPHS * 128 * 4);
  float* XP32     = (float*)alloc(NGRAPHS * 32 * 4);
  float* XC       = (float*)alloc(NGRAPHS * 384 * 4);
  float* XC2      = (float*)alloc(NGRAPHS * 256 * 4);
  float* XC3      = (float*)alloc(NGRAPHS * 128 * 4);
  float* O0       = (float*)alloc((size_t)NNODES * 128 * 4);
  float* O1       = (float*)alloc((size_t)NNODES * 128 * 4);
  (void)ws_size; (void)in_sizes; (void)n_in; (void)out_size;

  hipMemsetAsync(d_ws, 0, zero_bytes, stream);

  // CSR build: 5 merged launches
  hist2_kernel<<<NEDGES / 256 + NNODES / 256, 256, 0, stream>>>(ei, batch, counts, gcounts);
  scan_block2_kernel<<<NNODES / 256 + NGRAPHS / 256, 256, 0, stream>>>(
      counts, row_ptr, bsumsA, gcounts, gptr, bsumsB);
  scan_top2_kernel<<<2, 1024, 0, stream>>>(bsumsA, bsumsB);
  scan_add2_kernel<<<NNODES / 256 + NGRAPHS / 256, 256, 0, stream>>>(
      row_ptr, bsumsA, nxt, gptr, bsumsB);
  scatter_kernel<<<(NEDGES + 255) / 256, 256, 0, stream>>>(ei, nxt, csr_src);

  // fat0: gin0 + a2h split-K gemm + conv branch (independent work backfills CUs)
  fat0_kernel<<<NNODES / 32 + (NGRAPHS / 16) * A2H_NSPLIT + NGRAPHS, 256, 0, stream>>>(
      x_lig, row_ptr, csr_src, ginW1[0], ginb1[0], ginW2[0], ginb2[0],
      O0, bn_sum, bn_sq, a2h, a1W, a1b, XA, pseq, convk, convb, XP32);

  // gin1/gin2 with inline BN finalize of previous layer
  gin_kernel<128, true><<<NNODES / 32, 256, 0, stream>>>(O0, row_ptr, csr_src,
      ginW1[1], ginb1[1], ginW2[1], ginb2[1], bn_sum, bn_sq, bng[0], bnb[0],
      O1, bn_sum + 128, bn_sq + 128);
  gin_kernel<128, true><<<NNODES / 32, 256, 0, stream>>>(O1, row_ptr, csr_src,
      ginW1[2], ginb1[2], ginW2[2], ginb2[2], bn_sum + 128, bn_sq + 128, bng[1], bnb[1],
      O0, bn_sum + 256, bn_sq + 256);

  // pool (inline BN2) -> fused branch gemms -> head
  pool_kernel<<<NGRAPHS / 4, 256, 0, stream>>>(O0, gptr, bn_sum + 256, bn_sq + 256,
                                               bng[2], bnb[2], P);
  branches_kernel<<<dim3(NGRAPHS / 16, 6), 256, 0, stream>>>(
      P, XP32, XA, ligW, ligb, protW, protb, a2W, a2b, XC);
  gemm2_kernel<<<dim3(NGRAPHS / 16, 4), 256, 0, stream>>>(XC, 384, 384, c1W, 256, c1b, XC2, 256);
  gemm2_kernel<<<dim3(NGRAPHS / 16, 2), 256, 0, stream>>>(XC2, 256, 256, c2W, 128, c2b, XC3, 128);
  final_dot_kernel<<<NGRAPHS / 4, 256, 0, stream>>>(XC3, oW, ob, (float*)d_out);
}

// Round 9
// 848.299 us; speedup vs baseline: 1.6347x; 1.0384x over previous
//
#include <hip/hip_runtime.h>
#include <math.h>

constexpr int NNODES  = 102400;
constexpr int NEDGES  = 409600;
constexpr int NGRAPHS = 2048;
constexpr int HIDDEN  = 128;

typedef __attribute__((ext_vector_type(8))) short s16x8;
typedef __attribute__((ext_vector_type(4))) float f32x4;

__device__ __forceinline__ float relu_f(float v) { return fmaxf(v, 0.0f); }

// exact 3-way bf16 truncation split: x == b0 + b1 + b2 (b2 exact)
__device__ __forceinline__ void split3(float x, short& s0, short& s1, short& s2) {
  unsigned u0 = __float_as_uint(x);
  s0 = (short)(u0 >> 16);
  float r1 = x - __uint_as_float(u0 & 0xFFFF0000u);
  unsigned u1 = __float_as_uint(r1);
  s1 = (short)(u1 >> 16);
  float r2 = r1 - __uint_as_float(u1 & 0xFFFF0000u);
  s2 = (short)(__float_as_uint(r2) >> 16);
}

// ---------------- prep: histograms + weight-split (merged) ----------------
// blocks [0,1600): edge-dst hist; [1600,2000): batch hist; [2000,2736): weight split
// wsplit layout per mat: plane p in {0,1,2}, elem ((k>>5)*128+n)*32 + (k&31)
__global__ void prep_kernel(const int* __restrict__ ei, const int* __restrict__ batch,
                            int* __restrict__ counts, int* __restrict__ gcounts,
                            const float* __restrict__ W10, const float* __restrict__ W20,
                            const float* __restrict__ W11, const float* __restrict__ W21,
                            const float* __restrict__ W12, const float* __restrict__ W22,
                            short* __restrict__ ws) {
  int b = blockIdx.x;
  if (b < NEDGES / 256) {
    atomicAdd(&counts[ei[NEDGES + b * 256 + threadIdx.x]], 1);
    return;
  }
  if (b < NEDGES / 256 + NNODES / 256) {
    atomicAdd(&gcounts[batch[(b - NEDGES / 256) * 256 + threadIdx.x]], 1);
    return;
  }
  int bw = b - (NEDGES / 256 + NNODES / 256);
  int n = threadIdx.x;
  if (n >= 128) return;
  const float* src; long base; int k, realK, KP;
  if (bw < 96) {
    src = W10; base = 0; k = bw; realK = 78; KP = 96;
  } else {
    int q = bw - 96;
    int mat = q >> 7;        // 0..4 -> W20,W11,W21,W12,W22
    k = q & 127; realK = 128; KP = 128;
    const float* srcs[5] = {W20, W11, W21, W12, W22};
    const long bases[5] = {36864, 86016, 135168, 184320, 233472};
    src = srcs[mat]; base = bases[mat];
  }
  float x = (k < realK) ? src[k * 128 + n] : 0.0f;
  short s0, s1, s2;
  split3(x, s0, s1, s2);
  long e = base + ((long)(k >> 5) * 128 + n) * 32 + (k & 31);
  long ps = (long)KP * 128;
  ws[e] = s0; ws[e + ps] = s1; ws[e + 2 * ps] = s2;
}

// ---------------- merged block scans ----------------
__device__ __forceinline__ void scan_block_body(const int* in, int n, int* out_excl,
                                                int* bsums, int lb) {
  __shared__ int s[256];
  int t = threadIdx.x;
  int i = lb * 256 + t;
  int v = (i < n) ? in[i] : 0;
  s[t] = v;
  __syncthreads();
  for (int off = 1; off < 256; off <<= 1) {
    int x = (t >= off) ? s[t - off] : 0;
    __syncthreads();
    s[t] += x;
    __syncthreads();
  }
  if (i < n) out_excl[i] = s[t] - v;
  if (t == 255) bsums[lb] = s[255];
}

__global__ void scan_block2_kernel(const int* __restrict__ counts, int* __restrict__ row_ptr,
                                   int* __restrict__ bsumsA, const int* __restrict__ gcounts,
                                   int* __restrict__ gptr, int* __restrict__ bsumsB) {
  int b = blockIdx.x;
  if (b < NNODES / 256) scan_block_body(counts, NNODES, row_ptr, bsumsA, b);
  else scan_block_body(gcounts, NGRAPHS, gptr, bsumsB, b - NNODES / 256);
}

__global__ void scan_top2_kernel(int* __restrict__ bsumsA, int* __restrict__ bsumsB) {
  __shared__ int s[1024];
  int* bs = (blockIdx.x == 0) ? bsumsA : bsumsB;
  int nb  = (blockIdx.x == 0) ? (NNODES / 256) : (NGRAPHS / 256);
  int t = threadIdx.x;
  int v = (t < nb) ? bs[t] : 0;
  s[t] = v;
  __syncthreads();
  for (int off = 1; off < 1024; off <<= 1) {
    int x = (t >= off) ? s[t - off] : 0;
    __syncthreads();
    s[t] += x;
    __syncthreads();
  }
  if (t < nb) bs[t] = s[t] - v;
  if (t == 1023) bs[nb] = s[1023];
}

__global__ void scan_add2_kernel(int* __restrict__ row_ptr, const int* __restrict__ bsumsA,
                                 int* __restrict__ nxt, int* __restrict__ gptr,
                                 const int* __restrict__ bsumsB) {
  int b = blockIdx.x, t = threadIdx.x;
  if (b < NNODES / 256) {
    int i = b * 256 + t;
    int v = row_ptr[i] + bsumsA[b];
    row_ptr[i] = v;
    nxt[i] = v;
    if (i == 0) row_ptr[NNODES] = bsumsA[NNODES / 256];
  } else {
    int lb = b - NNODES / 256;
    int i = lb * 256 + t;
    gptr[i] += bsumsB[lb];
    if (i == 0) gptr[NGRAPHS] = bsumsB[NGRAPHS / 256];
  }
}

__global__ void scatter_kernel(const int* __restrict__ ei, int* __restrict__ nxt,
                               int* __restrict__ csr_src) {
  int e = blockIdx.x * blockDim.x + threadIdx.x;
  if (e < NEDGES) {
    int s = ei[e];
    int d = ei[NEDGES + e];
    int pos = atomicAdd(&nxt[d], 1);
    csr_src[pos] = s;
  }
}

// ---------------- GIN block body ----------------
// gather (depth-4 pipelined, R6-proven) -> buf[r][k] (STRK=132) -> MFMA mm1/mm2
// via exact bf16x3 split (6 products == fp32 accuracy) -> O + BN partials.
constexpr int STRK = 132;
template<int DIN, int KP1, bool XF>
__device__ __forceinline__ void gin_block(
    int bid, const float* __restrict__ X,
    const int* __restrict__ row_ptr, const int* __restrict__ csr_src,
    const short* __restrict__ w1s, const float* __restrict__ b1,
    const short* __restrict__ w2s, const float* __restrict__ b2,
    const float* __restrict__ psum, const float* __restrict__ psq,
    const float* __restrict__ bg, const float* __restrict__ bb2,
    float* __restrict__ O, float* __restrict__ bn_sum, float* __restrict__ bn_sq,
    float* buf) {
  const int t = threadIdx.x;
  const int wv = t >> 6, lane = t & 63;
  const int base = bid * 32;

  // ---- gather: lane owns feature pair fp, fp+1; rows [r][k] layout
  const int fp = 2 * lane;
  if (fp < KP1) {
    if (fp < DIN) {
      float sc0 = 1.f, sh0 = 0.f, sc1 = 1.f, sh1 = 0.f;
      if (XF) {
        float mu0 = psum[fp] * (1.0f / NNODES);
        float va0 = fmaxf(psq[fp] * (1.0f / NNODES) - mu0 * mu0, 0.0f);
        sc0 = bg[fp] / sqrtf(va0 + 1e-5f);
        sh0 = bb2[fp] - mu0 * sc0;
        float mu1 = psum[fp + 1] * (1.0f / NNODES);
        float va1 = fmaxf(psq[fp + 1] * (1.0f / NNODES) - mu1 * mu1, 0.0f);
        sc1 = bg[fp + 1] / sqrtf(va1 + 1e-5f);
        sh1 = bb2[fp + 1] - mu1 * sc1;
      }
      for (int g = 0; g < 2; ++g) {
        const int rbase = wv * 8 + g * 4;
        float a0[4], a1[4];
        int ecur[4], eend[4], idx[4];
#pragma unroll
        for (int r = 0; r < 4; ++r) {
          const int node = base + rbase + r;
          ecur[r] = row_ptr[node];
          eend[r] = row_ptr[node + 1];
          const float2 s = *(const float2*)&X[(long)node * DIN + fp];
          a0[r] = XF ? relu_f(fmaf(s.x, sc0, sh0)) : s.x;
          a1[r] = XF ? relu_f(fmaf(s.y, sc1, sh1)) : s.y;
          idx[r] = (ecur[r] < eend[r]) ? csr_src[ecur[r]] : -1;
        }
        bool any = (idx[0] >= 0) || (idx[1] >= 0) || (idx[2] >= 0) || (idx[3] >= 0);
        while (any) {
          float2 uu[4];
#pragma unroll
          for (int r = 0; r < 4; ++r)
            if (idx[r] >= 0) uu[r] = *(const float2*)&X[(long)idx[r] * DIN + fp];
          any = false;
#pragma unroll
          for (int r = 0; r < 4; ++r) {
            if (idx[r] >= 0) {
              a0[r] += XF ? relu_f(fmaf(uu[r].x, sc0, sh0)) : uu[r].x;
              a1[r] += XF ? relu_f(fmaf(uu[r].y, sc1, sh1)) : uu[r].y;
              ++ecur[r];
              idx[r] = (ecur[r] < eend[r]) ? csr_src[ecur[r]] : -1;
            }
            any = any || (idx[r] >= 0);
          }
        }
#pragma unroll
        for (int r = 0; r < 4; ++r)
          *(float2*)&buf[(rbase + r) * STRK + fp] = make_float2(a0[r], a1[r]);
      }
    } else {
      // zero-pad columns [DIN, KP1)
      for (int r = 0; r < 8; ++r)
        *(float2*)&buf[(wv * 8 + r) * STRK + fp] = make_float2(0.f, 0.f);
    }
  }
  __syncthreads();

  const int rb = wv & 1, nbase = (wv >> 1) * 64;
  const int l15 = lane & 15, quad = lane >> 4;
  const int aoff = (rb * 16 + l15) * STRK;
  constexpr int PS1 = KP1 * 128;
  constexpr int PS2 = 128 * 128;

  // ---- mm1 (MFMA): acc1 = h @ W1
  f32x4 acc1[4] = {};
  for (int ks = 0; ks < KP1 / 32; ++ks) {
    const int k0 = ks * 32;
    const float4 xa = *(const float4*)&buf[aoff + k0 + quad * 8];
    const float4 xb = *(const float4*)&buf[aoff + k0 + quad * 8 + 4];
    s16x8 A0, A1, A2;
    {
      const float xv[8] = {xa.x, xa.y, xa.z, xa.w, xb.x, xb.y, xb.z, xb.w};
#pragma unroll
      for (int j = 0; j < 8; ++j) {
        short s0, s1, s2;
        split3(xv[j], s0, s1, s2);
        A0[j] = s0; A1[j] = s1; A2[j] = s2;
      }
    }
    s16x8 B0[4], B1[4], B2[4];
#pragma unroll
    for (int ct = 0; ct < 4; ++ct) {
      const int n = nbase + ct * 16 + l15;
      const short* wp = w1s + ((long)(ks * 128 + n) << 5) + (quad << 3);
      B0[ct] = *(const s16x8*)(wp);
      B1[ct] = *(const s16x8*)(wp + PS1);
      B2[ct] = *(const s16x8*)(wp + 2 * PS1);
    }
#pragma unroll
    for (int ct = 0; ct < 4; ++ct) acc1[ct] = __builtin_amdgcn_mfma_f32_16x16x32_bf16(A0, B2[ct], acc1[ct], 0, 0, 0);
#pragma unroll
    for (int ct = 0; ct < 4; ++ct) acc1[ct] = __builtin_amdgcn_mfma_f32_16x16x32_bf16(A1, B1[ct], acc1[ct], 0, 0, 0);
#pragma unroll
    for (int ct = 0; ct < 4; ++ct) acc1[ct] = __builtin_amdgcn_mfma_f32_16x16x32_bf16(A2, B0[ct], acc1[ct], 0, 0, 0);
#pragma unroll
    for (int ct = 0; ct < 4; ++ct) acc1[ct] = __builtin_amdgcn_mfma_f32_16x16x32_bf16(A0, B1[ct], acc1[ct], 0, 0, 0);
#pragma unroll
    for (int ct = 0; ct < 4; ++ct) acc1[ct] = __builtin_amdgcn_mfma_f32_16x16x32_bf16(A1, B0[ct], acc1[ct], 0, 0, 0);
#pragma unroll
    for (int ct = 0; ct < 4; ++ct) acc1[ct] = __builtin_amdgcn_mfma_f32_16x16x32_bf16(A0, B0[ct], acc1[ct], 0, 0, 0);
  }
  __syncthreads();   // xT reads done -> buf reusable as mid

  // mid = relu(acc1 + b1), stored [m][j]  (C/D: col=lane&15, row=quad*4+reg)
#pragma unroll
  for (int ct = 0; ct < 4; ++ct) {
    const int n = nbase + ct * 16 + l15;
    const float bb = b1[n];
#pragma unroll
    for (int reg = 0; reg < 4; ++reg) {
      const int m = rb * 16 + quad * 4 + reg;
      buf[m * STRK + n] = relu_f(acc1[ct][reg] + bb);
    }
  }
  __syncthreads();

  // ---- mm2 (MFMA): acc2 = mid @ W2
  f32x4 acc2[4] = {};
  for (int ks = 0; ks < 4; ++ks) {
    const int k0 = ks * 32;
    const float4 xa = *(const float4*)&buf[aoff + k0 + quad * 8];
    const float4 xb = *(const float4*)&buf[aoff + k0 + quad * 8 + 4];
    s16x8 A0, A1, A2;
    {
      const float xv[8] = {xa.x, xa.y, xa.z, xa.w, xb.x, xb.y, xb.z, xb.w};
#pragma unroll
      for (int j = 0; j < 8; ++j) {
        short s0, s1, s2;
        split3(xv[j], s0, s1, s2);
        A0[j] = s0; A1[j] = s1; A2[j] = s2;
      }
    }
    s16x8 B0[4], B1[4], B2[4];
#pragma unroll
    for (int ct = 0; ct < 4; ++ct) {
      const int n = nbase + ct * 16 + l15;
      const short* wp = w2s + ((long)(ks * 128 + n) << 5) + (quad << 3);
      B0[ct] = *(const s16x8*)(wp);
      B1[ct] = *(const s16x8*)(wp + PS2);
      B2[ct] = *(const s16x8*)(wp + 2 * PS2);
    }
#pragma unroll
    for (int ct = 0; ct < 4; ++ct) acc2[ct] = __builtin_amdgcn_mfma_f32_16x16x32_bf16(A0, B2[ct], acc2[ct], 0, 0, 0);
#pragma unroll
    for (int ct = 0; ct < 4; ++ct) acc2[ct] = __builtin_amdgcn_mfma_f32_16x16x32_bf16(A1, B1[ct], acc2[ct], 0, 0, 0);
#pragma unroll
    for (int ct = 0; ct < 4; ++ct) acc2[ct] = __builtin_amdgcn_mfma_f32_16x16x32_bf16(A2, B0[ct], acc2[ct], 0, 0, 0);
#pragma unroll
    for (int ct = 0; ct < 4; ++ct) acc2[ct] = __builtin_amdgcn_mfma_f32_16x16x32_bf16(A0, B1[ct], acc2[ct], 0, 0, 0);
#pragma unroll
    for (int ct = 0; ct < 4; ++ct) acc2[ct] = __builtin_amdgcn_mfma_f32_16x16x32_bf16(A1, B0[ct], acc2[ct], 0, 0, 0);
#pragma unroll
    for (int ct = 0; ct < 4; ++ct) acc2[ct] = __builtin_amdgcn_mfma_f32_16x16x32_bf16(A0, B0[ct], acc2[ct], 0, 0, 0);
  }

  // epilogue: O store + per-column BN partials (lane owns column n per ct)
  float cs[4], cq[4];
#pragma unroll
  for (int ct = 0; ct < 4; ++ct) {
    const int n = nbase + ct * 16 + l15;
    const float bb = b2[n];
    float s = 0.f, q = 0.f;
#pragma unroll
    for (int reg = 0; reg < 4; ++reg) {
      const int m = rb * 16 + quad * 4 + reg;
      const float o = acc2[ct][reg] + bb;
      O[(long)(base + m) * HIDDEN + n] = o;
      s += o;
      q = fmaf(o, o, q);
    }
    cs[ct] = s; cq[ct] = q;
  }
  __syncthreads();   // mid reads done -> buf reusable as reduction scratch
  const int g = rb * 4 + quad;
#pragma unroll
  for (int ct = 0; ct < 4; ++ct) {
    const int n = nbase + ct * 16 + l15;
    buf[n * 8 + g] = cs[ct];
    buf[1024 + n * 8 + g] = cq[ct];
  }
  __syncthreads();
  if (t < HIDDEN) {
    float s = 0.f, q = 0.f;
    for (int gg = 0; gg < 8; ++gg) { s += buf[t * 8 + gg]; q += buf[1024 + t * 8 + gg]; }
    atomicAdd(&bn_sum[t], s);
    atomicAdd(&bn_sq[t], q);
  }
}

// ---------------- a2h split-K block ----------------
constexpr int A2H_K = 3000, A2H_SPLIT = 200, A2H_NSPLIT = 15;
__device__ __forceinline__ void a2h_block(int rb, int sp, const float* __restrict__ A,
    const float* __restrict__ W, const float* __restrict__ bias, float* __restrict__ XA,
    float* xT) {
  constexpr int STR = 18;
  const int t = threadIdx.x;
  const int row0 = rb * 16;
  const int k0 = sp * A2H_SPLIT;
  for (int i = t; i < 16 * 50; i += 256) {
    const int r = i / 50, kq = i - r * 50;
    const float4 v = *(const float4*)&A[(long)(row0 + r) * A2H_K + k0 + kq * 4];
    xT[(kq * 4 + 0) * STR + r] = v.x;
    xT[(kq * 4 + 1) * STR + r] = v.y;
    xT[(kq * 4 + 2) * STR + r] = v.z;
    xT[(kq * 4 + 3) * STR + r] = v.w;
  }
  __syncthreads();
  const int rg = t >> 5, cg = t & 31;
  const int r0 = rg * 2, j0 = cg * 4;
  float acc[2][4];
  for (int r = 0; r < 2; ++r)
    for (int c = 0; c < 4; ++c) acc[r][c] = 0.f;
  const float* Wp = W + (long)k0 * HIDDEN + j0;
  for (int k = 0; k < A2H_SPLIT; ++k) {
    const float4 w = *(const float4*)&Wp[(long)k * HIDDEN];
    const float2 x = *(const float2*)&xT[k * STR + r0];
    const float wa[4] = {w.x, w.y, w.z, w.w};
    for (int c = 0; c < 4; ++c) {
      acc[0][c] = fmaf(x.x, wa[c], acc[0][c]);
      acc[1][c] = fmaf(x.y, wa[c], acc[1][c]);
    }
  }
  if (sp == 0)
    for (int c = 0; c < 4; ++c) { acc[0][c] += bias[j0 + c]; acc[1][c] += bias[j0 + c]; }
  for (int r = 0; r < 2; ++r)
    for (int c = 0; c < 4; ++c)
      atomicAdd(&XA[(long)(row0 + r0 + r) * HIDDEN + j0 + c], acc[r][c]);
}

// ---------------- conv block ----------------
__device__ __forceinline__ void conv_block(int g, const float* __restrict__ PS,
    const float* __restrict__ CK, const float* __restrict__ CB, float* __restrict__ XP,
    float* seq) {
  const int t = threadIdx.x;
  for (int i = t; i < 1000; i += 256) seq[i] = PS[g * 1000 + i];
  __syncthreads();
  const int pl = t & 31, cgp = t >> 5;
  float kr[4][8];
  for (int cc = 0; cc < 4; ++cc)
    for (int k = 0; k < 8; ++k) kr[cc][k] = CK[(cgp * 4 + cc) * 8 + k];
  float m[4] = {-1e30f, -1e30f, -1e30f, -1e30f};
  for (int i = 0; i < 32; ++i) {
    int p = pl + 32 * i;
    if (p < 993) {
      float sv[8];
      for (int k = 0; k < 8; ++k) sv[k] = seq[p + k];
      for (int cc = 0; cc < 4; ++cc) {
        float s = 0.f;
        for (int k = 0; k < 8; ++k) s = fmaf(sv[k], kr[cc][k], s);
        m[cc] = fmaxf(m[cc], s);
      }
    }
  }
  for (int off = 16; off >= 1; off >>= 1)
    for (int cc = 0; cc < 4; ++cc) m[cc] = fmaxf(m[cc], __shfl_xor(m[cc], off));
  if (pl == 0)
    for (int cc = 0; cc < 4; ++cc)
      XP[g * 32 + cgp * 4 + cc] = relu_f(m[cc] + CB[cgp * 4 + cc]);
}

// ---------------- fat0: gin0 + a2h + conv ----------------
__global__ __launch_bounds__(256, 4) void fat0_kernel(
    const float* __restrict__ x_lig, const int* __restrict__ row_ptr,
    const int* __restrict__ csr_src,
    const short* __restrict__ ws, const float* __restrict__ b1,
    const float* __restrict__ b2,
    float* __restrict__ O0, float* __restrict__ bn_sum, float* __restrict__ bn_sq,
    const float* __restrict__ a2h, const float* __restrict__ a1W,
    const float* __restrict__ a1b, float* __restrict__ XA,
    const float* __restrict__ pseq, const float* __restrict__ convk,
    const float* __restrict__ convb, float* __restrict__ XP32) {
  __shared__ __align__(16) float buf[32 * STRK];   // 16896 B
  const int b = blockIdx.x;
  if (b < NNODES / 32) {
    gin_block<78, 96, false>(b, x_lig, row_ptr, csr_src, ws, b1, ws + 36864, b2,
                             nullptr, nullptr, nullptr, nullptr, O0, bn_sum, bn_sq, buf);
  } else if (b < NNODES / 32 + (NGRAPHS / 16) * A2H_NSPLIT) {
    const int q = b - NNODES / 32;
    a2h_block(q & 127, q >> 7, a2h, a1W, a1b, XA, buf);
  } else {
    conv_block(b - (NNODES / 32 + (NGRAPHS / 16) * A2H_NSPLIT), pseq, convk, convb, XP32, buf);
  }
}

// ---------------- gin wrapper (layers 1,2; inline BN of previous layer) ----------------
__global__ __launch_bounds__(256, 4) void gin_kernel(
    const float* __restrict__ X, const int* __restrict__ row_ptr,
    const int* __restrict__ csr_src,
    const short* __restrict__ w1s, const float* __restrict__ b1,
    const short* __restrict__ w2s, const float* __restrict__ b2,
    const float* __restrict__ psum, const float* __restrict__ psq,
    const float* __restrict__ bg, const float* __restrict__ bb2,
    float* __restrict__ O, float* __restrict__ bn_sum, float* __restrict__ bn_sq) {
  __shared__ __align__(16) float buf[32 * STRK];
  gin_block<128, 128, true>(blockIdx.x, X, row_ptr, csr_src, w1s, b1, w2s, b2,
                            psum, psq, bg, bb2, O, bn_sum, bn_sq, buf);
}

// ---------------- pool with inline BN finalize of layer 2 ----------------
__global__ __launch_bounds__(256) void pool_kernel(const float* __restrict__ O,
    const int* __restrict__ gp, const float* __restrict__ psum, const float* __restrict__ psq,
    const float* __restrict__ bg, const float* __restrict__ bb2, float* __restrict__ P) {
  int t = threadIdx.x;
  int g = blockIdx.x * 4 + (t >> 6);
  int lane = t & 63;
  int f0 = lane, f1 = lane + 64;
  float mu0 = psum[f0] * (1.0f / NNODES);
  float va0 = fmaxf(psq[f0] * (1.0f / NNODES) - mu0 * mu0, 0.0f);
  float sc0 = bg[f0] / sqrtf(va0 + 1e-5f);
  float sh0 = bb2[f0] - mu0 * sc0;
  float mu1 = psum[f1] * (1.0f / NNODES);
  float va1 = fmaxf(psq[f1] * (1.0f / NNODES) - mu1 * mu1, 0.0f);
  float sc1 = bg[f1] / sqrtf(va1 + 1e-5f);
  float sh1 = bb2[f1] - mu1 * sc1;
  int n0 = gp[g], n1 = gp[g + 1];
  float a0 = 0.f, a1 = 0.f;
  for (int n = n0; n < n1; ++n) {
    a0 += relu_f(fmaf(O[(long)n * HIDDEN + f0], sc0, sh0));
    a1 += relu_f(fmaf(O[(long)n * HIDDEN + f1], sc1, sh1));
  }
  P[g * HIDDEN + f0] = a0;
  P[g * HIDDEN + f1] = a1;
}

// ---------------- generic 16-row x 64-col gemm body ----------------
__device__ __forceinline__ void gemm16_body(const float* __restrict__ A, int lda, int K,
    const float* __restrict__ W, int ldw, const float* __restrict__ bias,
    float* __restrict__ C, int ldc, int coff, int yc, bool reluA, float* AT) {
  constexpr int RT = 16, CH = 64, STR = RT + 4;
  const int t = threadIdx.x;
  const int rg = t >> 6, cg = t & 63;
  const int r0 = rg * 4;
  const int row0 = blockIdx.x * RT;
  const int col = yc * 64 + cg;
  float a0 = 0.f, a1 = 0.f, a2 = 0.f, a3 = 0.f;
  for (int k0 = 0; k0 < K; k0 += CH) {
    const int kc = min(CH, K - k0);
    __syncthreads();
    for (int i = t; i < RT * CH; i += 256) {
      int kk = i & (CH - 1), r = i >> 6;
      if (kk < kc) {
        float v = A[(long)(row0 + r) * lda + k0 + kk];
        AT[kk * STR + r] = reluA ? relu_f(v) : v;
      }
    }
    __syncthreads();
    for (int kk = 0; kk < kc; ++kk) {
      const float4 x = *(const float4*)&AT[kk * STR + r0];
      const float w = W[(long)(k0 + kk) * ldw + col];
      a0 = fmaf(x.x, w, a0);
      a1 = fmaf(x.y, w, a1);
      a2 = fmaf(x.z, w, a2);
      a3 = fmaf(x.w, w, a3);
    }
  }
  const float bv = bias[col];
  C[(long)(row0 + r0 + 0) * ldc + coff + col] = relu_f(a0 + bv);
  C[(long)(row0 + r0 + 1) * ldc + coff + col] = relu_f(a1 + bv);
  C[(long)(row0 + r0 + 2) * ldc + coff + col] = relu_f(a2 + bv);
  C[(long)(row0 + r0 + 3) * ldc + coff + col] = relu_f(a3 + bv);
}

__global__ __launch_bounds__(256) void branches_kernel(
    const float* __restrict__ P, const float* __restrict__ XP32, const float* __restrict__ XA,
    const float* __restrict__ ligW, const float* __restrict__ ligb,
    const float* __restrict__ protW, const float* __restrict__ protb,
    const float* __restrict__ a2W, const float* __restrict__ a2b, float* __restrict__ XC) {
  __shared__ __align__(16) float AT[64 * 20];
  const int cfg = blockIdx.y >> 1, yc = blockIdx.y & 1;
  if (cfg == 0)      gemm16_body(P,    128, 128, ligW,  128, ligb,  XC, 384, 0,   yc, false, AT);
  else if (cfg == 1) gemm16_body(XP32, 32,  32,  protW, 128, protb, XC, 384, 128, yc, false, AT);
  else               gemm16_body(XA,   128, 128, a2W,   128, a2b,   XC, 384, 256, yc, true,  AT);
}

__global__ __launch_bounds__(256) void gemm2_kernel(const float* __restrict__ A, int lda, int K,
    const float* __restrict__ W, int ldw, const float* __restrict__ bias,
    float* __restrict__ C, int ldc) {
  __shared__ __align__(16) float AT[64 * 20];
  gemm16_body(A, lda, K, W, ldw, bias, C, ldc, 0, blockIdx.y, false, AT);
}

__global__ __launch_bounds__(256) void final_dot_kernel(const float* __restrict__ X,
    const float* __restrict__ Wo, const float* __restrict__ bo, float* __restrict__ out) {
  int t = threadIdx.x;
  int g = blockIdx.x * 4 + (t >> 6);
  int lane = t & 63;
  float2 x = *(const float2*)&X[g * HIDDEN + lane * 2];
  float2 w = *(const float2*)&Wo[lane * 2];
  float p = x.x * w.x + x.y * w.y;
  for (int off = 32; off >= 1; off >>= 1) p += __shfl_down(p, off);
  if (lane == 0) out[g] = p + bo[0];
}

extern "C" void kernel_launch(void* const* d_in, const int* in_sizes, int n_in,
                              void* d_out, int out_size, void* d_ws, size_t ws_size,
                              hipStream_t stream) {
  const float* x_lig = (const float*)d_in[0];
  const float* pseq  = (const float*)d_in[1];
  const float* a2h   = (const float*)d_in[2];
  const int*   ei    = (const int*)d_in[3];
  const int*   batch = (const int*)d_in[4];
  const float* ginW1[3] = {(const float*)d_in[5],  (const float*)d_in[11], (const float*)d_in[17]};
  const float* ginb1[3] = {(const float*)d_in[6],  (const float*)d_in[12], (const float*)d_in[18]};
  const float* ginW2[3] = {(const float*)d_in[7],  (const float*)d_in[13], (const float*)d_in[19]};
  const float* ginb2[3] = {(const float*)d_in[8],  (const float*)d_in[14], (const float*)d_in[20]};
  const float* bng[3]   = {(const float*)d_in[9],  (const float*)d_in[15], (const float*)d_in[21]};
  const float* bnb[3]   = {(const float*)d_in[10], (const float*)d_in[16], (const float*)d_in[22]};
  const float* ligW  = (const float*)d_in[23]; const float* ligb  = (const float*)d_in[24];
  const float* convk = (const float*)d_in[25]; const float* convb = (const float*)d_in[26];
  const float* protW = (const float*)d_in[27]; const float* protb = (const float*)d_in[28];
  const float* a1W   = (const float*)d_in[29]; const float* a1b   = (const float*)d_in[30];
  const float* a2W   = (const float*)d_in[31]; const float* a2b   = (const float*)d_in[32];
  const float* c1W   = (const float*)d_in[33]; const float* c1b   = (const float*)d_in[34];
  const float* c2W   = (const float*)d_in[35]; const float* c2b   = (const float*)d_in[36];
  const float* oW    = (const float*)d_in[37]; const float* ob    = (const float*)d_in[38];

  char* base = (char*)d_ws;
  size_t off = 0;
  auto alloc = [&](size_t bytes) -> char* {
    char* p = base + off;
    off = (off + bytes + 511) & ~size_t(511);
    return p;
  };
  // zeroed prefix
  int*   counts  = (int*)alloc(NNODES * 4);
  int*   gcounts = (int*)alloc(NGRAPHS * 4);
  float* bn_sum  = (float*)alloc(3 * 128 * 4);
  float* bn_sq   = (float*)alloc(3 * 128 * 4);
  float* XA      = (float*)alloc(NGRAPHS * 128 * 4);
  const size_t zero_bytes = off;
  short* wsplit   = (short*)alloc(282624 * 2);
  int*   row_ptr  = (int*)alloc((NNODES + 1) * 4);
  int*   nxt      = (int*)alloc(NNODES * 4);
  int*   gptr     = (int*)alloc((NGRAPHS + 1) * 4);
  int*   bsumsA   = (int*)alloc(401 * 4);
  int*   bsumsB   = (int*)alloc(9 * 4);
  int*   csr_src  = (int*)alloc(NEDGES * 4);
  float* P        = (float*)alloc(NGRAPHS * 128 * 4);
  float* XP32     = (float*)alloc(NGRAPHS * 32 * 4);
  float* XC       = (float*)alloc(NGRAPHS * 384 * 4);
  float* XC2      = (float*)alloc(NGRAPHS * 256 * 4);
  float* XC3      = (float*)alloc(NGRAPHS * 128 * 4);
  float* O0       = (float*)alloc((size_t)NNODES * 128 * 4);
  float* O1       = (float*)alloc((size_t)NNODES * 128 * 4);
  (void)ws_size; (void)in_sizes; (void)n_in; (void)out_size;

  hipMemsetAsync(d_ws, 0, zero_bytes, stream);

  // hist + weight-split, then scan chain, then scatter
  prep_kernel<<<NEDGES / 256 + NNODES / 256 + 736, 256, 0, stream>>>(
      ei, batch, counts, gcounts, ginW1[0], ginW2[0], ginW1[1], ginW2[1],
      ginW1[2], ginW2[2], wsplit);
  scan_block2_kernel<<<NNODES / 256 + NGRAPHS / 256, 256, 0, stream>>>(
      counts, row_ptr, bsumsA, gcounts, gptr, bsumsB);
  scan_top2_kernel<<<2, 1024, 0, stream>>>(bsumsA, bsumsB);
  scan_add2_kernel<<<NNODES / 256 + NGRAPHS / 256, 256, 0, stream>>>(
      row_ptr, bsumsA, nxt, gptr, bsumsB);
  scatter_kernel<<<(NEDGES + 255) / 256, 256, 0, stream>>>(ei, nxt, csr_src);

  // fat0: gin0 (MFMA mm) + a2h split-K + conv
  fat0_kernel<<<NNODES / 32 + (NGRAPHS / 16) * A2H_NSPLIT + NGRAPHS, 256, 0, stream>>>(
      x_lig, row_ptr, csr_src, wsplit, ginb1[0], ginb2[0],
      O0, bn_sum, bn_sq, a2h, a1W, a1b, XA, pseq, convk, convb, XP32);

  // gin1/gin2 (MFMA mm, inline BN of previous layer)
  gin_kernel<<<NNODES / 32, 256, 0, stream>>>(O0, row_ptr, csr_src,
      wsplit + 86016, ginb1[1], wsplit + 135168, ginb2[1],
      bn_sum, bn_sq, bng[0], bnb[0], O1, bn_sum + 128, bn_sq + 128);
  gin_kernel<<<NNODES / 32, 256, 0, stream>>>(O1, row_ptr, csr_src,
      wsplit + 184320, ginb1[2], wsplit + 233472, ginb2[2],
      bn_sum + 128, bn_sq + 128, bng[1], bnb[1], O0, bn_sum + 256, bn_sq + 256);

  // pool (inline BN2) -> fused branch gemms -> head
  pool_kernel<<<NGRAPHS / 4, 256, 0, stream>>>(O0, gptr, bn_sum + 256, bn_sq + 256,
                                               bng[2], bnb[2], P);
  branches_kernel<<<dim3(NGRAPHS / 16, 6), 256, 0, stream>>>(
      P, XP32, XA, ligW, ligb, protW, protb, a2W, a2b, XC);
  gemm2_kernel<<<dim3(NGRAPHS / 16, 4), 256, 0, stream>>>(XC, 384, 384, c1W, 256, c1b, XC2, 256);
  gemm2_kernel<<<dim3(NGRAPHS / 16, 2), 256, 0, stream>>>(XC2, 256, 256, c2W, 128, c2b, XC3, 128);
  final_dot_kernel<<<NGRAPHS / 4, 256, 0, stream>>>(XC3, oW, ob, (float*)d_out);
}

// Round 10
// 764.728 us; speedup vs baseline: 1.8134x; 1.1093x over previous
//
#include <hip/hip_runtime.h>
#include <math.h>

constexpr int NNODES  = 102400;
constexpr int NEDGES  = 409600;
constexpr int NGRAPHS = 2048;
constexpr int HIDDEN  = 128;

typedef __attribute__((ext_vector_type(8))) short s16x8;
typedef __attribute__((ext_vector_type(4))) float f32x4;

__device__ __forceinline__ float relu_f(float v) { return fmaxf(v, 0.0f); }

// exact 3-way bf16 truncation split: x == b0 + b1 + b2
__device__ __forceinline__ void split3(float x, short& s0, short& s1, short& s2) {
  unsigned u0 = __float_as_uint(x);
  s0 = (short)(u0 >> 16);
  float r1 = x - __uint_as_float(u0 & 0xFFFF0000u);
  unsigned u1 = __float_as_uint(r1);
  s1 = (short)(u1 >> 16);
  float r2 = r1 - __uint_as_float(u1 & 0xFFFF0000u);
  s2 = (short)(__float_as_uint(r2) >> 16);
}

// ---------------- prep: histograms + weight-split (merged) ----------------
__global__ void prep_kernel(const int* __restrict__ ei, const int* __restrict__ batch,
                            int* __restrict__ counts, int* __restrict__ gcounts,
                            const float* __restrict__ W10, const float* __restrict__ W20,
                            const float* __restrict__ W11, const float* __restrict__ W21,
                            const float* __restrict__ W12, const float* __restrict__ W22,
                            short* __restrict__ ws) {
  int b = blockIdx.x;
  if (b < NEDGES / 256) {
    atomicAdd(&counts[ei[NEDGES + b * 256 + threadIdx.x]], 1);
    return;
  }
  if (b < NEDGES / 256 + NNODES / 256) {
    atomicAdd(&gcounts[batch[(b - NEDGES / 256) * 256 + threadIdx.x]], 1);
    return;
  }
  int bw = b - (NEDGES / 256 + NNODES / 256);
  int n = threadIdx.x;
  if (n >= 128) return;
  const float* src; long base; int k, realK, KP;
  if (bw < 96) {
    src = W10; base = 0; k = bw; realK = 78; KP = 96;
  } else {
    int q = bw - 96;
    int mat = q >> 7;
    k = q & 127; realK = 128; KP = 128;
    const float* srcs[5] = {W20, W11, W21, W12, W22};
    const long bases[5] = {36864, 86016, 135168, 184320, 233472};
    src = srcs[mat]; base = bases[mat];
  }
  float x = (k < realK) ? src[k * 128 + n] : 0.0f;
  short s0, s1, s2;
  split3(x, s0, s1, s2);
  long e = base + ((long)(k >> 5) * 128 + n) * 32 + (k & 31);
  long ps = (long)KP * 128;
  ws[e] = s0; ws[e + ps] = s1; ws[e + 2 * ps] = s2;
}

// ---------------- merged scans ----------------
__device__ __forceinline__ void scan_block_body(const int* in, int n, int* out_excl,
                                                int* bsums, int lb) {
  __shared__ int s[256];
  int t = threadIdx.x;
  int i = lb * 256 + t;
  int v = (i < n) ? in[i] : 0;
  s[t] = v;
  __syncthreads();
  for (int off = 1; off < 256; off <<= 1) {
    int x = (t >= off) ? s[t - off] : 0;
    __syncthreads();
    s[t] += x;
    __syncthreads();
  }
  if (i < n) out_excl[i] = s[t] - v;
  if (t == 255) bsums[lb] = s[255];
}

__global__ void scan_block2_kernel(const int* __restrict__ counts, int* __restrict__ row_ptr,
                                   int* __restrict__ bsumsA, const int* __restrict__ gcounts,
                                   int* __restrict__ gptr, int* __restrict__ bsumsB) {
  int b = blockIdx.x;
  if (b < NNODES / 256) scan_block_body(counts, NNODES, row_ptr, bsumsA, b);
  else scan_block_body(gcounts, NGRAPHS, gptr, bsumsB, b - NNODES / 256);
}

__global__ void scan_top2_kernel(int* __restrict__ bsumsA, int* __restrict__ bsumsB) {
  __shared__ int s[1024];
  int* bs = (blockIdx.x == 0) ? bsumsA : bsumsB;
  int nb  = (blockIdx.x == 0) ? (NNODES / 256) : (NGRAPHS / 256);
  int t = threadIdx.x;
  int v = (t < nb) ? bs[t] : 0;
  s[t] = v;
  __syncthreads();
  for (int off = 1; off < 1024; off <<= 1) {
    int x = (t >= off) ? s[t - off] : 0;
    __syncthreads();
    s[t] += x;
    __syncthreads();
  }
  if (t < nb) bs[t] = s[t] - v;
  if (t == 1023) bs[nb] = s[1023];
}

__global__ void scan_add2_kernel(int* __restrict__ row_ptr, const int* __restrict__ bsumsA,
                                 int* __restrict__ nxt, int* __restrict__ gptr,
                                 const int* __restrict__ bsumsB) {
  int b = blockIdx.x, t = threadIdx.x;
  if (b < NNODES / 256) {
    int i = b * 256 + t;
    int v = row_ptr[i] + bsumsA[b];
    row_ptr[i] = v;
    nxt[i] = v;
    if (i == 0) row_ptr[NNODES] = bsumsA[NNODES / 256];
  } else {
    int lb = b - NNODES / 256;
    int i = lb * 256 + t;
    gptr[i] += bsumsB[lb];
    if (i == 0) gptr[NGRAPHS] = bsumsB[NGRAPHS / 256];
  }
}

__global__ void scatter_kernel(const int* __restrict__ ei, int* __restrict__ nxt,
                               int* __restrict__ csr_src) {
  int e = blockIdx.x * blockDim.x + threadIdx.x;
  if (e < NEDGES) {
    int s = ei[e];
    int d = ei[NEDGES + e];
    int pos = atomicAdd(&nxt[d], 1);
    csr_src[pos] = s;
  }
}

// ---------------- GIN block body ----------------
// G4 gather (DIN=128): half-wave per row, float4/lane -> 2 rows per VMEM instr,
// 4 pair-slots = all 8 rows of the wave in one pipeline (halves queue entries
// vs R8's float2 scheme). Then MFMA mm1/mm2 via exact bf16x3 split.
constexpr int STRK = 132;
template<int DIN, int KP1, bool XF, bool G4>
__device__ __forceinline__ void gin_block(
    int bid, const float* __restrict__ X,
    const int* __restrict__ row_ptr, const int* __restrict__ csr_src,
    const short* __restrict__ w1s, const float* __restrict__ b1,
    const short* __restrict__ w2s, const float* __restrict__ b2,
    const float* __restrict__ psum, const float* __restrict__ psq,
    const float* __restrict__ bg, const float* __restrict__ bb2,
    float* __restrict__ O, float* __restrict__ bn_sum, float* __restrict__ bn_sq,
    float* buf) {
  const int t = threadIdx.x;
  const int wv = t >> 6, lane = t & 63;
  const int base = bid * 32;

  if (G4) {
    // ---- float4 gather: lane = (row-half, feature-quad)
    const int q = lane & 31, half = lane >> 5;
    const int f = 4 * q;
    float sc[4] = {1.f, 1.f, 1.f, 1.f}, sh[4] = {0.f, 0.f, 0.f, 0.f};
    if (XF) {
#pragma unroll
      for (int c = 0; c < 4; ++c) {
        float mu = psum[f + c] * (1.0f / NNODES);
        float va = fmaxf(psq[f + c] * (1.0f / NNODES) - mu * mu, 0.0f);
        sc[c] = bg[f + c] / sqrtf(va + 1e-5f);
        sh[c] = bb2[f + c] - mu * sc[c];
      }
    }
    float4 acc[4];
    int ecur[4], eend[4], idx[4];
#pragma unroll
    for (int p = 0; p < 4; ++p) {
      const int node = base + wv * 8 + 2 * p + half;
      ecur[p] = row_ptr[node];
      eend[p] = row_ptr[node + 1];
      float4 s = *(const float4*)&X[(long)node * 128 + f];
      if (XF) {
        acc[p].x = relu_f(fmaf(s.x, sc[0], sh[0]));
        acc[p].y = relu_f(fmaf(s.y, sc[1], sh[1]));
        acc[p].z = relu_f(fmaf(s.z, sc[2], sh[2]));
        acc[p].w = relu_f(fmaf(s.w, sc[3], sh[3]));
      } else acc[p] = s;
      idx[p] = (ecur[p] < eend[p]) ? csr_src[ecur[p]] : -1;
    }
    bool any = (idx[0] >= 0) || (idx[1] >= 0) || (idx[2] >= 0) || (idx[3] >= 0);
    while (any) {
      float4 uu[4];
#pragma unroll
      for (int p = 0; p < 4; ++p)
        if (idx[p] >= 0) uu[p] = *(const float4*)&X[(long)idx[p] * 128 + f];
      any = false;
#pragma unroll
      for (int p = 0; p < 4; ++p) {
        if (idx[p] >= 0) {
          if (XF) {
            acc[p].x += relu_f(fmaf(uu[p].x, sc[0], sh[0]));
            acc[p].y += relu_f(fmaf(uu[p].y, sc[1], sh[1]));
            acc[p].z += relu_f(fmaf(uu[p].z, sc[2], sh[2]));
            acc[p].w += relu_f(fmaf(uu[p].w, sc[3], sh[3]));
          } else {
            acc[p].x += uu[p].x; acc[p].y += uu[p].y;
            acc[p].z += uu[p].z; acc[p].w += uu[p].w;
          }
          ++ecur[p];
          idx[p] = (ecur[p] < eend[p]) ? csr_src[ecur[p]] : -1;
        }
        any = any || (idx[p] >= 0);
      }
    }
#pragma unroll
    for (int p = 0; p < 4; ++p)
      *(float4*)&buf[(wv * 8 + 2 * p + half) * STRK + f] = acc[p];
  } else {
    // ---- float2 gather (layer 0, DIN=78, KP=96)
    const int fp = 2 * lane;
    if (fp < KP1) {
      if (fp < DIN) {
        for (int g = 0; g < 2; ++g) {
          const int rbase = wv * 8 + g * 4;
          float a0[4], a1[4];
          int ecur[4], eend[4], idx[4];
#pragma unroll
          for (int r = 0; r < 4; ++r) {
            const int node = base + rbase + r;
            ecur[r] = row_ptr[node];
            eend[r] = row_ptr[node + 1];
            const float2 s = *(const float2*)&X[(long)node * DIN + fp];
            a0[r] = s.x; a1[r] = s.y;
            idx[r] = (ecur[r] < eend[r]) ? csr_src[ecur[r]] : -1;
          }
          bool any = (idx[0] >= 0) || (idx[1] >= 0) || (idx[2] >= 0) || (idx[3] >= 0);
          while (any) {
            float2 uu[4];
#pragma unroll
            for (int r = 0; r < 4; ++r)
              if (idx[r] >= 0) uu[r] = *(const float2*)&X[(long)idx[r] * DIN + fp];
            any = false;
#pragma unroll
            for (int r = 0; r < 4; ++r) {
              if (idx[r] >= 0) {
                a0[r] += uu[r].x;
                a1[r] += uu[r].y;
                ++ecur[r];
                idx[r] = (ecur[r] < eend[r]) ? csr_src[ecur[r]] : -1;
              }
              any = any || (idx[r] >= 0);
            }
          }
#pragma unroll
          for (int r = 0; r < 4; ++r)
            *(float2*)&buf[(rbase + r) * STRK + fp] = make_float2(a0[r], a1[r]);
        }
      } else {
        for (int r = 0; r < 8; ++r)
          *(float2*)&buf[(wv * 8 + r) * STRK + fp] = make_float2(0.f, 0.f);
      }
    }
  }
  __syncthreads();

  const int rb = wv & 1, nbase = (wv >> 1) * 64;
  const int l15 = lane & 15, quad = lane >> 4;
  const int aoff = (rb * 16 + l15) * STRK;
  constexpr int PS1 = KP1 * 128;
  constexpr int PS2 = 128 * 128;

  // ---- mm1 (MFMA): acc1 = h @ W1
  f32x4 acc1[4] = {};
  for (int ks = 0; ks < KP1 / 32; ++ks) {
    const int k0 = ks * 32;
    const float4 xa = *(const float4*)&buf[aoff + k0 + quad * 8];
    const float4 xb = *(const float4*)&buf[aoff + k0 + quad * 8 + 4];
    s16x8 A0, A1, A2;
    {
      const float xv[8] = {xa.x, xa.y, xa.z, xa.w, xb.x, xb.y, xb.z, xb.w};
#pragma unroll
      for (int j = 0; j < 8; ++j) {
        short s0, s1, s2;
        split3(xv[j], s0, s1, s2);
        A0[j] = s0; A1[j] = s1; A2[j] = s2;
      }
    }
    s16x8 B0[4], B1[4], B2[4];
#pragma unroll
    for (int ct = 0; ct < 4; ++ct) {
      const int n = nbase + ct * 16 + l15;
      const short* wp = w1s + ((long)(ks * 128 + n) << 5) + (quad << 3);
      B0[ct] = *(const s16x8*)(wp);
      B1[ct] = *(const s16x8*)(wp + PS1);
      B2[ct] = *(const s16x8*)(wp + 2 * PS1);
    }
#pragma unroll
    for (int ct = 0; ct < 4; ++ct) acc1[ct] = __builtin_amdgcn_mfma_f32_16x16x32_bf16(A0, B2[ct], acc1[ct], 0, 0, 0);
#pragma unroll
    for (int ct = 0; ct < 4; ++ct) acc1[ct] = __builtin_amdgcn_mfma_f32_16x16x32_bf16(A1, B1[ct], acc1[ct], 0, 0, 0);
#pragma unroll
    for (int ct = 0; ct < 4; ++ct) acc1[ct] = __builtin_amdgcn_mfma_f32_16x16x32_bf16(A2, B0[ct], acc1[ct], 0, 0, 0);
#pragma unroll
    for (int ct = 0; ct < 4; ++ct) acc1[ct] = __builtin_amdgcn_mfma_f32_16x16x32_bf16(A0, B1[ct], acc1[ct], 0, 0, 0);
#pragma unroll
    for (int ct = 0; ct < 4; ++ct) acc1[ct] = __builtin_amdgcn_mfma_f32_16x16x32_bf16(A1, B0[ct], acc1[ct], 0, 0, 0);
#pragma unroll
    for (int ct = 0; ct < 4; ++ct) acc1[ct] = __builtin_amdgcn_mfma_f32_16x16x32_bf16(A0, B0[ct], acc1[ct], 0, 0, 0);
  }
  __syncthreads();

  // mid = relu(acc1 + b1), stored [m][j]
#pragma unroll
  for (int ct = 0; ct < 4; ++ct) {
    const int n = nbase + ct * 16 + l15;
    const float bb = b1[n];
#pragma unroll
    for (int reg = 0; reg < 4; ++reg) {
      const int m = rb * 16 + quad * 4 + reg;
      buf[m * STRK + n] = relu_f(acc1[ct][reg] + bb);
    }
  }
  __syncthreads();

  // ---- mm2 (MFMA)
  f32x4 acc2[4] = {};
  for (int ks = 0; ks < 4; ++ks) {
    const int k0 = ks * 32;
    const float4 xa = *(const float4*)&buf[aoff + k0 + quad * 8];
    const float4 xb = *(const float4*)&buf[aoff + k0 + quad * 8 + 4];
    s16x8 A0, A1, A2;
    {
      const float xv[8] = {xa.x, xa.y, xa.z, xa.w, xb.x, xb.y, xb.z, xb.w};
#pragma unroll
      for (int j = 0; j < 8; ++j) {
        short s0, s1, s2;
        split3(xv[j], s0, s1, s2);
        A0[j] = s0; A1[j] = s1; A2[j] = s2;
      }
    }
    s16x8 B0[4], B1[4], B2[4];
#pragma unroll
    for (int ct = 0; ct < 4; ++ct) {
      const int n = nbase + ct * 16 + l15;
      const short* wp = w2s + ((long)(ks * 128 + n) << 5) + (quad << 3);
      B0[ct] = *(const s16x8*)(wp);
      B1[ct] = *(const s16x8*)(wp + PS2);
      B2[ct] = *(const s16x8*)(wp + 2 * PS2);
    }
#pragma unroll
    for (int ct = 0; ct < 4; ++ct) acc2[ct] = __builtin_amdgcn_mfma_f32_16x16x32_bf16(A0, B2[ct], acc2[ct], 0, 0, 0);
#pragma unroll
    for (int ct = 0; ct < 4; ++ct) acc2[ct] = __builtin_amdgcn_mfma_f32_16x16x32_bf16(A1, B1[ct], acc2[ct], 0, 0, 0);
#pragma unroll
    for (int ct = 0; ct < 4; ++ct) acc2[ct] = __builtin_amdgcn_mfma_f32_16x16x32_bf16(A2, B0[ct], acc2[ct], 0, 0, 0);
#pragma unroll
    for (int ct = 0; ct < 4; ++ct) acc2[ct] = __builtin_amdgcn_mfma_f32_16x16x32_bf16(A0, B1[ct], acc2[ct], 0, 0, 0);
#pragma unroll
    for (int ct = 0; ct < 4; ++ct) acc2[ct] = __builtin_amdgcn_mfma_f32_16x16x32_bf16(A1, B0[ct], acc2[ct], 0, 0, 0);
#pragma unroll
    for (int ct = 0; ct < 4; ++ct) acc2[ct] = __builtin_amdgcn_mfma_f32_16x16x32_bf16(A0, B0[ct], acc2[ct], 0, 0, 0);
  }

  // epilogue
  float cs[4], cq[4];
#pragma unroll
  for (int ct = 0; ct < 4; ++ct) {
    const int n = nbase + ct * 16 + l15;
    const float bb = b2[n];
    float s = 0.f, q = 0.f;
#pragma unroll
    for (int reg = 0; reg < 4; ++reg) {
      const int m = rb * 16 + quad * 4 + reg;
      const float o = acc2[ct][reg] + bb;
      O[(long)(base + m) * HIDDEN + n] = o;
      s += o;
      q = fmaf(o, o, q);
    }
    cs[ct] = s; cq[ct] = q;
  }
  __syncthreads();
  const int g = rb * 4 + quad;
#pragma unroll
  for (int ct = 0; ct < 4; ++ct) {
    const int n = nbase + ct * 16 + l15;
    buf[n * 8 + g] = cs[ct];
    buf[1024 + n * 8 + g] = cq[ct];
  }
  __syncthreads();
  if (t < HIDDEN) {
    float s = 0.f, q = 0.f;
    for (int gg = 0; gg < 8; ++gg) { s += buf[t * 8 + gg]; q += buf[1024 + t * 8 + gg]; }
    atomicAdd(&bn_sum[t], s);
    atomicAdd(&bn_sq[t], q);
  }
}

// ---------------- a2h split-K block ----------------
constexpr int A2H_K = 3000, A2H_SPLIT = 200, A2H_NSPLIT = 15;
__device__ __forceinline__ void a2h_block(int rb, int sp, const float* __restrict__ A,
    const float* __restrict__ W, const float* __restrict__ bias, float* __restrict__ XA,
    float* xT) {
  constexpr int STR = 18;
  const int t = threadIdx.x;
  const int row0 = rb * 16;
  const int k0 = sp * A2H_SPLIT;
  for (int i = t; i < 16 * 50; i += 256) {
    const int r = i / 50, kq = i - r * 50;
    const float4 v = *(const float4*)&A[(long)(row0 + r) * A2H_K + k0 + kq * 4];
    xT[(kq * 4 + 0) * STR + r] = v.x;
    xT[(kq * 4 + 1) * STR + r] = v.y;
    xT[(kq * 4 + 2) * STR + r] = v.z;
    xT[(kq * 4 + 3) * STR + r] = v.w;
  }
  __syncthreads();
  const int rg = t >> 5, cg = t & 31;
  const int r0 = rg * 2, j0 = cg * 4;
  float acc[2][4];
  for (int r = 0; r < 2; ++r)
    for (int c = 0; c < 4; ++c) acc[r][c] = 0.f;
  const float* Wp = W + (long)k0 * HIDDEN + j0;
  for (int k = 0; k < A2H_SPLIT; ++k) {
    const float4 w = *(const float4*)&Wp[(long)k * HIDDEN];
    const float2 x = *(const float2*)&xT[k * STR + r0];
    const float wa[4] = {w.x, w.y, w.z, w.w};
    for (int c = 0; c < 4; ++c) {
      acc[0][c] = fmaf(x.x, wa[c], acc[0][c]);
      acc[1][c] = fmaf(x.y, wa[c], acc[1][c]);
    }
  }
  if (sp == 0)
    for (int c = 0; c < 4; ++c) { acc[0][c] += bias[j0 + c]; acc[1][c] += bias[j0 + c]; }
  for (int r = 0; r < 2; ++r)
    for (int c = 0; c < 4; ++c)
      atomicAdd(&XA[(long)(row0 + r0 + r) * HIDDEN + j0 + c], acc[r][c]);
}

// ---------------- conv block ----------------
__device__ __forceinline__ void conv_block(int g, const float* __restrict__ PS,
    const float* __restrict__ CK, const float* __restrict__ CB, float* __restrict__ XP,
    float* seq) {
  const int t = threadIdx.x;
  for (int i = t; i < 1000; i += 256) seq[i] = PS[g * 1000 + i];
  __syncthreads();
  const int pl = t & 31, cgp = t >> 5;
  float kr[4][8];
  for (int cc = 0; cc < 4; ++cc)
    for (int k = 0; k < 8; ++k) kr[cc][k] = CK[(cgp * 4 + cc) * 8 + k];
  float m[4] = {-1e30f, -1e30f, -1e30f, -1e30f};
  for (int i = 0; i < 32; ++i) {
    int p = pl + 32 * i;
    if (p < 993) {
      float sv[8];
      for (int k = 0; k < 8; ++k) sv[k] = seq[p + k];
      for (int cc = 0; cc < 4; ++cc) {
        float s = 0.f;
        for (int k = 0; k < 8; ++k) s = fmaf(sv[k], kr[cc][k], s);
        m[cc] = fmaxf(m[cc], s);
      }
    }
  }
  for (int off = 16; off >= 1; off >>= 1)
    for (int cc = 0; cc < 4; ++cc) m[cc] = fmaxf(m[cc], __shfl_xor(m[cc], off));
  if (pl == 0)
    for (int cc = 0; cc < 4; ++cc)
      XP[g * 32 + cgp * 4 + cc] = relu_f(m[cc] + CB[cgp * 4 + cc]);
}

// ---------------- fat0: gin0 + a2h + conv ----------------
__global__ __launch_bounds__(256, 4) void fat0_kernel(
    const float* __restrict__ x_lig, const int* __restrict__ row_ptr,
    const int* __restrict__ csr_src,
    const short* __restrict__ ws, const float* __restrict__ b1,
    const float* __restrict__ b2,
    float* __restrict__ O0, float* __restrict__ bn_sum, float* __restrict__ bn_sq,
    const float* __restrict__ a2h, const float* __restrict__ a1W,
    const float* __restrict__ a1b, float* __restrict__ XA,
    const float* __restrict__ pseq, const float* __restrict__ convk,
    const float* __restrict__ convb, float* __restrict__ XP32) {
  __shared__ __align__(16) float buf[32 * STRK];
  const int b = blockIdx.x;
  if (b < NNODES / 32) {
    gin_block<78, 96, false, false>(b, x_lig, row_ptr, csr_src, ws, b1, ws + 36864, b2,
                                    nullptr, nullptr, nullptr, nullptr, O0, bn_sum, bn_sq, buf);
  } else if (b < NNODES / 32 + (NGRAPHS / 16) * A2H_NSPLIT) {
    const int q = b - NNODES / 32;
    a2h_block(q & 127, q >> 7, a2h, a1W, a1b, XA, buf);
  } else {
    conv_block(b - (NNODES / 32 + (NGRAPHS / 16) * A2H_NSPLIT), pseq, convk, convb, XP32, buf);
  }
}

// ---------------- gin wrapper (layers 1,2; float4 gather, inline BN) ----------------
__global__ __launch_bounds__(256, 4) void gin_kernel(
    const float* __restrict__ X, const int* __restrict__ row_ptr,
    const int* __restrict__ csr_src,
    const short* __restrict__ w1s, const float* __restrict__ b1,
    const short* __restrict__ w2s, const float* __restrict__ b2,
    const float* __restrict__ psum, const float* __restrict__ psq,
    const float* __restrict__ bg, const float* __restrict__ bb2,
    float* __restrict__ O, float* __restrict__ bn_sum, float* __restrict__ bn_sq) {
  __shared__ __align__(16) float buf[32 * STRK];
  gin_block<128, 128, true, true>(blockIdx.x, X, row_ptr, csr_src, w1s, b1, w2s, b2,
                                  psum, psq, bg, bb2, O, bn_sum, bn_sq, buf);
}

// ---------------- mega-head: pool(BN2 inline) + 3 branch gemms + c1 + c2 + out ----------------
__global__ __launch_bounds__(256) void head_kernel(
    const float* __restrict__ O, const int* __restrict__ gp,
    const float* __restrict__ psum, const float* __restrict__ psq,
    const float* __restrict__ bg, const float* __restrict__ bb2,
    const float* __restrict__ XP32, const float* __restrict__ XA,
    const float* __restrict__ ligW, const float* __restrict__ ligb,
    const float* __restrict__ protW, const float* __restrict__ protb,
    const float* __restrict__ a2W, const float* __restrict__ a2b,
    const float* __restrict__ c1W, const float* __restrict__ c1b,
    const float* __restrict__ c2W, const float* __restrict__ c2b,
    const float* __restrict__ oW, const float* __restrict__ ob,
    float* __restrict__ out) {
  __shared__ float Ps[4][128];
  __shared__ float XAs[4][128];
  __shared__ float XPs[4][32];
  __shared__ float XCs[4][384];
  __shared__ float XC2s[4][256];
  __shared__ float XC3s[4][128];
  const int t = threadIdx.x;
  const int g0 = blockIdx.x * 4;

  // phase A: pool (inline BN of layer 2) + stage XA(relu) / XP
  {
    const int sub = t >> 6, lane = t & 63;
    const int g = g0 + sub;
    const int f0 = lane, f1 = lane + 64;
    float mu0 = psum[f0] * (1.0f / NNODES);
    float va0 = fmaxf(psq[f0] * (1.0f / NNODES) - mu0 * mu0, 0.0f);
    float sc0 = bg[f0] / sqrtf(va0 + 1e-5f);
    float sh0 = bb2[f0] - mu0 * sc0;
    float mu1 = psum[f1] * (1.0f / NNODES);
    float va1 = fmaxf(psq[f1] * (1.0f / NNODES) - mu1 * mu1, 0.0f);
    float sc1 = bg[f1] / sqrtf(va1 + 1e-5f);
    float sh1 = bb2[f1] - mu1 * sc1;
    const int n0 = gp[g], n1 = gp[g + 1];
    float a0 = 0.f, a1 = 0.f;
    for (int n = n0; n < n1; ++n) {
      a0 += relu_f(fmaf(O[(long)n * HIDDEN + f0], sc0, sh0));
      a1 += relu_f(fmaf(O[(long)n * HIDDEN + f1], sc1, sh1));
    }
    Ps[sub][f0] = a0;
    Ps[sub][f1] = a1;
    for (int i = t; i < 512; i += 256) XAs[i >> 7][i & 127] = relu_f(XA[g0 * 128 + i]);
    for (int i = t; i < 128; i += 256) XPs[i >> 5][i & 31] = XP32[g0 * 32 + i];
  }
  __syncthreads();

  // phase B: lig / prot / a2 -> XCs   (thread: col j, 2 graphs)
  {
    const int j = t & 127, pr = t >> 7;
    const int s0 = pr * 2, s1 = pr * 2 + 1;
    float L0 = ligb[j], L1 = L0;
    float A0 = a2b[j], A1 = A0;
    for (int k = 0; k < 128; ++k) {
      const float wl = ligW[k * 128 + j];
      const float wa = a2W[k * 128 + j];
      L0 = fmaf(Ps[s0][k], wl, L0); L1 = fmaf(Ps[s1][k], wl, L1);
      A0 = fmaf(XAs[s0][k], wa, A0); A1 = fmaf(XAs[s1][k], wa, A1);
    }
    float P0 = protb[j], P1 = P0;
    for (int k = 0; k < 32; ++k) {
      const float wp = protW[k * 128 + j];
      P0 = fmaf(XPs[s0][k], wp, P0); P1 = fmaf(XPs[s1][k], wp, P1);
    }
    XCs[s0][j] = relu_f(L0);        XCs[s1][j] = relu_f(L1);
    XCs[s0][128 + j] = relu_f(P0);  XCs[s1][128 + j] = relu_f(P1);
    XCs[s0][256 + j] = relu_f(A0);  XCs[s1][256 + j] = relu_f(A1);
  }
  __syncthreads();

  // phase C: c1 (384 -> 256), thread: col t, all 4 graphs
  {
    const int j = t;
    float a[4];
    const float bv = c1b[j];
    for (int s = 0; s < 4; ++s) a[s] = bv;
    for (int k = 0; k < 384; ++k) {
      const float w = c1W[k * 256 + j];
      for (int s = 0; s < 4; ++s) a[s] = fmaf(XCs[s][k], w, a[s]);
    }
    for (int s = 0; s < 4; ++s) XC2s[s][j] = relu_f(a[s]);
  }
  __syncthreads();

  // phase D: c2 (256 -> 128), thread: col j, 2 graphs
  {
    const int j = t & 127, pr = t >> 7;
    const int s0 = pr * 2, s1 = pr * 2 + 1;
    float a0 = c2b[j], a1 = a0;
    for (int k = 0; k < 256; ++k) {
      const float w = c2W[k * 128 + j];
      a0 = fmaf(XC2s[s0][k], w, a0);
      a1 = fmaf(XC2s[s1][k], w, a1);
    }
    XC3s[s0][j] = relu_f(a0);
    XC3s[s1][j] = relu_f(a1);
  }
  __syncthreads();

  // phase E: out (128 -> 1) — one wave per graph
  {
    const int w = t >> 6, lane = t & 63;
    float p = XC3s[w][lane] * oW[lane] + XC3s[w][lane + 64] * oW[lane + 64];
    for (int off = 32; off >= 1; off >>= 1) p += __shfl_down(p, off);
    if (lane == 0) out[g0 + w] = p + ob[0];
  }
}

extern "C" void kernel_launch(void* const* d_in, const int* in_sizes, int n_in,
                              void* d_out, int out_size, void* d_ws, size_t ws_size,
                              hipStream_t stream) {
  const float* x_lig = (const float*)d_in[0];
  const float* pseq  = (const float*)d_in[1];
  const float* a2h   = (const float*)d_in[2];
  const int*   ei    = (const int*)d_in[3];
  const int*   batch = (const int*)d_in[4];
  const float* ginW1[3] = {(const float*)d_in[5],  (const float*)d_in[11], (const float*)d_in[17]};
  const float* ginb1[3] = {(const float*)d_in[6],  (const float*)d_in[12], (const float*)d_in[18]};
  const float* ginW2[3] = {(const float*)d_in[7],  (const float*)d_in[13], (const float*)d_in[19]};
  const float* ginb2[3] = {(const float*)d_in[8],  (const float*)d_in[14], (const float*)d_in[20]};
  const float* bng[3]   = {(const float*)d_in[9],  (const float*)d_in[15], (const float*)d_in[21]};
  const float* bnb[3]   = {(const float*)d_in[10], (const float*)d_in[16], (const float*)d_in[22]};
  const float* ligW  = (const float*)d_in[23]; const float* ligb  = (const float*)d_in[24];
  const float* convk = (const float*)d_in[25]; const float* convb = (const float*)d_in[26];
  const float* protW = (const float*)d_in[27]; const float* protb = (const float*)d_in[28];
  const float* a1W   = (const float*)d_in[29]; const float* a1b   = (const float*)d_in[30];
  const float* a2W   = (const float*)d_in[31]; const float* a2b   = (const float*)d_in[32];
  const float* c1W   = (const float*)d_in[33]; const float* c1b   = (const float*)d_in[34];
  const float* c2W   = (const float*)d_in[35]; const float* c2b   = (const float*)d_in[36];
  const float* oW    = (const float*)d_in[37]; const float* ob    = (const float*)d_in[38];

  char* base = (char*)d_ws;
  size_t off = 0;
  auto alloc = [&](size_t bytes) -> char* {
    char* p = base + off;
    off = (off + bytes + 511) & ~size_t(511);
    return p;
  };
  int*   counts  = (int*)alloc(NNODES * 4);
  int*   gcounts = (int*)alloc(NGRAPHS * 4);
  float* bn_sum  = (float*)alloc(3 * 128 * 4);
  float* bn_sq   = (float*)alloc(3 * 128 * 4);
  float* XA      = (float*)alloc(NGRAPHS * 128 * 4);
  const size_t zero_bytes = off;
  short* wsplit   = (short*)alloc(282624 * 2);
  int*   row_ptr  = (int*)alloc((NNODES + 1) * 4);
  int*   nxt      = (int*)alloc(NNODES * 4);
  int*   gptr     = (int*)alloc((NGRAPHS + 1) * 4);
  int*   bsumsA   = (int*)alloc(401 * 4);
  int*   bsumsB   = (int*)alloc(9 * 4);
  int*   csr_src  = (int*)alloc(NEDGES * 4);
  float* XP32     = (float*)alloc(NGRAPHS * 32 * 4);
  float* O0       = (float*)alloc((size_t)NNODES * 128 * 4);
  float* O1       = (float*)alloc((size_t)NNODES * 128 * 4);
  (void)ws_size; (void)in_sizes; (void)n_in; (void)out_size;

  hipMemsetAsync(d_ws, 0, zero_bytes, stream);

  prep_kernel<<<NEDGES / 256 + NNODES / 256 + 736, 256, 0, stream>>>(
      ei, batch, counts, gcounts, ginW1[0], ginW2[0], ginW1[1], ginW2[1],
      ginW1[2], ginW2[2], wsplit);
  scan_block2_kernel<<<NNODES / 256 + NGRAPHS / 256, 256, 0, stream>>>(
      counts, row_ptr, bsumsA, gcounts, gptr, bsumsB);
  scan_top2_kernel<<<2, 1024, 0, stream>>>(bsumsA, bsumsB);
  scan_add2_kernel<<<NNODES / 256 + NGRAPHS / 256, 256, 0, stream>>>(
      row_ptr, bsumsA, nxt, gptr, bsumsB);
  scatter_kernel<<<(NEDGES + 255) / 256, 256, 0, stream>>>(ei, nxt, csr_src);

  fat0_kernel<<<NNODES / 32 + (NGRAPHS / 16) * A2H_NSPLIT + NGRAPHS, 256, 0, stream>>>(
      x_lig, row_ptr, csr_src, wsplit, ginb1[0], ginb2[0],
      O0, bn_sum, bn_sq, a2h, a1W, a1b, XA, pseq, convk, convb, XP32);

  gin_kernel<<<NNODES / 32, 256, 0, stream>>>(O0, row_ptr, csr_src,
      wsplit + 86016, ginb1[1], wsplit + 135168, ginb2[1],
      bn_sum, bn_sq, bng[0], bnb[0], O1, bn_sum + 128, bn_sq + 128);
  gin_kernel<<<NNODES / 32, 256, 0, stream>>>(O1, row_ptr, csr_src,
      wsplit + 184320, ginb1[2], wsplit + 233472, ginb2[2],
      bn_sum + 128, bn_sq + 128, bng[1], bnb[1], O0, bn_sum + 256, bn_sq + 256);

  head_kernel<<<NGRAPHS / 4, 256, 0, stream>>>(O0, gptr,
      bn_sum + 256, bn_sq + 256, bng[2], bnb[2], XP32, XA,
      ligW, ligb, protW, protb, a2W, a2b, c1W, c1b, c2W, c2b, oW, ob, (float*)d_out);
}

// Round 11
// 715.804 us; speedup vs baseline: 1.9373x; 1.0683x over previous
//
#include <hip/hip_runtime.h>
#include <math.h>

constexpr int NNODES  = 102400;
constexpr int NEDGES  = 409600;
constexpr int NGRAPHS = 2048;
constexpr int HIDDEN  = 128;

typedef __attribute__((ext_vector_type(8))) short s16x8;
typedef __attribute__((ext_vector_type(4))) float f32x4;

__device__ __forceinline__ float relu_f(float v) { return fmaxf(v, 0.0f); }

// exact 3-way bf16 truncation split: x == b0 + b1 + b2
__device__ __forceinline__ void split3(float x, short& s0, short& s1, short& s2) {
  unsigned u0 = __float_as_uint(x);
  s0 = (short)(u0 >> 16);
  float r1 = x - __uint_as_float(u0 & 0xFFFF0000u);
  unsigned u1 = __float_as_uint(r1);
  s1 = (short)(u1 >> 16);
  float r2 = r1 - __uint_as_float(u1 & 0xFFFF0000u);
  s2 = (short)(__float_as_uint(r2) >> 16);
}

// ---------------- prep: histograms + weight-split (merged) ----------------
__global__ void prep_kernel(const int* __restrict__ ei, const int* __restrict__ batch,
                            int* __restrict__ counts, int* __restrict__ gcounts,
                            const float* __restrict__ W10, const float* __restrict__ W20,
                            const float* __restrict__ W11, const float* __restrict__ W21,
                            const float* __restrict__ W12, const float* __restrict__ W22,
                            short* __restrict__ ws) {
  int b = blockIdx.x;
  if (b < NEDGES / 256) {
    atomicAdd(&counts[ei[NEDGES + b * 256 + threadIdx.x]], 1);
    return;
  }
  if (b < NEDGES / 256 + NNODES / 256) {
    atomicAdd(&gcounts[batch[(b - NEDGES / 256) * 256 + threadIdx.x]], 1);
    return;
  }
  int bw = b - (NEDGES / 256 + NNODES / 256);
  int n = threadIdx.x;
  if (n >= 128) return;
  const float* src; long base; int k, realK, KP;
  if (bw < 96) {
    src = W10; base = 0; k = bw; realK = 78; KP = 96;
  } else {
    int q = bw - 96;
    int mat = q >> 7;
    k = q & 127; realK = 128; KP = 128;
    const float* srcs[5] = {W20, W11, W21, W12, W22};
    const long bases[5] = {36864, 86016, 135168, 184320, 233472};
    src = srcs[mat]; base = bases[mat];
  }
  float x = (k < realK) ? src[k * 128 + n] : 0.0f;
  short s0, s1, s2;
  split3(x, s0, s1, s2);
  long e = base + ((long)(k >> 5) * 128 + n) * 32 + (k & 31);
  long ps = (long)KP * 128;
  ws[e] = s0; ws[e + ps] = s1; ws[e + 2 * ps] = s2;
}

// ---------------- merged scans ----------------
__device__ __forceinline__ void scan_block_body(const int* in, int n, int* out_excl,
                                                int* bsums, int lb) {
  __shared__ int s[256];
  int t = threadIdx.x;
  int i = lb * 256 + t;
  int v = (i < n) ? in[i] : 0;
  s[t] = v;
  __syncthreads();
  for (int off = 1; off < 256; off <<= 1) {
    int x = (t >= off) ? s[t - off] : 0;
    __syncthreads();
    s[t] += x;
    __syncthreads();
  }
  if (i < n) out_excl[i] = s[t] - v;
  if (t == 255) bsums[lb] = s[255];
}

__global__ void scan_block2_kernel(const int* __restrict__ counts, int* __restrict__ row_ptr,
                                   int* __restrict__ bsumsA, const int* __restrict__ gcounts,
                                   int* __restrict__ gptr, int* __restrict__ bsumsB) {
  int b = blockIdx.x;
  if (b < NNODES / 256) scan_block_body(counts, NNODES, row_ptr, bsumsA, b);
  else scan_block_body(gcounts, NGRAPHS, gptr, bsumsB, b - NNODES / 256);
}

__global__ void scan_top2_kernel(int* __restrict__ bsumsA, int* __restrict__ bsumsB) {
  __shared__ int s[1024];
  int* bs = (blockIdx.x == 0) ? bsumsA : bsumsB;
  int nb  = (blockIdx.x == 0) ? (NNODES / 256) : (NGRAPHS / 256);
  int t = threadIdx.x;
  int v = (t < nb) ? bs[t] : 0;
  s[t] = v;
  __syncthreads();
  for (int off = 1; off < 1024; off <<= 1) {
    int x = (t >= off) ? s[t - off] : 0;
    __syncthreads();
    s[t] += x;
    __syncthreads();
  }
  if (t < nb) bs[t] = s[t] - v;
  if (t == 1023) bs[nb] = s[1023];
}

__global__ void scan_add2_kernel(int* __restrict__ row_ptr, const int* __restrict__ bsumsA,
                                 int* __restrict__ nxt, int* __restrict__ gptr,
                                 const int* __restrict__ bsumsB) {
  int b = blockIdx.x, t = threadIdx.x;
  if (b < NNODES / 256) {
    int i = b * 256 + t;
    int v = row_ptr[i] + bsumsA[b];
    row_ptr[i] = v;
    nxt[i] = v;
    if (i == 0) row_ptr[NNODES] = bsumsA[NNODES / 256];
  } else {
    int lb = b - NNODES / 256;
    int i = lb * 256 + t;
    gptr[i] += bsumsB[lb];
    if (i == 0) gptr[NGRAPHS] = bsumsB[NGRAPHS / 256];
  }
}

__global__ void scatter_kernel(const int* __restrict__ ei, int* __restrict__ nxt,
                               int* __restrict__ csr_src) {
  int e = blockIdx.x * blockDim.x + threadIdx.x;
  if (e < NEDGES) {
    int s = ei[e];
    int d = ei[NEDGES + e];
    int pos = atomicAdd(&nxt[d], 1);
    csr_src[pos] = s;
  }
}

// ---------------- GIN block body ----------------
// Gather: depth-2 software-pipelined edge stream per slot (2 X-row loads in
// flight, csr index prefetched 2 ahead -> idx->row dependency off the critical
// path). Then MFMA mm1/mm2 via exact bf16x3 split.
constexpr int STRK = 132;
template<int DIN, int KP1, bool XF, bool G4>
__device__ __forceinline__ void gin_block(
    int bid, const float* __restrict__ X,
    const int* __restrict__ row_ptr, const int* __restrict__ csr_src,
    const short* __restrict__ w1s, const float* __restrict__ b1,
    const short* __restrict__ w2s, const float* __restrict__ b2,
    const float* __restrict__ psum, const float* __restrict__ psq,
    const float* __restrict__ bg, const float* __restrict__ bb2,
    float* __restrict__ O, float* __restrict__ bn_sum, float* __restrict__ bn_sq,
    float* buf) {
  const int t = threadIdx.x;
  const int wv = t >> 6, lane = t & 63;
  const int base = bid * 32;

  if (G4) {
    // ---- float4 gather, depth-2 pipelined: lane = (row-half, feature-quad)
    const int q = lane & 31, half = lane >> 5;
    const int f = 4 * q;
    float sc[4] = {1.f, 1.f, 1.f, 1.f}, sh[4] = {0.f, 0.f, 0.f, 0.f};
    if (XF) {
#pragma unroll
      for (int c = 0; c < 4; ++c) {
        float mu = psum[f + c] * (1.0f / NNODES);
        float va = fmaxf(psq[f + c] * (1.0f / NNODES) - mu * mu, 0.0f);
        sc[c] = bg[f + c] / sqrtf(va + 1e-5f);
        sh[c] = bb2[f + c] - mu * sc[c];
      }
    }
    float4 acc[4], u0[4];
    int e[4], eend[4], i0[4], i1[4];
#pragma unroll
    for (int p = 0; p < 4; ++p) {
      const int node = base + wv * 8 + 2 * p + half;
      e[p] = row_ptr[node];
      eend[p] = row_ptr[node + 1];
      float4 s = *(const float4*)&X[(long)node * 128 + f];
      if (XF) {
        acc[p].x = relu_f(fmaf(s.x, sc[0], sh[0]));
        acc[p].y = relu_f(fmaf(s.y, sc[1], sh[1]));
        acc[p].z = relu_f(fmaf(s.z, sc[2], sh[2]));
        acc[p].w = relu_f(fmaf(s.w, sc[3], sh[3]));
      } else acc[p] = s;
      i0[p] = (e[p] < eend[p]) ? csr_src[e[p]] : -1;
      i1[p] = (e[p] + 1 < eend[p]) ? csr_src[e[p] + 1] : -1;
    }
#pragma unroll
    for (int p = 0; p < 4; ++p)
      if (i0[p] >= 0) u0[p] = *(const float4*)&X[(long)i0[p] * 128 + f];
    bool any = (i0[0] >= 0) || (i0[1] >= 0) || (i0[2] >= 0) || (i0[3] >= 0);
    while (any) {
      float4 u1[4];
      int i2[4];
#pragma unroll
      for (int p = 0; p < 4; ++p)
        if (i1[p] >= 0) u1[p] = *(const float4*)&X[(long)i1[p] * 128 + f];
#pragma unroll
      for (int p = 0; p < 4; ++p)
        i2[p] = (e[p] + 2 < eend[p]) ? csr_src[e[p] + 2] : -1;
      any = false;
#pragma unroll
      for (int p = 0; p < 4; ++p) {
        if (i0[p] >= 0) {
          if (XF) {
            acc[p].x += relu_f(fmaf(u0[p].x, sc[0], sh[0]));
            acc[p].y += relu_f(fmaf(u0[p].y, sc[1], sh[1]));
            acc[p].z += relu_f(fmaf(u0[p].z, sc[2], sh[2]));
            acc[p].w += relu_f(fmaf(u0[p].w, sc[3], sh[3]));
          } else {
            acc[p].x += u0[p].x; acc[p].y += u0[p].y;
            acc[p].z += u0[p].z; acc[p].w += u0[p].w;
          }
        }
        ++e[p];
        i0[p] = i1[p]; i1[p] = i2[p]; u0[p] = u1[p];
        any = any || (i0[p] >= 0);
      }
    }
#pragma unroll
    for (int p = 0; p < 4; ++p)
      *(float4*)&buf[(wv * 8 + 2 * p + half) * STRK + f] = acc[p];
  } else {
    // ---- float2 gather (layer 0, DIN=78, KP=96), depth-2 pipelined
    const int fp = 2 * lane;
    if (fp < KP1) {
      if (fp < DIN) {
        for (int g = 0; g < 2; ++g) {
          const int rbase = wv * 8 + g * 4;
          float a0[4], a1[4];
          float2 u0[4];
          int e[4], eend[4], i0[4], i1[4];
#pragma unroll
          for (int r = 0; r < 4; ++r) {
            const int node = base + rbase + r;
            e[r] = row_ptr[node];
            eend[r] = row_ptr[node + 1];
            const float2 s = *(const float2*)&X[(long)node * DIN + fp];
            a0[r] = s.x; a1[r] = s.y;
            i0[r] = (e[r] < eend[r]) ? csr_src[e[r]] : -1;
            i1[r] = (e[r] + 1 < eend[r]) ? csr_src[e[r] + 1] : -1;
          }
#pragma unroll
          for (int r = 0; r < 4; ++r)
            if (i0[r] >= 0) u0[r] = *(const float2*)&X[(long)i0[r] * DIN + fp];
          bool any = (i0[0] >= 0) || (i0[1] >= 0) || (i0[2] >= 0) || (i0[3] >= 0);
          while (any) {
            float2 u1[4];
            int i2[4];
#pragma unroll
            for (int r = 0; r < 4; ++r)
              if (i1[r] >= 0) u1[r] = *(const float2*)&X[(long)i1[r] * DIN + fp];
#pragma unroll
            for (int r = 0; r < 4; ++r)
              i2[r] = (e[r] + 2 < eend[r]) ? csr_src[e[r] + 2] : -1;
            any = false;
#pragma unroll
            for (int r = 0; r < 4; ++r) {
              if (i0[r] >= 0) {
                a0[r] += u0[r].x;
                a1[r] += u0[r].y;
              }
              ++e[r];
              i0[r] = i1[r]; i1[r] = i2[r]; u0[r] = u1[r];
              any = any || (i0[r] >= 0);
            }
          }
#pragma unroll
          for (int r = 0; r < 4; ++r)
            *(float2*)&buf[(rbase + r) * STRK + fp] = make_float2(a0[r], a1[r]);
        }
      } else {
        for (int r = 0; r < 8; ++r)
          *(float2*)&buf[(wv * 8 + r) * STRK + fp] = make_float2(0.f, 0.f);
      }
    }
  }
  __syncthreads();

  const int rb = wv & 1, nbase = (wv >> 1) * 64;
  const int l15 = lane & 15, quad = lane >> 4;
  const int aoff = (rb * 16 + l15) * STRK;
  constexpr int PS1 = KP1 * 128;
  constexpr int PS2 = 128 * 128;

  // ---- mm1 (MFMA): acc1 = h @ W1
  f32x4 acc1[4] = {};
  for (int ks = 0; ks < KP1 / 32; ++ks) {
    const int k0 = ks * 32;
    const float4 xa = *(const float4*)&buf[aoff + k0 + quad * 8];
    const float4 xb = *(const float4*)&buf[aoff + k0 + quad * 8 + 4];
    s16x8 A0, A1, A2;
    {
      const float xv[8] = {xa.x, xa.y, xa.z, xa.w, xb.x, xb.y, xb.z, xb.w};
#pragma unroll
      for (int j = 0; j < 8; ++j) {
        short s0, s1, s2;
        split3(xv[j], s0, s1, s2);
        A0[j] = s0; A1[j] = s1; A2[j] = s2;
      }
    }
    s16x8 B0[4], B1[4], B2[4];
#pragma unroll
    for (int ct = 0; ct < 4; ++ct) {
      const int n = nbase + ct * 16 + l15;
      const short* wp = w1s + ((long)(ks * 128 + n) << 5) + (quad << 3);
      B0[ct] = *(const s16x8*)(wp);
      B1[ct] = *(const s16x8*)(wp + PS1);
      B2[ct] = *(const s16x8*)(wp + 2 * PS1);
    }
#pragma unroll
    for (int ct = 0; ct < 4; ++ct) acc1[ct] = __builtin_amdgcn_mfma_f32_16x16x32_bf16(A0, B2[ct], acc1[ct], 0, 0, 0);
#pragma unroll
    for (int ct = 0; ct < 4; ++ct) acc1[ct] = __builtin_amdgcn_mfma_f32_16x16x32_bf16(A1, B1[ct], acc1[ct], 0, 0, 0);
#pragma unroll
    for (int ct = 0; ct < 4; ++ct) acc1[ct] = __builtin_amdgcn_mfma_f32_16x16x32_bf16(A2, B0[ct], acc1[ct], 0, 0, 0);
#pragma unroll
    for (int ct = 0; ct < 4; ++ct) acc1[ct] = __builtin_amdgcn_mfma_f32_16x16x32_bf16(A0, B1[ct], acc1[ct], 0, 0, 0);
#pragma unroll
    for (int ct = 0; ct < 4; ++ct) acc1[ct] = __builtin_amdgcn_mfma_f32_16x16x32_bf16(A1, B0[ct], acc1[ct], 0, 0, 0);
#pragma unroll
    for (int ct = 0; ct < 4; ++ct) acc1[ct] = __builtin_amdgcn_mfma_f32_16x16x32_bf16(A0, B0[ct], acc1[ct], 0, 0, 0);
  }
  __syncthreads();

  // mid = relu(acc1 + b1), stored [m][j]
#pragma unroll
  for (int ct = 0; ct < 4; ++ct) {
    const int n = nbase + ct * 16 + l15;
    const float bb = b1[n];
#pragma unroll
    for (int reg = 0; reg < 4; ++reg) {
      const int m = rb * 16 + quad * 4 + reg;
      buf[m * STRK + n] = relu_f(acc1[ct][reg] + bb);
    }
  }
  __syncthreads();

  // ---- mm2 (MFMA)
  f32x4 acc2[4] = {};
  for (int ks = 0; ks < 4; ++ks) {
    const int k0 = ks * 32;
    const float4 xa = *(const float4*)&buf[aoff + k0 + quad * 8];
    const float4 xb = *(const float4*)&buf[aoff + k0 + quad * 8 + 4];
    s16x8 A0, A1, A2;
    {
      const float xv[8] = {xa.x, xa.y, xa.z, xa.w, xb.x, xb.y, xb.z, xb.w};
#pragma unroll
      for (int j = 0; j < 8; ++j) {
        short s0, s1, s2;
        split3(xv[j], s0, s1, s2);
        A0[j] = s0; A1[j] = s1; A2[j] = s2;
      }
    }
    s16x8 B0[4], B1[4], B2[4];
#pragma unroll
    for (int ct = 0; ct < 4; ++ct) {
      const int n = nbase + ct * 16 + l15;
      const short* wp = w2s + ((long)(ks * 128 + n) << 5) + (quad << 3);
      B0[ct] = *(const s16x8*)(wp);
      B1[ct] = *(const s16x8*)(wp + PS2);
      B2[ct] = *(const s16x8*)(wp + 2 * PS2);
    }
#pragma unroll
    for (int ct = 0; ct < 4; ++ct) acc2[ct] = __builtin_amdgcn_mfma_f32_16x16x32_bf16(A0, B2[ct], acc2[ct], 0, 0, 0);
#pragma unroll
    for (int ct = 0; ct < 4; ++ct) acc2[ct] = __builtin_amdgcn_mfma_f32_16x16x32_bf16(A1, B1[ct], acc2[ct], 0, 0, 0);
#pragma unroll
    for (int ct = 0; ct < 4; ++ct) acc2[ct] = __builtin_amdgcn_mfma_f32_16x16x32_bf16(A2, B0[ct], acc2[ct], 0, 0, 0);
#pragma unroll
    for (int ct = 0; ct < 4; ++ct) acc2[ct] = __builtin_amdgcn_mfma_f32_16x16x32_bf16(A0, B1[ct], acc2[ct], 0, 0, 0);
#pragma unroll
    for (int ct = 0; ct < 4; ++ct) acc2[ct] = __builtin_amdgcn_mfma_f32_16x16x32_bf16(A1, B0[ct], acc2[ct], 0, 0, 0);
#pragma unroll
    for (int ct = 0; ct < 4; ++ct) acc2[ct] = __builtin_amdgcn_mfma_f32_16x16x32_bf16(A0, B0[ct], acc2[ct], 0, 0, 0);
  }

  // epilogue
  float cs[4], cq[4];
#pragma unroll
  for (int ct = 0; ct < 4; ++ct) {
    const int n = nbase + ct * 16 + l15;
    const float bb = b2[n];
    float s = 0.f, q = 0.f;
#pragma unroll
    for (int reg = 0; reg < 4; ++reg) {
      const int m = rb * 16 + quad * 4 + reg;
      const float o = acc2[ct][reg] + bb;
      O[(long)(base + m) * HIDDEN + n] = o;
      s += o;
      q = fmaf(o, o, q);
    }
    cs[ct] = s; cq[ct] = q;
  }
  __syncthreads();
  const int g = rb * 4 + quad;
#pragma unroll
  for (int ct = 0; ct < 4; ++ct) {
    const int n = nbase + ct * 16 + l15;
    buf[n * 8 + g] = cs[ct];
    buf[1024 + n * 8 + g] = cq[ct];
  }
  __syncthreads();
  if (t < HIDDEN) {
    float s = 0.f, q = 0.f;
    for (int gg = 0; gg < 8; ++gg) { s += buf[t * 8 + gg]; q += buf[1024 + t * 8 + gg]; }
    atomicAdd(&bn_sum[t], s);
    atomicAdd(&bn_sq[t], q);
  }
}

// ---------------- a2h split-K block ----------------
constexpr int A2H_K = 3000, A2H_SPLIT = 200, A2H_NSPLIT = 15;
__device__ __forceinline__ void a2h_block(int rb, int sp, const float* __restrict__ A,
    const float* __restrict__ W, const float* __restrict__ bias, float* __restrict__ XA,
    float* xT) {
  constexpr int STR = 18;
  const int t = threadIdx.x;
  const int row0 = rb * 16;
  const int k0 = sp * A2H_SPLIT;
  for (int i = t; i < 16 * 50; i += 256) {
    const int r = i / 50, kq = i - r * 50;
    const float4 v = *(const float4*)&A[(long)(row0 + r) * A2H_K + k0 + kq * 4];
    xT[(kq * 4 + 0) * STR + r] = v.x;
    xT[(kq * 4 + 1) * STR + r] = v.y;
    xT[(kq * 4 + 2) * STR + r] = v.z;
    xT[(kq * 4 + 3) * STR + r] = v.w;
  }
  __syncthreads();
  const int rg = t >> 5, cg = t & 31;
  const int r0 = rg * 2, j0 = cg * 4;
  float acc[2][4];
  for (int r = 0; r < 2; ++r)
    for (int c = 0; c < 4; ++c) acc[r][c] = 0.f;
  const float* Wp = W + (long)k0 * HIDDEN + j0;
  for (int k = 0; k < A2H_SPLIT; ++k) {
    const float4 w = *(const float4*)&Wp[(long)k * HIDDEN];
    const float2 x = *(const float2*)&xT[k * STR + r0];
    const float wa[4] = {w.x, w.y, w.z, w.w};
    for (int c = 0; c < 4; ++c) {
      acc[0][c] = fmaf(x.x, wa[c], acc[0][c]);
      acc[1][c] = fmaf(x.y, wa[c], acc[1][c]);
    }
  }
  if (sp == 0)
    for (int c = 0; c < 4; ++c) { acc[0][c] += bias[j0 + c]; acc[1][c] += bias[j0 + c]; }
  for (int r = 0; r < 2; ++r)
    for (int c = 0; c < 4; ++c)
      atomicAdd(&XA[(long)(row0 + r0 + r) * HIDDEN + j0 + c], acc[r][c]);
}

// ---------------- conv block ----------------
__device__ __forceinline__ void conv_block(int g, const float* __restrict__ PS,
    const float* __restrict__ CK, const float* __restrict__ CB, float* __restrict__ XP,
    float* seq) {
  const int t = threadIdx.x;
  for (int i = t; i < 1000; i += 256) seq[i] = PS[g * 1000 + i];
  __syncthreads();
  const int pl = t & 31, cgp = t >> 5;
  float kr[4][8];
  for (int cc = 0; cc < 4; ++cc)
    for (int k = 0; k < 8; ++k) kr[cc][k] = CK[(cgp * 4 + cc) * 8 + k];
  float m[4] = {-1e30f, -1e30f, -1e30f, -1e30f};
  for (int i = 0; i < 32; ++i) {
    int p = pl + 32 * i;
    if (p < 993) {
      float sv[8];
      for (int k = 0; k < 8; ++k) sv[k] = seq[p + k];
      for (int cc = 0; cc < 4; ++cc) {
        float s = 0.f;
        for (int k = 0; k < 8; ++k) s = fmaf(sv[k], kr[cc][k], s);
        m[cc] = fmaxf(m[cc], s);
      }
    }
  }
  for (int off = 16; off >= 1; off >>= 1)
    for (int cc = 0; cc < 4; ++cc) m[cc] = fmaxf(m[cc], __shfl_xor(m[cc], off));
  if (pl == 0)
    for (int cc = 0; cc < 4; ++cc)
      XP[g * 32 + cgp * 4 + cc] = relu_f(m[cc] + CB[cgp * 4 + cc]);
}

// ---------------- fat0: gin0 + a2h + conv ----------------
__global__ __launch_bounds__(256, 4) void fat0_kernel(
    const float* __restrict__ x_lig, const int* __restrict__ row_ptr,
    const int* __restrict__ csr_src,
    const short* __restrict__ ws, const float* __restrict__ b1,
    const float* __restrict__ b2,
    float* __restrict__ O0, float* __restrict__ bn_sum, float* __restrict__ bn_sq,
    const float* __restrict__ a2h, const float* __restrict__ a1W,
    const float* __restrict__ a1b, float* __restrict__ XA,
    const float* __restrict__ pseq, const float* __restrict__ convk,
    const float* __restrict__ convb, float* __restrict__ XP32) {
  __shared__ __align__(16) float buf[32 * STRK];
  const int b = blockIdx.x;
  if (b < NNODES / 32) {
    gin_block<78, 96, false, false>(b, x_lig, row_ptr, csr_src, ws, b1, ws + 36864, b2,
                                    nullptr, nullptr, nullptr, nullptr, O0, bn_sum, bn_sq, buf);
  } else if (b < NNODES / 32 + (NGRAPHS / 16) * A2H_NSPLIT) {
    const int q = b - NNODES / 32;
    a2h_block(q & 127, q >> 7, a2h, a1W, a1b, XA, buf);
  } else {
    conv_block(b - (NNODES / 32 + (NGRAPHS / 16) * A2H_NSPLIT), pseq, convk, convb, XP32, buf);
  }
}

// ---------------- gin wrapper (layers 1,2; pipelined float4 gather, inline BN) ----------------
__global__ __launch_bounds__(256, 4) void gin_kernel(
    const float* __restrict__ X, const int* __restrict__ row_ptr,
    const int* __restrict__ csr_src,
    const short* __restrict__ w1s, const float* __restrict__ b1,
    const short* __restrict__ w2s, const float* __restrict__ b2,
    const float* __restrict__ psum, const float* __restrict__ psq,
    const float* __restrict__ bg, const float* __restrict__ bb2,
    float* __restrict__ O, float* __restrict__ bn_sum, float* __restrict__ bn_sq) {
  __shared__ __align__(16) float buf[32 * STRK];
  gin_block<128, 128, true, true>(blockIdx.x, X, row_ptr, csr_src, w1s, b1, w2s, b2,
                                  psum, psq, bg, bb2, O, bn_sum, bn_sq, buf);
}

// ---------------- mega-head: pool(BN2 inline) + 3 branch gemms + c1 + c2 + out ----------------
__global__ __launch_bounds__(256) void head_kernel(
    const float* __restrict__ O, const int* __restrict__ gp,
    const float* __restrict__ psum, const float* __restrict__ psq,
    const float* __restrict__ bg, const float* __restrict__ bb2,
    const float* __restrict__ XP32, const float* __restrict__ XA,
    const float* __restrict__ ligW, const float* __restrict__ ligb,
    const float* __restrict__ protW, const float* __restrict__ protb,
    const float* __restrict__ a2W, const float* __restrict__ a2b,
    const float* __restrict__ c1W, const float* __restrict__ c1b,
    const float* __restrict__ c2W, const float* __restrict__ c2b,
    const float* __restrict__ oW, const float* __restrict__ ob,
    float* __restrict__ out) {
  __shared__ float Ps[4][128];
  __shared__ float XAs[4][128];
  __shared__ float XPs[4][32];
  __shared__ float XCs[4][384];
  __shared__ float XC2s[4][256];
  __shared__ float XC3s[4][128];
  const int t = threadIdx.x;
  const int g0 = blockIdx.x * 4;

  // phase A: pool (inline BN of layer 2) + stage XA(relu) / XP
  {
    const int sub = t >> 6, lane = t & 63;
    const int g = g0 + sub;
    const int f0 = lane, f1 = lane + 64;
    float mu0 = psum[f0] * (1.0f / NNODES);
    float va0 = fmaxf(psq[f0] * (1.0f / NNODES) - mu0 * mu0, 0.0f);
    float sc0 = bg[f0] / sqrtf(va0 + 1e-5f);
    float sh0 = bb2[f0] - mu0 * sc0;
    float mu1 = psum[f1] * (1.0f / NNODES);
    float va1 = fmaxf(psq[f1] * (1.0f / NNODES) - mu1 * mu1, 0.0f);
    float sc1 = bg[f1] / sqrtf(va1 + 1e-5f);
    float sh1 = bb2[f1] - mu1 * sc1;
    const int n0 = gp[g], n1 = gp[g + 1];
    float a0 = 0.f, a1 = 0.f;
    for (int n = n0; n < n1; ++n) {
      a0 += relu_f(fmaf(O[(long)n * HIDDEN + f0], sc0, sh0));
      a1 += relu_f(fmaf(O[(long)n * HIDDEN + f1], sc1, sh1));
    }
    Ps[sub][f0] = a0;
    Ps[sub][f1] = a1;
    for (int i = t; i < 512; i += 256) XAs[i >> 7][i & 127] = relu_f(XA[g0 * 128 + i]);
    for (int i = t; i < 128; i += 256) XPs[i >> 5][i & 31] = XP32[g0 * 32 + i];
  }
  __syncthreads();

  // phase B: lig / prot / a2 -> XCs
  {
    const int j = t & 127, pr = t >> 7;
    const int s0 = pr * 2, s1 = pr * 2 + 1;
    float L0 = ligb[j], L1 = L0;
    float A0 = a2b[j], A1 = A0;
    for (int k = 0; k < 128; ++k) {
      const float wl = ligW[k * 128 + j];
      const float wa = a2W[k * 128 + j];
      L0 = fmaf(Ps[s0][k], wl, L0); L1 = fmaf(Ps[s1][k], wl, L1);
      A0 = fmaf(XAs[s0][k], wa, A0); A1 = fmaf(XAs[s1][k], wa, A1);
    }
    float P0 = protb[j], P1 = P0;
    for (int k = 0; k < 32; ++k) {
      const float wp = protW[k * 128 + j];
      P0 = fmaf(XPs[s0][k], wp, P0); P1 = fmaf(XPs[s1][k], wp, P1);
    }
    XCs[s0][j] = relu_f(L0);        XCs[s1][j] = relu_f(L1);
    XCs[s0][128 + j] = relu_f(P0);  XCs[s1][128 + j] = relu_f(P1);
    XCs[s0][256 + j] = relu_f(A0);  XCs[s1][256 + j] = relu_f(A1);
  }
  __syncthreads();

  // phase C: c1 (384 -> 256)
  {
    const int j = t;
    float a[4];
    const float bv = c1b[j];
    for (int s = 0; s < 4; ++s) a[s] = bv;
    for (int k = 0; k < 384; ++k) {
      const float w = c1W[k * 256 + j];
      for (int s = 0; s < 4; ++s) a[s] = fmaf(XCs[s][k], w, a[s]);
    }
    for (int s = 0; s < 4; ++s) XC2s[s][j] = relu_f(a[s]);
  }
  __syncthreads();

  // phase D: c2 (256 -> 128)
  {
    const int j = t & 127, pr = t >> 7;
    const int s0 = pr * 2, s1 = pr * 2 + 1;
    float a0 = c2b[j], a1 = a0;
    for (int k = 0; k < 256; ++k) {
      const float w = c2W[k * 128 + j];
      a0 = fmaf(XC2s[s0][k], w, a0);
      a1 = fmaf(XC2s[s1][k], w, a1);
    }
    XC3s[s0][j] = relu_f(a0);
    XC3s[s1][j] = relu_f(a1);
  }
  __syncthreads();

  // phase E: out (128 -> 1)
  {
    const int w = t >> 6, lane = t & 63;
    float p = XC3s[w][lane] * oW[lane] + XC3s[w][lane + 64] * oW[lane + 64];
    for (int off = 32; off >= 1; off >>= 1) p += __shfl_down(p, off);
    if (lane == 0) out[g0 + w] = p + ob[0];
  }
}

extern "C" void kernel_launch(void* const* d_in, const int* in_sizes, int n_in,
                              void* d_out, int out_size, void* d_ws, size_t ws_size,
                              hipStream_t stream) {
  const float* x_lig = (const float*)d_in[0];
  const float* pseq  = (const float*)d_in[1];
  const float* a2h   = (const float*)d_in[2];
  const int*   ei    = (const int*)d_in[3];
  const int*   batch = (const int*)d_in[4];
  const float* ginW1[3] = {(const float*)d_in[5],  (const float*)d_in[11], (const float*)d_in[17]};
  const float* ginb1[3] = {(const float*)d_in[6],  (const float*)d_in[12], (const float*)d_in[18]};
  const float* ginW2[3] = {(const float*)d_in[7],  (const float*)d_in[13], (const float*)d_in[19]};
  const float* ginb2[3] = {(const float*)d_in[8],  (const float*)d_in[14], (const float*)d_in[20]};
  const float* bng[3]   = {(const float*)d_in[9],  (const float*)d_in[15], (const float*)d_in[21]};
  const float* bnb[3]   = {(const float*)d_in[10], (const float*)d_in[16], (const float*)d_in[22]};
  const float* ligW  = (const float*)d_in[23]; const float* ligb  = (const float*)d_in[24];
  const float* convk = (const float*)d_in[25]; const float* convb = (const float*)d_in[26];
  const float* protW = (const float*)d_in[27]; const float* protb = (const float*)d_in[28];
  const float* a1W   = (const float*)d_in[29]; const float* a1b   = (const float*)d_in[30];
  const float* a2W   = (const float*)d_in[31]; const float* a2b   = (const float*)d_in[32];
  const float* c1W   = (const float*)d_in[33]; const float* c1b   = (const float*)d_in[34];
  const float* c2W   = (const float*)d_in[35]; const float* c2b   = (const float*)d_in[36];
  const float* oW    = (const float*)d_in[37]; const float* ob    = (const float*)d_in[38];

  char* base = (char*)d_ws;
  size_t off = 0;
  auto alloc = [&](size_t bytes) -> char* {
    char* p = base + off;
    off = (off + bytes + 511) & ~size_t(511);
    return p;
  };
  int*   counts  = (int*)alloc(NNODES * 4);
  int*   gcounts = (int*)alloc(NGRAPHS * 4);
  float* bn_sum  = (float*)alloc(3 * 128 * 4);
  float* bn_sq   = (float*)alloc(3 * 128 * 4);
  float* XA      = (float*)alloc(NGRAPHS * 128 * 4);
  const size_t zero_bytes = off;
  short* wsplit   = (short*)alloc(282624 * 2);
  int*   row_ptr  = (int*)alloc((NNODES + 1) * 4);
  int*   nxt      = (int*)alloc(NNODES * 4);
  int*   gptr     = (int*)alloc((NGRAPHS + 1) * 4);
  int*   bsumsA   = (int*)alloc(401 * 4);
  int*   bsumsB   = (int*)alloc(9 * 4);
  int*   csr_src  = (int*)alloc(NEDGES * 4);
  float* XP32     = (float*)alloc(NGRAPHS * 32 * 4);
  float* O0       = (float*)alloc((size_t)NNODES * 128 * 4);
  float* O1       = (float*)alloc((size_t)NNODES * 128 * 4);
  (void)ws_size; (void)in_sizes; (void)n_in; (void)out_size;

  hipMemsetAsync(d_ws, 0, zero_bytes, stream);

  prep_kernel<<<NEDGES / 256 + NNODES / 256 + 736, 256, 0, stream>>>(
      ei, batch, counts, gcounts, ginW1[0], ginW2[0], ginW1[1], ginW2[1],
      ginW1[2], ginW2[2], wsplit);
  scan_block2_kernel<<<NNODES / 256 + NGRAPHS / 256, 256, 0, stream>>>(
      counts, row_ptr, bsumsA, gcounts, gptr, bsumsB);
  scan_top2_kernel<<<2, 1024, 0, stream>>>(bsumsA, bsumsB);
  scan_add2_kernel<<<NNODES / 256 + NGRAPHS / 256, 256, 0, stream>>>(
      row_ptr, bsumsA, nxt, gptr, bsumsB);
  scatter_kernel<<<(NEDGES + 255) / 256, 256, 0, stream>>>(ei, nxt, csr_src);

  fat0_kernel<<<NNODES / 32 + (NGRAPHS / 16) * A2H_NSPLIT + NGRAPHS, 256, 0, stream>>>(
      x_lig, row_ptr, csr_src, wsplit, ginb1[0], ginb2[0],
      O0, bn_sum, bn_sq, a2h, a1W, a1b, XA, pseq, convk, convb, XP32);

  gin_kernel<<<NNODES / 32, 256, 0, stream>>>(O0, row_ptr, csr_src,
      wsplit + 86016, ginb1[1], wsplit + 135168, ginb2[1],
      bn_sum, bn_sq, bng[0], bnb[0], O1, bn_sum + 128, bn_sq + 128);
  gin_kernel<<<NNODES / 32, 256, 0, stream>>>(O1, row_ptr, csr_src,
      wsplit + 184320, ginb1[2], wsplit + 233472, ginb2[2],
      bn_sum + 128, bn_sq + 128, bng[1], bnb[1], O0, bn_sum + 256, bn_sq + 256);

  head_kernel<<<NGRAPHS / 4, 256, 0, stream>>>(O0, gptr,
      bn_sum + 256, bn_sq + 256, bng[2], bnb[2], XP32, XA,
      ligW, ligb, protW, protb, a2W, a2b, c1W, c1b, c2W, c2b, oW, ob, (float*)d_out);
}